// Round 7
// baseline (21464.767 us; speedup 1.0000x reference)
//
#include <hip/hip_runtime.h>
#include <hip/hip_bf16.h>
#include <math.h>

#define NB 16
#define TT 4096
#define LL 512
#define DM 128
#define DI 256
#define NLAYER 6

static __device__ __forceinline__ float gelu_f(float v){
  return 0.5f*v*(1.f + erff(v*0.70710678118654752f));
}
static __device__ __forceinline__ float silu_f(float v){
  return v/(1.f + expf(-v));
}

__global__ __launch_bounds__(256) void k_maskmul(const float* __restrict__ x, const float* __restrict__ m,
                          float* __restrict__ out, int n){
  int i = blockIdx.x*256 + threadIdx.x;
  if (i < n) out[i] = x[i]*m[i];
}

// conv1d stride2 pad1 k3: (B,Ci,Li)->(B,Co,Li/2). block per (b,o). W (Co,Ci,3).
__global__ __launch_bounds__(256) void k_conv2(const float* __restrict__ x, const float* __restrict__ W,
                        const float* __restrict__ bias, float* __restrict__ y,
                        int Ci, int Co, int Li){
  __shared__ float w[192];
  int b = blockIdx.x / Co, o = blockIdx.x % Co;
  for (int j = threadIdx.x; j < Ci*3; j += 256) w[j] = W[(size_t)o*Ci*3 + j];
  __syncthreads();
  int Lo = Li >> 1;
  const float* xb = x + (size_t)b*Ci*Li;
  float bo = bias[o];
  float* yo = y + ((size_t)b*Co + o)*Lo;
  for (int t = threadIdx.x; t < Lo; t += 256){
    int tin = 2*t - 1;
    float acc = bo;
    for (int ci = 0; ci < Ci; ci++){
      const float* xr = xb + (size_t)ci*Li;
      float v0 = (tin >= 0) ? xr[tin] : 0.f;
      acc += w[ci*3+0]*v0 + w[ci*3+1]*xr[tin+1] + w[ci*3+2]*xr[tin+2];
    }
    yo[t] = acc;
  }
}

// GroupNorm(1 group) over (C,T) per batch, two-pass, then exact GELU. in-place.
__global__ __launch_bounds__(256) void k_gn_gelu2(float* __restrict__ x, const float* __restrict__ g,
                           const float* __restrict__ be, int C, int Tl){
  __shared__ float sh[4];
  __shared__ float bc;
  int b = blockIdx.x;
  int n = C*Tl;
  float* xb = x + (size_t)b*n;
  float s = 0.f;
  for (int i = threadIdx.x; i < n; i += 256) s += xb[i];
  #pragma unroll
  for (int o = 32; o; o >>= 1) s += __shfl_down(s, o);
  if ((threadIdx.x & 63) == 0) sh[threadIdx.x >> 6] = s;
  __syncthreads();
  if (threadIdx.x == 0) bc = (sh[0]+sh[1]+sh[2]+sh[3])/(float)n;
  __syncthreads();
  float mean = bc;
  float s2 = 0.f;
  for (int i = threadIdx.x; i < n; i += 256){ float d = xb[i]-mean; s2 += d*d; }
  #pragma unroll
  for (int o = 32; o; o >>= 1) s2 += __shfl_down(s2, o);
  __syncthreads();
  if ((threadIdx.x & 63) == 0) sh[threadIdx.x >> 6] = s2;
  __syncthreads();
  if (threadIdx.x == 0) bc = rsqrtf((sh[0]+sh[1]+sh[2]+sh[3])/(float)n + 1e-5f);
  __syncthreads();
  float inv = bc;
  for (int i = threadIdx.x; i < n; i += 256){
    int c = i / Tl;
    float v = (xb[i]-mean)*inv*g[c] + be[c];
    xb[i] = gelu_f(v);
  }
}

// (B,128,512) NCH -> (B,512,128) BLD.
__global__ __launch_bounds__(256) void k_transpose2(const float* __restrict__ in, float* __restrict__ out){
  int idx = blockIdx.x*256 + threadIdx.x;
  if (idx >= NB*DM*LL) return;
  int t = idx & 511;
  int c = (idx >> 9) & 127;
  int b = idx >> 16;
  out[(size_t)b*65536 + (size_t)t*128 + c] = in[idx];
}

// LayerNorm last-dim(128), one wave per row.
__global__ __launch_bounds__(256) void k_ln2(const float* __restrict__ x, const float* __restrict__ g,
                      const float* __restrict__ be, float* __restrict__ out, int rows){
  int row = blockIdx.x*4 + (threadIdx.x >> 6);
  if (row >= rows) return;
  int lid = threadIdx.x & 63;
  const float* xr = x + (size_t)row*DM;
  float v0 = xr[lid], v1 = xr[lid+64];
  float s = v0 + v1;
  #pragma unroll
  for (int o = 32; o; o >>= 1) s += __shfl_xor(s, o);
  float mean = s*(1.f/128.f);
  float d0 = v0-mean, d1 = v1-mean;
  float s2 = d0*d0 + d1*d1;
  #pragma unroll
  for (int o = 32; o; o >>= 1) s2 += __shfl_xor(s2, o);
  float inv = rsqrtf(s2*(1.f/128.f) + 1e-5f);
  float* orow = out + (size_t)row*DM;
  orow[lid]    = d0*inv*g[lid]    + be[lid];
  orow[lid+64] = d1*inv*g[lid+64] + be[lid+64];
}

// C[m,n] (+)= sum_k A[m*lda+k]*B[n*K+k].
template<int ACCUM>
__global__ __launch_bounds__(256) void k_gemm_naive(const float* __restrict__ A, const float* __restrict__ B,
                             float* __restrict__ C, int N, int K, int lda){
  int m = blockIdx.x;
  int n = blockIdx.y*256 + threadIdx.x;
  if (n >= N) return;
  const float* a = A + (size_t)m*lda;
  const float* b = B + (size_t)n*K;
  float acc = 0.f;
  for (int k = 0; k < K; k++) acc += a[k]*b[k];
  size_t off = (size_t)m*N + n;
  C[off] = (ACCUM ? C[off] : 0.f) + acc;
}

// depthwise causal conv k=4 over xi=XZ[...,:256], +bias, SiLU -> XC (B,L,256)
__global__ __launch_bounds__(256) void k_cconv2(const float* __restrict__ xz, const float* __restrict__ cw,
                         const float* __restrict__ cb, float* __restrict__ xc){
  int idx = blockIdx.x*256 + threadIdx.x;
  if (idx >= NB*LL*DI) return;
  int d = idx & 255;
  int l = (idx >> 8) & 511;
  int b = idx >> 17;
  const float* xi = xz + (size_t)b*262144 + d;
  float acc = cb[d];
  #pragma unroll
  for (int j = 0; j < 4; j++){
    int m = l - 3 + j;
    if (m >= 0) acc += xi[(size_t)m*512]*cw[d*4 + j];
  }
  xc[idx] = silu_f(acc);
}

// dt[row,d] = softplus(dt_b[d] + sum_r dbl[row*40+r]*dt_W[d*8+r])
__global__ __launch_bounds__(256) void k_dt2(const float* __restrict__ dbl, const float* __restrict__ dtW,
                      const float* __restrict__ dtb, float* __restrict__ dt){
  int idx = blockIdx.x*256 + threadIdx.x;
  if (idx >= NB*LL*DI) return;
  int d = idx & 255;
  int row = idx >> 8;
  const float* r = dbl + (size_t)row*40;
  float acc = dtb[d];
  #pragma unroll
  for (int j = 0; j < 8; j++) acc += r[j]*dtW[d*8 + j];
  dt[idx] = (acc > 20.f) ? acc : log1pf(expf(acc));
}

// scan: one thread per (b,d); 16 states in registers.
__global__ __launch_bounds__(256) void k_scan2(const float* __restrict__ dt, const float* __restrict__ xc,
                        const float* __restrict__ dbl, const float* __restrict__ xz,
                        const float* __restrict__ Alog, const float* __restrict__ Dp,
                        float* __restrict__ y){
  int id = blockIdx.x*256 + threadIdx.x;
  int b = id >> 8;
  int d = id & 255;
  float ea[16], h[16];
  #pragma unroll
  for (int s = 0; s < 16; s++){ ea[s] = expf(Alog[d*16 + s]); h[s] = 0.f; }
  float Dd = Dp[d];
  const float* dtp = dt + (size_t)b*LL*DI + d;
  const float* xcp = xc + (size_t)b*LL*DI + d;
  const float* zp  = xz + (size_t)b*262144 + 256 + d;
  const float* dbp = dbl + (size_t)b*LL*40;
  float* yp = y + (size_t)b*LL*DI + d;
  for (int l = 0; l < LL; l++){
    float dtv = dtp[(size_t)l*DI];
    float xcv = xcp[(size_t)l*DI];
    float zv  = zp[(size_t)l*512];
    const float* r = dbp + (size_t)l*40;
    float dx = dtv*xcv;
    float acc = Dd*xcv;
    #pragma unroll
    for (int s = 0; s < 16; s++){
      h[s] = expf(-dtv*ea[s])*h[s] + dx*r[8 + s];
      acc += h[s]*r[24 + s];
    }
    yp[(size_t)l*DI] = acc*silu_f(zv);
  }
}

// deconv stride2 k3 pad1 outpad1: (B,Ci,Li)->(B,Co,2Li). W (Ci,Co,3). block per (b,o).
__global__ __launch_bounds__(256) void k_deconv2(const float* __restrict__ x, const float* __restrict__ W,
                          const float* __restrict__ bias, float* __restrict__ y,
                          int Ci, int Co, int Li, int cs, int ts){
  __shared__ float w[384];
  int b = blockIdx.x / Co, o = blockIdx.x % Co;
  for (int j = threadIdx.x; j < Ci*3; j += 256){
    int i = j/3, k = j - 3*i;
    w[j] = W[((size_t)i*Co + o)*3 + k];
  }
  __syncthreads();
  int Lo = 2*Li;
  const float* xb = x + (size_t)b*Ci*Li;
  float bo = bias[o];
  size_t obase = ((size_t)b*Co + o)*Lo;
  for (int t = threadIdx.x; t < Lo; t += 256){
    float acc = bo;
    if ((t & 1) == 0){
      int m = t >> 1;
      for (int i = 0; i < Ci; i++) acc += w[i*3+1]*xb[(size_t)i*cs + (size_t)m*ts];
    } else {
      int m0 = t >> 1, m1 = m0 + 1;
      if (m1 < Li){
        for (int i = 0; i < Ci; i++){
          const float* xr = xb + (size_t)i*cs;
          acc += w[i*3+2]*xr[(size_t)m0*ts] + w[i*3+0]*xr[(size_t)m1*ts];
        }
      } else {
        for (int i = 0; i < Ci; i++) acc += w[i*3+2]*xb[(size_t)i*cs + (size_t)m0*ts];
      }
    }
    y[obase + t] = acc;
  }
}

__global__ __launch_bounds__(256) void k_copyf(const float* __restrict__ in, float* __restrict__ out, int n){
  int i = blockIdx.x*256 + threadIdx.x;
  if (i < n) out[i] = in[i];
}

extern "C" void kernel_launch(void* const* d_in, const int* in_sizes, int n_in,
                              void* d_out, int out_size, void* d_ws, size_t ws_size,
                              hipStream_t stream) {
  const float* x      = (const float*)d_in[0];
  const float* mask   = (const float*)d_in[1];
  const float* enc_W0 = (const float*)d_in[2];
  const float* enc_b0 = (const float*)d_in[3];
  const float* enc_g0 = (const float*)d_in[4];
  const float* enc_be0= (const float*)d_in[5];
  const float* enc_W1 = (const float*)d_in[6];
  const float* enc_b1 = (const float*)d_in[7];
  const float* enc_g1 = (const float*)d_in[8];
  const float* enc_be1= (const float*)d_in[9];
  const float* enc_W2 = (const float*)d_in[10];
  const float* enc_b2 = (const float*)d_in[11];
  const float* enc_g2 = (const float*)d_in[12];
  const float* enc_be2= (const float*)d_in[13];
  const float* ln_g   = (const float*)d_in[14];
  const float* ln_b   = (const float*)d_in[15];
  const float* in_W   = (const float*)d_in[16];
  const float* conv_W = (const float*)d_in[17];
  const float* conv_b = (const float*)d_in[18];
  const float* xp_W   = (const float*)d_in[19];
  const float* dt_W   = (const float*)d_in[20];
  const float* dt_b   = (const float*)d_in[21];
  const float* A_log  = (const float*)d_in[22];
  const float* D_p    = (const float*)d_in[23];
  const float* out_W  = (const float*)d_in[24];
  const float* nf_g   = (const float*)d_in[25];
  const float* nf_b   = (const float*)d_in[26];
  const float* dec_W0 = (const float*)d_in[27];
  const float* dec_b0 = (const float*)d_in[28];
  const float* dec_g0 = (const float*)d_in[29];
  const float* dec_be0= (const float*)d_in[30];
  const float* dec_W1 = (const float*)d_in[31];
  const float* dec_b1 = (const float*)d_in[32];
  const float* dec_g1 = (const float*)d_in[33];
  const float* dec_be1= (const float*)d_in[34];
  const float* dec_W2 = (const float*)d_in[35];
  const float* dec_b2 = (const float*)d_in[36];

  float* out = (float*)d_out;   // <<< f32 output (round-6 side-channel result)

  float* ws  = (float*)d_ws;
  float* S   = ws;                  // 1,048,576  (B,L,128)
  float* U   = S   + 1048576;       // 1,048,576  (B,L,128)
  float* XZ  = U   + 1048576;       // 4,194,304  (B,L,512)
  float* XC  = XZ  + 4194304;       // 2,097,152  (B,L,256)
  float* DBL = XC  + 2097152;       //   327,680  (B,L,40)
  float* DT  = DBL + 327680;        // 2,097,152  (B,L,256)
  float* Y   = DT  + 2097152;       // 2,097,152  (B,L,256)
  float* EB0 = XZ;                  // encoder/decoder scratch (<=1M each)
  float* EB1 = XZ + 1048576;
  float* H0  = DT;                  // masked input (131,072), DT dead here

  // ---------------- encoder ----------------
  k_maskmul<<<512, 256, 0, stream>>>(x, mask, H0, NB*2*TT);
  k_conv2<<<16*32, 256, 0, stream>>>(H0, enc_W0, enc_b0, EB0, 2, 32, 4096);
  k_gn_gelu2<<<16, 256, 0, stream>>>(EB0, enc_g0, enc_be0, 32, 2048);
  k_conv2<<<16*64, 256, 0, stream>>>(EB0, enc_W1, enc_b1, EB1, 32, 64, 2048);
  k_gn_gelu2<<<16, 256, 0, stream>>>(EB1, enc_g1, enc_be1, 64, 1024);
  k_conv2<<<16*128, 256, 0, stream>>>(EB1, enc_W2, enc_b2, EB0, 64, 128, 1024);
  k_gn_gelu2<<<16, 256, 0, stream>>>(EB0, enc_g2, enc_be2, 128, 512);
  k_transpose2<<<4096, 256, 0, stream>>>(EB0, S);

  // ---------------- mamba layers ----------------
  const int rows = NB*LL; // 8192
  for (int i = 0; i < NLAYER; i++){
    k_ln2<<<2048, 256, 0, stream>>>(S, ln_g + i*DM, ln_b + i*DM, U, rows);
    k_gemm_naive<0><<<dim3(rows, 2), 256, 0, stream>>>(U, in_W + (size_t)i*512*DM, XZ, 512, DM, DM);
    k_cconv2<<<8192, 256, 0, stream>>>(XZ, conv_W + (size_t)i*DI*4, conv_b + (size_t)i*DI, XC);
    k_gemm_naive<0><<<dim3(rows, 1), 256, 0, stream>>>(XC, xp_W + (size_t)i*40*DI, DBL, 40, DI, DI);
    k_dt2<<<8192, 256, 0, stream>>>(DBL, dt_W + (size_t)i*DI*8, dt_b + (size_t)i*DI, DT);
    k_scan2<<<16, 256, 0, stream>>>(DT, XC, DBL, XZ,
                                    A_log + (size_t)i*DI*16, D_p + (size_t)i*DI, Y);
    k_gemm_naive<1><<<dim3(rows, 1), 256, 0, stream>>>(Y, out_W + (size_t)i*DM*DI, S, DM, DI, DI);
  }

  // ---------------- decoder ----------------
  k_ln2<<<2048, 256, 0, stream>>>(S, nf_g, nf_b, U, rows);
  // U is (b,t,c): elem (b,i,m) at U[b*65536 + m*128 + i] -> cs=1, ts=128
  k_deconv2<<<16*64, 256, 0, stream>>>(U, dec_W0, dec_b0, EB0, 128, 64, 512, 1, 128);
  k_gn_gelu2<<<16, 256, 0, stream>>>(EB0, dec_g0, dec_be0, 64, 1024);
  k_deconv2<<<16*32, 256, 0, stream>>>(EB0, dec_W1, dec_b1, EB1, 64, 32, 1024, 1024, 1);
  k_gn_gelu2<<<16, 256, 0, stream>>>(EB1, dec_g1, dec_be1, 32, 2048);
  k_deconv2<<<16*2, 256, 0, stream>>>(EB1, dec_W2, dec_b2, out, 32, 2, 2048, 2048, 1);

  // echoes (f32)
  k_copyf<<<512, 256, 0, stream>>>(x,    out + 131072, 131072);
  k_copyf<<<512, 256, 0, stream>>>(mask, out + 262144, 131072);
}

// Round 8
// 4329.985 us; speedup vs baseline: 4.9572x; 4.9572x over previous
//
#include <hip/hip_runtime.h>
#include <hip/hip_bf16.h>
#include <math.h>

#define NB 16
#define TT 4096
#define LL 512
#define DM 128
#define DI 256
#define NLAYER 6

static __device__ __forceinline__ float gelu_f(float v){
  return 0.5f*v*(1.f + erff(v*0.70710678118654752f));
}
static __device__ __forceinline__ float silu_f(float v){
  return v/(1.f + expf(-v));
}

__global__ __launch_bounds__(256) void k_maskmul(const float* __restrict__ x, const float* __restrict__ m,
                          float* __restrict__ out, int n){
  int i = blockIdx.x*256 + threadIdx.x;
  if (i < n) out[i] = x[i]*m[i];
}

// conv1d stride2 pad1 k3: (B,Ci,Li)->(B,Co,Li/2). block per (b,o). W (Co,Ci,3).
__global__ __launch_bounds__(256) void k_conv2(const float* __restrict__ x, const float* __restrict__ W,
                        const float* __restrict__ bias, float* __restrict__ y,
                        int Ci, int Co, int Li){
  __shared__ float w[192];
  int b = blockIdx.x / Co, o = blockIdx.x % Co;
  for (int j = threadIdx.x; j < Ci*3; j += 256) w[j] = W[(size_t)o*Ci*3 + j];
  __syncthreads();
  int Lo = Li >> 1;
  const float* xb = x + (size_t)b*Ci*Li;
  float bo = bias[o];
  float* yo = y + ((size_t)b*Co + o)*Lo;
  for (int t = threadIdx.x; t < Lo; t += 256){
    int tin = 2*t - 1;
    float acc = bo;
    for (int ci = 0; ci < Ci; ci++){
      const float* xr = xb + (size_t)ci*Li;
      float v0 = (tin >= 0) ? xr[tin] : 0.f;
      acc += w[ci*3+0]*v0 + w[ci*3+1]*xr[tin+1] + w[ci*3+2]*xr[tin+2];
    }
    yo[t] = acc;
  }
}

// GroupNorm(1 group) over (C,T) per batch, two-pass, then exact GELU. in-place.
__global__ __launch_bounds__(256) void k_gn_gelu2(float* __restrict__ x, const float* __restrict__ g,
                           const float* __restrict__ be, int C, int Tl){
  __shared__ float sh[4];
  __shared__ float bc;
  int b = blockIdx.x;
  int n = C*Tl;
  float* xb = x + (size_t)b*n;
  float s = 0.f;
  for (int i = threadIdx.x; i < n; i += 256) s += xb[i];
  #pragma unroll
  for (int o = 32; o; o >>= 1) s += __shfl_down(s, o);
  if ((threadIdx.x & 63) == 0) sh[threadIdx.x >> 6] = s;
  __syncthreads();
  if (threadIdx.x == 0) bc = (sh[0]+sh[1]+sh[2]+sh[3])/(float)n;
  __syncthreads();
  float mean = bc;
  float s2 = 0.f;
  for (int i = threadIdx.x; i < n; i += 256){ float d = xb[i]-mean; s2 += d*d; }
  #pragma unroll
  for (int o = 32; o; o >>= 1) s2 += __shfl_down(s2, o);
  __syncthreads();
  if ((threadIdx.x & 63) == 0) sh[threadIdx.x >> 6] = s2;
  __syncthreads();
  if (threadIdx.x == 0) bc = rsqrtf((sh[0]+sh[1]+sh[2]+sh[3])/(float)n + 1e-5f);
  __syncthreads();
  float inv = bc;
  for (int i = threadIdx.x; i < n; i += 256){
    int c = i / Tl;
    float v = (xb[i]-mean)*inv*g[c] + be[c];
    xb[i] = gelu_f(v);
  }
}

// (B,128,512) NCH -> (B,512,128) BLD.
__global__ __launch_bounds__(256) void k_transpose2(const float* __restrict__ in, float* __restrict__ out){
  int idx = blockIdx.x*256 + threadIdx.x;
  if (idx >= NB*DM*LL) return;
  int t = idx & 511;
  int c = (idx >> 9) & 127;
  int b = idx >> 16;
  out[(size_t)b*65536 + (size_t)t*128 + c] = in[idx];
}

// LayerNorm last-dim(128), one wave per row.
__global__ __launch_bounds__(256) void k_ln2(const float* __restrict__ x, const float* __restrict__ g,
                      const float* __restrict__ be, float* __restrict__ out, int rows){
  int row = blockIdx.x*4 + (threadIdx.x >> 6);
  if (row >= rows) return;
  int lid = threadIdx.x & 63;
  const float* xr = x + (size_t)row*DM;
  float v0 = xr[lid], v1 = xr[lid+64];
  float s = v0 + v1;
  #pragma unroll
  for (int o = 32; o; o >>= 1) s += __shfl_xor(s, o);
  float mean = s*(1.f/128.f);
  float d0 = v0-mean, d1 = v1-mean;
  float s2 = d0*d0 + d1*d1;
  #pragma unroll
  for (int o = 32; o; o >>= 1) s2 += __shfl_xor(s2, o);
  float inv = rsqrtf(s2*(1.f/128.f) + 1e-5f);
  float* orow = out + (size_t)row*DM;
  orow[lid]    = d0*inv*g[lid]    + be[lid];
  orow[lid+64] = d1*inv*g[lid+64] + be[lid+64];
}

// C[M,N] (+)= A[M,K](row stride lda) * B[N,K]^T. 64x64 tile, BK=16, 4x4/thread.
// M must be multiple of 64, K multiple of 16. N guarded.
template<int ACCUM>
__global__ __launch_bounds__(256) void k_gemm_nt(const float* __restrict__ A, const float* __restrict__ B,
                          float* __restrict__ C, int M, int N, int K, int lda){
  __shared__ float As[64][17];
  __shared__ float Bs[64][17];
  int tx = threadIdx.x & 15, ty = threadIdx.x >> 4;
  int m0 = blockIdx.y*64, n0 = blockIdx.x*64;
  int lr = threadIdx.x >> 2;
  int lc = (threadIdx.x & 3)*4;
  float acc[4][4] = {};
  for (int k0 = 0; k0 < K; k0 += 16){
    float4 av = *(const float4*)(A + (size_t)(m0+lr)*lda + k0 + lc);
    As[lr][lc+0]=av.x; As[lr][lc+1]=av.y; As[lr][lc+2]=av.z; As[lr][lc+3]=av.w;
    float4 bv = make_float4(0.f,0.f,0.f,0.f);
    if (n0+lr < N) bv = *(const float4*)(B + (size_t)(n0+lr)*K + k0 + lc);
    Bs[lr][lc+0]=bv.x; Bs[lr][lc+1]=bv.y; Bs[lr][lc+2]=bv.z; Bs[lr][lc+3]=bv.w;
    __syncthreads();
    #pragma unroll
    for (int k = 0; k < 16; k++){
      float a[4], bb[4];
      #pragma unroll
      for (int i = 0; i < 4; i++) a[i]  = As[ty*4+i][k];
      #pragma unroll
      for (int j = 0; j < 4; j++) bb[j] = Bs[tx*4+j][k];
      #pragma unroll
      for (int i = 0; i < 4; i++)
        #pragma unroll
        for (int j = 0; j < 4; j++) acc[i][j] += a[i]*bb[j];
    }
    __syncthreads();
  }
  #pragma unroll
  for (int i = 0; i < 4; i++){
    int m = m0 + ty*4 + i;
    #pragma unroll
    for (int j = 0; j < 4; j++){
      int n = n0 + tx*4 + j;
      if (n < N){
        size_t off = (size_t)m*N + n;
        C[off] = (ACCUM ? C[off] : 0.f) + acc[i][j];
      }
    }
  }
}

// depthwise causal conv k=4 over xi=XZ[...,:256], +bias, SiLU -> XC (B,L,256)
__global__ __launch_bounds__(256) void k_cconv2(const float* __restrict__ xz, const float* __restrict__ cw,
                         const float* __restrict__ cb, float* __restrict__ xc){
  int idx = blockIdx.x*256 + threadIdx.x;
  if (idx >= NB*LL*DI) return;
  int d = idx & 255;
  int l = (idx >> 8) & 511;
  int b = idx >> 17;
  const float* xi = xz + (size_t)b*262144 + d;
  float acc = cb[d];
  #pragma unroll
  for (int j = 0; j < 4; j++){
    int m = l - 3 + j;
    if (m >= 0) acc += xi[(size_t)m*512]*cw[d*4 + j];
  }
  xc[idx] = silu_f(acc);
}

// dt[row,d] = softplus(dt_b[d] + sum_r dbl[row*40+r]*dt_W[d*8+r])
__global__ __launch_bounds__(256) void k_dt2(const float* __restrict__ dbl, const float* __restrict__ dtW,
                      const float* __restrict__ dtb, float* __restrict__ dt){
  int idx = blockIdx.x*256 + threadIdx.x;
  if (idx >= NB*LL*DI) return;
  int d = idx & 255;
  int row = idx >> 8;
  const float* r = dbl + (size_t)row*40;
  float acc = dtb[d];
  #pragma unroll
  for (int j = 0; j < 8; j++) acc += r[j]*dtW[d*8 + j];
  dt[idx] = (acc > 20.f) ? acc : log1pf(expf(acc));
}

// scan: 16 lanes per (b,d), lane = state s. 65536 threads.
__global__ __launch_bounds__(256) void k_scan16(const float* __restrict__ dt, const float* __restrict__ xc,
                        const float* __restrict__ dbl, const float* __restrict__ xz,
                        const float* __restrict__ Alog, const float* __restrict__ Dp,
                        float* __restrict__ y){
  int gidx = blockIdx.x*16 + (threadIdx.x >> 4);  // (b,d) in [0,4096)
  int s = threadIdx.x & 15;
  int b = gidx >> 8;
  int d = gidx & 255;
  float a  = -expf(Alog[d*16 + s]);
  float Dd = Dp[d];
  float h = 0.f;
  const float* dtp = dt + (size_t)b*LL*DI + d;
  const float* xcp = xc + (size_t)b*LL*DI + d;
  const float* zp  = xz + (size_t)b*262144 + 256 + d;
  const float* dbp = dbl + (size_t)b*LL*40;
  float* yp = y + (size_t)b*LL*DI + d;
  for (int l = 0; l < LL; l++){
    float dtv = dtp[(size_t)l*DI];
    float xcv = xcp[(size_t)l*DI];
    float bm  = dbp[l*40 + 8 + s];
    float cm  = dbp[l*40 + 24 + s];
    h = expf(dtv*a)*h + dtv*bm*xcv;
    float p = h*cm;
    p += __shfl_xor(p, 1); p += __shfl_xor(p, 2);
    p += __shfl_xor(p, 4); p += __shfl_xor(p, 8);
    if (s == 0){
      float zv = zp[(size_t)l*512];
      yp[(size_t)l*DI] = (p + Dd*xcv)*silu_f(zv);
    }
  }
}

// deconv stride2 k3 pad1 outpad1: (B,Ci,Li)->(B,Co,2Li). W (Ci,Co,3). block per (b,o).
__global__ __launch_bounds__(256) void k_deconv2(const float* __restrict__ x, const float* __restrict__ W,
                          const float* __restrict__ bias, float* __restrict__ y,
                          int Ci, int Co, int Li, int cs, int ts){
  __shared__ float w[384];
  int b = blockIdx.x / Co, o = blockIdx.x % Co;
  for (int j = threadIdx.x; j < Ci*3; j += 256){
    int i = j/3, k = j - 3*i;
    w[j] = W[((size_t)i*Co + o)*3 + k];
  }
  __syncthreads();
  int Lo = 2*Li;
  const float* xb = x + (size_t)b*Ci*Li;
  float bo = bias[o];
  size_t obase = ((size_t)b*Co + o)*Lo;
  for (int t = threadIdx.x; t < Lo; t += 256){
    float acc = bo;
    if ((t & 1) == 0){
      int m = t >> 1;
      for (int i = 0; i < Ci; i++) acc += w[i*3+1]*xb[(size_t)i*cs + (size_t)m*ts];
    } else {
      int m0 = t >> 1, m1 = m0 + 1;
      if (m1 < Li){
        for (int i = 0; i < Ci; i++){
          const float* xr = xb + (size_t)i*cs;
          acc += w[i*3+2]*xr[(size_t)m0*ts] + w[i*3+0]*xr[(size_t)m1*ts];
        }
      } else {
        for (int i = 0; i < Ci; i++) acc += w[i*3+2]*xb[(size_t)i*cs + (size_t)m0*ts];
      }
    }
    y[obase + t] = acc;
  }
}

__global__ __launch_bounds__(256) void k_copyf(const float* __restrict__ in, float* __restrict__ out, int n){
  int i = blockIdx.x*256 + threadIdx.x;
  if (i < n) out[i] = in[i];
}

extern "C" void kernel_launch(void* const* d_in, const int* in_sizes, int n_in,
                              void* d_out, int out_size, void* d_ws, size_t ws_size,
                              hipStream_t stream) {
  const float* x      = (const float*)d_in[0];
  const float* mask   = (const float*)d_in[1];
  const float* enc_W0 = (const float*)d_in[2];
  const float* enc_b0 = (const float*)d_in[3];
  const float* enc_g0 = (const float*)d_in[4];
  const float* enc_be0= (const float*)d_in[5];
  const float* enc_W1 = (const float*)d_in[6];
  const float* enc_b1 = (const float*)d_in[7];
  const float* enc_g1 = (const float*)d_in[8];
  const float* enc_be1= (const float*)d_in[9];
  const float* enc_W2 = (const float*)d_in[10];
  const float* enc_b2 = (const float*)d_in[11];
  const float* enc_g2 = (const float*)d_in[12];
  const float* enc_be2= (const float*)d_in[13];
  const float* ln_g   = (const float*)d_in[14];
  const float* ln_b   = (const float*)d_in[15];
  const float* in_W   = (const float*)d_in[16];
  const float* conv_W = (const float*)d_in[17];
  const float* conv_b = (const float*)d_in[18];
  const float* xp_W   = (const float*)d_in[19];
  const float* dt_W   = (const float*)d_in[20];
  const float* dt_b   = (const float*)d_in[21];
  const float* A_log  = (const float*)d_in[22];
  const float* D_p    = (const float*)d_in[23];
  const float* out_W  = (const float*)d_in[24];
  const float* nf_g   = (const float*)d_in[25];
  const float* nf_b   = (const float*)d_in[26];
  const float* dec_W0 = (const float*)d_in[27];
  const float* dec_b0 = (const float*)d_in[28];
  const float* dec_g0 = (const float*)d_in[29];
  const float* dec_be0= (const float*)d_in[30];
  const float* dec_W1 = (const float*)d_in[31];
  const float* dec_b1 = (const float*)d_in[32];
  const float* dec_g1 = (const float*)d_in[33];
  const float* dec_be1= (const float*)d_in[34];
  const float* dec_W2 = (const float*)d_in[35];
  const float* dec_b2 = (const float*)d_in[36];

  float* out = (float*)d_out;

  float* ws  = (float*)d_ws;
  float* S   = ws;                  // 1,048,576  (B,L,128)
  float* U   = S   + 1048576;       // 1,048,576  (B,L,128)
  float* XZ  = U   + 1048576;       // 4,194,304  (B,L,512)
  float* XC  = XZ  + 4194304;       // 2,097,152  (B,L,256)
  float* DBL = XC  + 2097152;       //   327,680  (B,L,40)
  float* DT  = DBL + 327680;        // 2,097,152  (B,L,256)
  float* Y   = DT  + 2097152;       // 2,097,152  (B,L,256)
  float* EB0 = XZ;                  // encoder/decoder scratch (<=1M each)
  float* EB1 = XZ + 1048576;
  float* H0  = DT;                  // masked input (131,072), DT dead here

  // ---------------- encoder ----------------
  k_maskmul<<<512, 256, 0, stream>>>(x, mask, H0, NB*2*TT);
  k_conv2<<<16*32, 256, 0, stream>>>(H0, enc_W0, enc_b0, EB0, 2, 32, 4096);
  k_gn_gelu2<<<16, 256, 0, stream>>>(EB0, enc_g0, enc_be0, 32, 2048);
  k_conv2<<<16*64, 256, 0, stream>>>(EB0, enc_W1, enc_b1, EB1, 32, 64, 2048);
  k_gn_gelu2<<<16, 256, 0, stream>>>(EB1, enc_g1, enc_be1, 64, 1024);
  k_conv2<<<16*128, 256, 0, stream>>>(EB1, enc_W2, enc_b2, EB0, 64, 128, 1024);
  k_gn_gelu2<<<16, 256, 0, stream>>>(EB0, enc_g2, enc_be2, 128, 512);
  k_transpose2<<<4096, 256, 0, stream>>>(EB0, S);

  // ---------------- mamba layers ----------------
  const int rows = NB*LL; // 8192
  for (int i = 0; i < NLAYER; i++){
    k_ln2<<<2048, 256, 0, stream>>>(S, ln_g + i*DM, ln_b + i*DM, U, rows);
    k_gemm_nt<0><<<dim3(8, 128), 256, 0, stream>>>(U, in_W + (size_t)i*512*DM, XZ, rows, 512, DM, DM);
    k_cconv2<<<8192, 256, 0, stream>>>(XZ, conv_W + (size_t)i*DI*4, conv_b + (size_t)i*DI, XC);
    k_gemm_nt<0><<<dim3(1, 128), 256, 0, stream>>>(XC, xp_W + (size_t)i*40*DI, DBL, rows, 40, DI, DI);
    k_dt2<<<8192, 256, 0, stream>>>(DBL, dt_W + (size_t)i*DI*8, dt_b + (size_t)i*DI, DT);
    k_scan16<<<256, 256, 0, stream>>>(DT, XC, DBL, XZ,
                                      A_log + (size_t)i*DI*16, D_p + (size_t)i*DI, Y);
    k_gemm_nt<1><<<dim3(2, 128), 256, 0, stream>>>(Y, out_W + (size_t)i*DM*DI, S, rows, DM, DI, DI);
  }

  // ---------------- decoder ----------------
  k_ln2<<<2048, 256, 0, stream>>>(S, nf_g, nf_b, U, rows);
  // U is (b,t,c): elem (b,i,m) at U[b*65536 + m*128 + i] -> cs=1, ts=128
  k_deconv2<<<16*64, 256, 0, stream>>>(U, dec_W0, dec_b0, EB0, 128, 64, 512, 1, 128);
  k_gn_gelu2<<<16, 256, 0, stream>>>(EB0, dec_g0, dec_be0, 64, 1024);
  k_deconv2<<<16*32, 256, 0, stream>>>(EB0, dec_W1, dec_b1, EB1, 64, 32, 1024, 1024, 1);
  k_gn_gelu2<<<16, 256, 0, stream>>>(EB1, dec_g1, dec_be1, 32, 2048);
  k_deconv2<<<16*2, 256, 0, stream>>>(EB1, dec_W2, dec_b2, out, 32, 2, 2048, 2048, 1);

  // echoes (f32)
  k_copyf<<<512, 256, 0, stream>>>(x,    out + 131072, 131072);
  k_copyf<<<512, 256, 0, stream>>>(mask, out + 262144, 131072);
}

// Round 9
// 3960.178 us; speedup vs baseline: 5.4202x; 1.0934x over previous
//
#include <hip/hip_runtime.h>
#include <hip/hip_bf16.h>
#include <math.h>

#define NB 16
#define TT 4096
#define LL 512
#define DM 128
#define DI 256
#define NLAYER 6

static __device__ __forceinline__ float gelu_f(float v){
  return 0.5f*v*(1.f + erff(v*0.70710678118654752f));
}
static __device__ __forceinline__ float silu_f(float v){
  return v/(1.f + __expf(-v));
}

__global__ __launch_bounds__(256) void k_maskmul(const float* __restrict__ x, const float* __restrict__ m,
                          float* __restrict__ out, int n){
  int i = blockIdx.x*256 + threadIdx.x;
  if (i < n) out[i] = x[i]*m[i];
}

// conv1d stride2 pad1 k3: (B,Ci,Li)->(B,Co,Li/2). block per (b,o). W (Co,Ci,3).
__global__ __launch_bounds__(256) void k_conv2(const float* __restrict__ x, const float* __restrict__ W,
                        const float* __restrict__ bias, float* __restrict__ y,
                        int Ci, int Co, int Li){
  __shared__ float w[192];
  int b = blockIdx.x / Co, o = blockIdx.x % Co;
  for (int j = threadIdx.x; j < Ci*3; j += 256) w[j] = W[(size_t)o*Ci*3 + j];
  __syncthreads();
  int Lo = Li >> 1;
  const float* xb = x + (size_t)b*Ci*Li;
  float bo = bias[o];
  float* yo = y + ((size_t)b*Co + o)*Lo;
  for (int t = threadIdx.x; t < Lo; t += 256){
    int tin = 2*t - 1;
    float acc = bo;
    for (int ci = 0; ci < Ci; ci++){
      const float* xr = xb + (size_t)ci*Li;
      float v0 = (tin >= 0) ? xr[tin] : 0.f;
      acc += w[ci*3+0]*v0 + w[ci*3+1]*xr[tin+1] + w[ci*3+2]*xr[tin+2];
    }
    yo[t] = acc;
  }
}

// GroupNorm(1 group) over (C,T) per batch, two-pass, then exact GELU. in-place. 1024 thr.
__global__ __launch_bounds__(1024) void k_gn_gelu2(float* __restrict__ x, const float* __restrict__ g,
                           const float* __restrict__ be, int C, int Tl){
  __shared__ float sh[16];
  __shared__ float bc;
  int b = blockIdx.x;
  int n = C*Tl;
  float* xb = x + (size_t)b*n;
  float s = 0.f;
  for (int i = threadIdx.x; i < n; i += 1024) s += xb[i];
  #pragma unroll
  for (int o = 32; o; o >>= 1) s += __shfl_down(s, o);
  if ((threadIdx.x & 63) == 0) sh[threadIdx.x >> 6] = s;
  __syncthreads();
  if (threadIdx.x == 0){
    float a = 0.f;
    #pragma unroll
    for (int k = 0; k < 16; k++) a += sh[k];
    bc = a/(float)n;
  }
  __syncthreads();
  float mean = bc;
  float s2 = 0.f;
  for (int i = threadIdx.x; i < n; i += 1024){ float d = xb[i]-mean; s2 += d*d; }
  #pragma unroll
  for (int o = 32; o; o >>= 1) s2 += __shfl_down(s2, o);
  __syncthreads();
  if ((threadIdx.x & 63) == 0) sh[threadIdx.x >> 6] = s2;
  __syncthreads();
  if (threadIdx.x == 0){
    float a = 0.f;
    #pragma unroll
    for (int k = 0; k < 16; k++) a += sh[k];
    bc = rsqrtf(a/(float)n + 1e-5f);
  }
  __syncthreads();
  float inv = bc;
  for (int i = threadIdx.x; i < n; i += 1024){
    int c = i / Tl;
    float v = (xb[i]-mean)*inv*g[c] + be[c];
    xb[i] = gelu_f(v);
  }
}

// (B,128,512) NCH -> (B,512,128) BLD.
__global__ __launch_bounds__(256) void k_transpose2(const float* __restrict__ in, float* __restrict__ out){
  int idx = blockIdx.x*256 + threadIdx.x;
  if (idx >= NB*DM*LL) return;
  int t = idx & 511;
  int c = (idx >> 9) & 127;
  int b = idx >> 16;
  out[(size_t)b*65536 + (size_t)t*128 + c] = in[idx];
}

// (B,512,128) BLD -> (B,128,512) NCH. idx enumerates OUTPUT (coalesced writes).
__global__ __launch_bounds__(256) void k_transposeB(const float* __restrict__ in, float* __restrict__ out){
  int idx = blockIdx.x*256 + threadIdx.x;
  if (idx >= NB*DM*LL) return;
  int m = idx & 511;
  int c = (idx >> 9) & 127;
  int b = idx >> 16;
  out[idx] = in[(size_t)b*65536 + (size_t)m*128 + c];
}

// LayerNorm last-dim(128), one wave per row.
__global__ __launch_bounds__(256) void k_ln2(const float* __restrict__ x, const float* __restrict__ g,
                      const float* __restrict__ be, float* __restrict__ out, int rows){
  int row = blockIdx.x*4 + (threadIdx.x >> 6);
  if (row >= rows) return;
  int lid = threadIdx.x & 63;
  const float* xr = x + (size_t)row*DM;
  float v0 = xr[lid], v1 = xr[lid+64];
  float s = v0 + v1;
  #pragma unroll
  for (int o = 32; o; o >>= 1) s += __shfl_xor(s, o);
  float mean = s*(1.f/128.f);
  float d0 = v0-mean, d1 = v1-mean;
  float s2 = d0*d0 + d1*d1;
  #pragma unroll
  for (int o = 32; o; o >>= 1) s2 += __shfl_xor(s2, o);
  float inv = rsqrtf(s2*(1.f/128.f) + 1e-5f);
  float* orow = out + (size_t)row*DM;
  orow[lid]    = d0*inv*g[lid]    + be[lid];
  orow[lid+64] = d1*inv*g[lid+64] + be[lid+64];
}

// C[M,N] (+)= A[M,K](row stride lda) * B[N,K]^T. 64x64 tile, BK=16, 4x4/thread.
template<int ACCUM>
__global__ __launch_bounds__(256) void k_gemm_nt(const float* __restrict__ A, const float* __restrict__ B,
                          float* __restrict__ C, int M, int N, int K, int lda){
  __shared__ float As[64][17];
  __shared__ float Bs[64][17];
  int tx = threadIdx.x & 15, ty = threadIdx.x >> 4;
  int m0 = blockIdx.y*64, n0 = blockIdx.x*64;
  int lr = threadIdx.x >> 2;
  int lc = (threadIdx.x & 3)*4;
  float acc[4][4] = {};
  for (int k0 = 0; k0 < K; k0 += 16){
    float4 av = *(const float4*)(A + (size_t)(m0+lr)*lda + k0 + lc);
    As[lr][lc+0]=av.x; As[lr][lc+1]=av.y; As[lr][lc+2]=av.z; As[lr][lc+3]=av.w;
    float4 bv = make_float4(0.f,0.f,0.f,0.f);
    if (n0+lr < N) bv = *(const float4*)(B + (size_t)(n0+lr)*K + k0 + lc);
    Bs[lr][lc+0]=bv.x; Bs[lr][lc+1]=bv.y; Bs[lr][lc+2]=bv.z; Bs[lr][lc+3]=bv.w;
    __syncthreads();
    #pragma unroll
    for (int k = 0; k < 16; k++){
      float a[4], bb[4];
      #pragma unroll
      for (int i = 0; i < 4; i++) a[i]  = As[ty*4+i][k];
      #pragma unroll
      for (int j = 0; j < 4; j++) bb[j] = Bs[tx*4+j][k];
      #pragma unroll
      for (int i = 0; i < 4; i++)
        #pragma unroll
        for (int j = 0; j < 4; j++) acc[i][j] += a[i]*bb[j];
    }
    __syncthreads();
  }
  #pragma unroll
  for (int i = 0; i < 4; i++){
    int m = m0 + ty*4 + i;
    #pragma unroll
    for (int j = 0; j < 4; j++){
      int n = n0 + tx*4 + j;
      if (n < N){
        size_t off = (size_t)m*N + n;
        C[off] = (ACCUM ? C[off] : 0.f) + acc[i][j];
      }
    }
  }
}

// depthwise causal conv k=4 over xi=XZ[...,:256], +bias, SiLU -> XC (B,L,256)
__global__ __launch_bounds__(256) void k_cconv2(const float* __restrict__ xz, const float* __restrict__ cw,
                         const float* __restrict__ cb, float* __restrict__ xc){
  int idx = blockIdx.x*256 + threadIdx.x;
  if (idx >= NB*LL*DI) return;
  int d = idx & 255;
  int l = (idx >> 8) & 511;
  int b = idx >> 17;
  const float* xi = xz + (size_t)b*262144 + d;
  float acc = cb[d];
  #pragma unroll
  for (int j = 0; j < 4; j++){
    int m = l - 3 + j;
    if (m >= 0) acc += xi[(size_t)m*512]*cw[d*4 + j];
  }
  xc[idx] = silu_f(acc);
}

// fused scan: dt-softplus GEMV + recurrence. 16 lanes per (b,d), lane = state s.
// Critical chain is h = e*h + dbx (one FMA); e/dbx computed in prefetch stage.
__global__ __launch_bounds__(256) void k_scanf(const float* __restrict__ xc,
                        const float* __restrict__ dbl, const float* __restrict__ xz,
                        const float* __restrict__ dtW, const float* __restrict__ dtb,
                        const float* __restrict__ Alog, const float* __restrict__ Dp,
                        float* __restrict__ y){
  int gidx = blockIdx.x*16 + (threadIdx.x >> 4);  // (b,d) in [0,4096)
  int s = threadIdx.x & 15;
  int b = gidx >> 8;
  int d = gidx & 255;
  float a  = -__expf(Alog[d*16 + s]);
  float Dd = Dp[d];
  float w[8];
  #pragma unroll
  for (int j = 0; j < 8; j++) w[j] = dtW[d*8 + j];
  float tb = dtb[d];
  const float* xcp = xc + (size_t)b*131072 + d;   // LL*DI
  const float* dbp = dbl + (size_t)b*20480;       // LL*40
  const float* zp  = xz + (size_t)b*262144 + 256 + d;
  float* yp = y + (size_t)b*131072 + d;

  // prefetch l=0 and fold into e/dbx form
  float xcv, e, dbx, cm;
  {
    float raw = tb;
    #pragma unroll
    for (int j = 0; j < 8; j++) raw += dbp[j]*w[j];
    float dtv = (raw > 20.f) ? raw : log1pf(__expf(raw));
    xcv = xcp[0];
    float bm = dbp[8 + s];
    cm = dbp[24 + s];
    e   = __expf(dtv*a);
    dbx = dtv*bm*xcv;
  }
  float h = 0.f;
  for (int l = 0; l < LL; l++){
    // ---- prefetch + off-chain math for l+1 ----
    float xcv_n = 0.f, e_n = 0.f, dbx_n = 0.f, cm_n = 0.f;
    if (l + 1 < LL){
      const float* r = dbp + (l+1)*40;
      float raw = tb;
      #pragma unroll
      for (int j = 0; j < 8; j++) raw += r[j]*w[j];
      float dtv = (raw > 20.f) ? raw : log1pf(__expf(raw));
      xcv_n = xcp[(size_t)(l+1)*DI];
      float bm = r[8 + s];
      cm_n = r[24 + s];
      e_n   = __expf(dtv*a);
      dbx_n = dtv*bm*xcv_n;
    }
    // ---- serial recurrence (single FMA on the chain) ----
    h = e*h + dbx;
    float p = h*cm;
    p += __shfl_xor(p, 1); p += __shfl_xor(p, 2);
    p += __shfl_xor(p, 4); p += __shfl_xor(p, 8);
    float zv = zp[(size_t)l*512];
    if (s == 0){
      yp[(size_t)l*DI] = (p + Dd*xcv)*silu_f(zv);
    }
    xcv = xcv_n; e = e_n; dbx = dbx_n; cm = cm_n;
  }
}

// deconv stride2 k3 pad1 outpad1: (B,Ci,Li)->(B,Co,2Li). W (Ci,Co,3). block per (b,o).
__global__ __launch_bounds__(256) void k_deconv2(const float* __restrict__ x, const float* __restrict__ W,
                          const float* __restrict__ bias, float* __restrict__ y,
                          int Ci, int Co, int Li, int cs, int ts){
  __shared__ float w[384];
  int b = blockIdx.x / Co, o = blockIdx.x % Co;
  for (int j = threadIdx.x; j < Ci*3; j += 256){
    int i = j/3, k = j - 3*i;
    w[j] = W[((size_t)i*Co + o)*3 + k];
  }
  __syncthreads();
  int Lo = 2*Li;
  const float* xb = x + (size_t)b*Ci*Li;
  float bo = bias[o];
  size_t obase = ((size_t)b*Co + o)*Lo;
  for (int t = threadIdx.x; t < Lo; t += 256){
    float acc = bo;
    if ((t & 1) == 0){
      int m = t >> 1;
      for (int i = 0; i < Ci; i++) acc += w[i*3+1]*xb[(size_t)i*cs + (size_t)m*ts];
    } else {
      int m0 = t >> 1, m1 = m0 + 1;
      if (m1 < Li){
        for (int i = 0; i < Ci; i++){
          const float* xr = xb + (size_t)i*cs;
          acc += w[i*3+2]*xr[(size_t)m0*ts] + w[i*3+0]*xr[(size_t)m1*ts];
        }
      } else {
        for (int i = 0; i < Ci; i++) acc += w[i*3+2]*xb[(size_t)i*cs + (size_t)m0*ts];
      }
    }
    y[obase + t] = acc;
  }
}

__global__ __launch_bounds__(256) void k_copyf(const float* __restrict__ in, float* __restrict__ out, int n){
  int i = blockIdx.x*256 + threadIdx.x;
  if (i < n) out[i] = in[i];
}

extern "C" void kernel_launch(void* const* d_in, const int* in_sizes, int n_in,
                              void* d_out, int out_size, void* d_ws, size_t ws_size,
                              hipStream_t stream) {
  const float* x      = (const float*)d_in[0];
  const float* mask   = (const float*)d_in[1];
  const float* enc_W0 = (const float*)d_in[2];
  const float* enc_b0 = (const float*)d_in[3];
  const float* enc_g0 = (const float*)d_in[4];
  const float* enc_be0= (const float*)d_in[5];
  const float* enc_W1 = (const float*)d_in[6];
  const float* enc_b1 = (const float*)d_in[7];
  const float* enc_g1 = (const float*)d_in[8];
  const float* enc_be1= (const float*)d_in[9];
  const float* enc_W2 = (const float*)d_in[10];
  const float* enc_b2 = (const float*)d_in[11];
  const float* enc_g2 = (const float*)d_in[12];
  const float* enc_be2= (const float*)d_in[13];
  const float* ln_g   = (const float*)d_in[14];
  const float* ln_b   = (const float*)d_in[15];
  const float* in_W   = (const float*)d_in[16];
  const float* conv_W = (const float*)d_in[17];
  const float* conv_b = (const float*)d_in[18];
  const float* xp_W   = (const float*)d_in[19];
  const float* dt_W   = (const float*)d_in[20];
  const float* dt_b   = (const float*)d_in[21];
  const float* A_log  = (const float*)d_in[22];
  const float* D_p    = (const float*)d_in[23];
  const float* out_W  = (const float*)d_in[24];
  const float* nf_g   = (const float*)d_in[25];
  const float* nf_b   = (const float*)d_in[26];
  const float* dec_W0 = (const float*)d_in[27];
  const float* dec_b0 = (const float*)d_in[28];
  const float* dec_g0 = (const float*)d_in[29];
  const float* dec_be0= (const float*)d_in[30];
  const float* dec_W1 = (const float*)d_in[31];
  const float* dec_b1 = (const float*)d_in[32];
  const float* dec_g1 = (const float*)d_in[33];
  const float* dec_be1= (const float*)d_in[34];
  const float* dec_W2 = (const float*)d_in[35];
  const float* dec_b2 = (const float*)d_in[36];

  float* out = (float*)d_out;

  float* ws  = (float*)d_ws;
  float* S   = ws;                  // 1,048,576  (B,L,128)
  float* U   = S   + 1048576;       // 1,048,576  (B,L,128)
  float* XZ  = U   + 1048576;       // 4,194,304  (B,L,512)
  float* XC  = XZ  + 4194304;       // 2,097,152  (B,L,256)
  float* DBL = XC  + 2097152;       //   327,680  (B,L,40)
  float* Y   = DBL + 327680;        // 2,097,152  (B,L,256)
  float* EB0 = XZ;                  // encoder/decoder scratch (<=1M each)
  float* EB1 = XZ + 1048576;
  float* H0  = Y;                   // masked input (131,072), Y dead in encoder
  float* UT  = Y;                   // transposed U for dec0, Y dead in decoder

  // ---------------- encoder ----------------
  k_maskmul<<<512, 256, 0, stream>>>(x, mask, H0, NB*2*TT);
  k_conv2<<<16*32, 256, 0, stream>>>(H0, enc_W0, enc_b0, EB0, 2, 32, 4096);
  k_gn_gelu2<<<16, 1024, 0, stream>>>(EB0, enc_g0, enc_be0, 32, 2048);
  k_conv2<<<16*64, 256, 0, stream>>>(EB0, enc_W1, enc_b1, EB1, 32, 64, 2048);
  k_gn_gelu2<<<16, 1024, 0, stream>>>(EB1, enc_g1, enc_be1, 64, 1024);
  k_conv2<<<16*128, 256, 0, stream>>>(EB1, enc_W2, enc_b2, EB0, 64, 128, 1024);
  k_gn_gelu2<<<16, 1024, 0, stream>>>(EB0, enc_g2, enc_be2, 128, 512);
  k_transpose2<<<4096, 256, 0, stream>>>(EB0, S);

  // ---------------- mamba layers ----------------
  const int rows = NB*LL; // 8192
  for (int i = 0; i < NLAYER; i++){
    k_ln2<<<2048, 256, 0, stream>>>(S, ln_g + i*DM, ln_b + i*DM, U, rows);
    k_gemm_nt<0><<<dim3(8, 128), 256, 0, stream>>>(U, in_W + (size_t)i*512*DM, XZ, rows, 512, DM, DM);
    k_cconv2<<<8192, 256, 0, stream>>>(XZ, conv_W + (size_t)i*DI*4, conv_b + (size_t)i*DI, XC);
    k_gemm_nt<0><<<dim3(1, 128), 256, 0, stream>>>(XC, xp_W + (size_t)i*40*DI, DBL, rows, 40, DI, DI);
    k_scanf<<<256, 256, 0, stream>>>(XC, DBL, XZ,
                                     dt_W + (size_t)i*DI*8, dt_b + (size_t)i*DI,
                                     A_log + (size_t)i*DI*16, D_p + (size_t)i*DI, Y);
    k_gemm_nt<1><<<dim3(2, 128), 256, 0, stream>>>(Y, out_W + (size_t)i*DM*DI, S, rows, DM, DI, DI);
  }

  // ---------------- decoder ----------------
  k_ln2<<<2048, 256, 0, stream>>>(S, nf_g, nf_b, U, rows);
  k_transposeB<<<4096, 256, 0, stream>>>(U, UT);   // (b,t,c) -> (b,c,t)
  k_deconv2<<<16*64, 256, 0, stream>>>(UT, dec_W0, dec_b0, EB0, 128, 64, 512, 512, 1);
  k_gn_gelu2<<<16, 1024, 0, stream>>>(EB0, dec_g0, dec_be0, 64, 1024);
  k_deconv2<<<16*32, 256, 0, stream>>>(EB0, dec_W1, dec_b1, EB1, 64, 32, 1024, 1024, 1);
  k_gn_gelu2<<<16, 1024, 0, stream>>>(EB1, dec_g1, dec_be1, 32, 2048);
  k_deconv2<<<16*2, 256, 0, stream>>>(EB1, dec_W2, dec_b2, out, 32, 2, 2048, 2048, 1);

  // echoes (f32)
  k_copyf<<<512, 256, 0, stream>>>(x,    out + 131072, 131072);
  k_copyf<<<512, 256, 0, stream>>>(mask, out + 262144, 131072);
}

// Round 10
// 2922.540 us; speedup vs baseline: 7.3446x; 1.3550x over previous
//
#include <hip/hip_runtime.h>
#include <hip/hip_bf16.h>
#include <math.h>

#define NB 16
#define TT 4096
#define LL 512
#define DM 128
#define DI 256
#define NLAYER 6

static __device__ __forceinline__ float gelu_f(float v){
  return 0.5f*v*(1.f + erff(v*0.70710678118654752f));
}
static __device__ __forceinline__ float silu_f(float v){
  return v/(1.f + __expf(-v));
}

__global__ __launch_bounds__(256) void k_maskmul(const float* __restrict__ x, const float* __restrict__ m,
                          float* __restrict__ out, int n){
  int i = blockIdx.x*256 + threadIdx.x;
  if (i < n) out[i] = x[i]*m[i];
}

// conv1d stride2 pad1 k3: (B,Ci,Li)->(B,Co,Li/2). block per (b,o). W (Co,Ci,3).
__global__ __launch_bounds__(256) void k_conv2(const float* __restrict__ x, const float* __restrict__ W,
                        const float* __restrict__ bias, float* __restrict__ y,
                        int Ci, int Co, int Li){
  __shared__ float w[192];
  int b = blockIdx.x / Co, o = blockIdx.x % Co;
  for (int j = threadIdx.x; j < Ci*3; j += 256) w[j] = W[(size_t)o*Ci*3 + j];
  __syncthreads();
  int Lo = Li >> 1;
  const float* xb = x + (size_t)b*Ci*Li;
  float bo = bias[o];
  float* yo = y + ((size_t)b*Co + o)*Lo;
  for (int t = threadIdx.x; t < Lo; t += 256){
    int tin = 2*t - 1;
    float acc = bo;
    for (int ci = 0; ci < Ci; ci++){
      const float* xr = xb + (size_t)ci*Li;
      float v0 = (tin >= 0) ? xr[tin] : 0.f;
      acc += w[ci*3+0]*v0 + w[ci*3+1]*xr[tin+1] + w[ci*3+2]*xr[tin+2];
    }
    yo[t] = acc;
  }
}

// GroupNorm(1 group) over (C,T) per batch, two-pass, then exact GELU. in-place. 1024 thr.
__global__ __launch_bounds__(1024) void k_gn_gelu2(float* __restrict__ x, const float* __restrict__ g,
                           const float* __restrict__ be, int C, int Tl){
  __shared__ float sh[16];
  __shared__ float bc;
  int b = blockIdx.x;
  int n = C*Tl;
  float* xb = x + (size_t)b*n;
  float s = 0.f;
  for (int i = threadIdx.x; i < n; i += 1024) s += xb[i];
  #pragma unroll
  for (int o = 32; o; o >>= 1) s += __shfl_down(s, o);
  if ((threadIdx.x & 63) == 0) sh[threadIdx.x >> 6] = s;
  __syncthreads();
  if (threadIdx.x == 0){
    float a = 0.f;
    #pragma unroll
    for (int k = 0; k < 16; k++) a += sh[k];
    bc = a/(float)n;
  }
  __syncthreads();
  float mean = bc;
  float s2 = 0.f;
  for (int i = threadIdx.x; i < n; i += 1024){ float d = xb[i]-mean; s2 += d*d; }
  #pragma unroll
  for (int o = 32; o; o >>= 1) s2 += __shfl_down(s2, o);
  __syncthreads();
  if ((threadIdx.x & 63) == 0) sh[threadIdx.x >> 6] = s2;
  __syncthreads();
  if (threadIdx.x == 0){
    float a = 0.f;
    #pragma unroll
    for (int k = 0; k < 16; k++) a += sh[k];
    bc = rsqrtf(a/(float)n + 1e-5f);
  }
  __syncthreads();
  float inv = bc;
  for (int i = threadIdx.x; i < n; i += 1024){
    int c = i / Tl;
    float v = (xb[i]-mean)*inv*g[c] + be[c];
    xb[i] = gelu_f(v);
  }
}

// (B,128,512) NCH -> (B,512,128) BLD.
__global__ __launch_bounds__(256) void k_transpose2(const float* __restrict__ in, float* __restrict__ out){
  int idx = blockIdx.x*256 + threadIdx.x;
  if (idx >= NB*DM*LL) return;
  int t = idx & 511;
  int c = (idx >> 9) & 127;
  int b = idx >> 16;
  out[(size_t)b*65536 + (size_t)t*128 + c] = in[idx];
}

// (B,512,128) BLD -> (B,128,512) NCH. idx enumerates OUTPUT (coalesced writes).
__global__ __launch_bounds__(256) void k_transposeB(const float* __restrict__ in, float* __restrict__ out){
  int idx = blockIdx.x*256 + threadIdx.x;
  if (idx >= NB*DM*LL) return;
  int m = idx & 511;
  int c = (idx >> 9) & 127;
  int b = idx >> 16;
  out[idx] = in[(size_t)b*65536 + (size_t)m*128 + c];
}

// LayerNorm last-dim(128), one wave per row.
__global__ __launch_bounds__(256) void k_ln2(const float* __restrict__ x, const float* __restrict__ g,
                      const float* __restrict__ be, float* __restrict__ out, int rows){
  int row = blockIdx.x*4 + (threadIdx.x >> 6);
  if (row >= rows) return;
  int lid = threadIdx.x & 63;
  const float* xr = x + (size_t)row*DM;
  float v0 = xr[lid], v1 = xr[lid+64];
  float s = v0 + v1;
  #pragma unroll
  for (int o = 32; o; o >>= 1) s += __shfl_xor(s, o);
  float mean = s*(1.f/128.f);
  float d0 = v0-mean, d1 = v1-mean;
  float s2 = d0*d0 + d1*d1;
  #pragma unroll
  for (int o = 32; o; o >>= 1) s2 += __shfl_xor(s2, o);
  float inv = rsqrtf(s2*(1.f/128.f) + 1e-5f);
  float* orow = out + (size_t)row*DM;
  orow[lid]    = d0*inv*g[lid]    + be[lid];
  orow[lid+64] = d1*inv*g[lid+64] + be[lid+64];
}

// C[M,N] (+)= A[M,K](row stride lda) * B[N,K]^T. 64x64 tile, BK=16, 4x4/thread.
template<int ACCUM>
__global__ __launch_bounds__(256) void k_gemm_nt(const float* __restrict__ A, const float* __restrict__ B,
                          float* __restrict__ C, int M, int N, int K, int lda){
  __shared__ float As[64][17];
  __shared__ float Bs[64][17];
  int tx = threadIdx.x & 15, ty = threadIdx.x >> 4;
  int m0 = blockIdx.y*64, n0 = blockIdx.x*64;
  int lr = threadIdx.x >> 2;
  int lc = (threadIdx.x & 3)*4;
  float acc[4][4] = {};
  for (int k0 = 0; k0 < K; k0 += 16){
    float4 av = *(const float4*)(A + (size_t)(m0+lr)*lda + k0 + lc);
    As[lr][lc+0]=av.x; As[lr][lc+1]=av.y; As[lr][lc+2]=av.z; As[lr][lc+3]=av.w;
    float4 bv = make_float4(0.f,0.f,0.f,0.f);
    if (n0+lr < N) bv = *(const float4*)(B + (size_t)(n0+lr)*K + k0 + lc);
    Bs[lr][lc+0]=bv.x; Bs[lr][lc+1]=bv.y; Bs[lr][lc+2]=bv.z; Bs[lr][lc+3]=bv.w;
    __syncthreads();
    #pragma unroll
    for (int k = 0; k < 16; k++){
      float a[4], bb[4];
      #pragma unroll
      for (int i = 0; i < 4; i++) a[i]  = As[ty*4+i][k];
      #pragma unroll
      for (int j = 0; j < 4; j++) bb[j] = Bs[tx*4+j][k];
      #pragma unroll
      for (int i = 0; i < 4; i++)
        #pragma unroll
        for (int j = 0; j < 4; j++) acc[i][j] += a[i]*bb[j];
    }
    __syncthreads();
  }
  #pragma unroll
  for (int i = 0; i < 4; i++){
    int m = m0 + ty*4 + i;
    #pragma unroll
    for (int j = 0; j < 4; j++){
      int n = n0 + tx*4 + j;
      if (n < N){
        size_t off = (size_t)m*N + n;
        C[off] = (ACCUM ? C[off] : 0.f) + acc[i][j];
      }
    }
  }
}

// depthwise causal conv k=4 over xi=XZ[...,:256], +bias, SiLU -> XC (B,L,256)
__global__ __launch_bounds__(256) void k_cconv2(const float* __restrict__ xz, const float* __restrict__ cw,
                         const float* __restrict__ cb, float* __restrict__ xc){
  int idx = blockIdx.x*256 + threadIdx.x;
  if (idx >= NB*LL*DI) return;
  int d = idx & 255;
  int l = (idx >> 8) & 511;
  int b = idx >> 17;
  const float* xi = xz + (size_t)b*262144 + d;
  float acc = cb[d];
  #pragma unroll
  for (int j = 0; j < 4; j++){
    int m = l - 3 + j;
    if (m >= 0) acc += xi[(size_t)m*512]*cw[d*4 + j];
  }
  xc[idx] = silu_f(acc);
}

// Block-parallel fused scan. One block per (b,d). thread = (chunk c, state s),
// chunk = 32 steps. Phase1: local scan keeping e/dbx in registers.
// LDS: exclusive chunk-prefix. Phase3: replay from registers, emit y.
__global__ __launch_bounds__(256) void k_scan_blk(const float* __restrict__ xc,
                        const float* __restrict__ dbl, const float* __restrict__ xz,
                        const float* __restrict__ dtW, const float* __restrict__ dtb,
                        const float* __restrict__ Alog, const float* __restrict__ Dp,
                        float* __restrict__ y){
  int bd = blockIdx.x;            // 0..4095
  int b = bd >> 8, d = bd & 255;
  int tid = threadIdx.x;
  int c = tid >> 4;               // chunk 0..15
  int s = tid & 15;               // state 0..15
  float a  = -__expf(Alog[d*16 + s]);
  float Dd = Dp[d];
  float w[8];
  #pragma unroll
  for (int j = 0; j < 8; j++) w[j] = dtW[d*8 + j];
  float tb = dtb[d];
  const float* xcp = xc + (size_t)b*131072 + d;
  const float* dbp = dbl + (size_t)b*20480;
  const float* zp  = xz + (size_t)b*262144 + 256 + d;
  float* yp = y + (size_t)b*131072 + d;

  const int l0 = c*32;
  float e[32], dbx[32];
  float A = 1.f, Bv = 0.f;
  #pragma unroll
  for (int i = 0; i < 32; i++){
    int l = l0 + i;
    const float* r = dbp + l*40;
    float raw = tb;
    #pragma unroll
    for (int j = 0; j < 8; j++) raw += r[j]*w[j];
    float dtv = (raw > 20.f) ? raw : log1pf(__expf(raw));
    float xcv = xcp[(size_t)l*DI];
    float ei  = __expf(dtv*a);
    float di  = dtv*r[8 + s]*xcv;
    e[i] = ei; dbx[i] = di;
    A *= ei; Bv = ei*Bv + di;
  }
  __shared__ float sA[16][17], sB[16][17];
  sA[c][s] = A; sB[c][s] = Bv;
  __syncthreads();
  if (tid < 16){
    float P = 0.f;
    for (int cc = 0; cc < 16; cc++){
      float Ac = sA[cc][tid], Bc = sB[cc][tid];
      sB[cc][tid] = P;            // exclusive prefix
      P = Ac*P + Bc;
    }
  }
  __syncthreads();
  float h = sB[c][s];
  #pragma unroll
  for (int i = 0; i < 32; i++){
    int l = l0 + i;
    h = e[i]*h + dbx[i];
    float p = h * dbp[l*40 + 24 + s];
    p += __shfl_xor(p, 1); p += __shfl_xor(p, 2);
    p += __shfl_xor(p, 4); p += __shfl_xor(p, 8);
    if (s == 0){
      float xcv = xcp[(size_t)l*DI];
      float zv  = zp[(size_t)l*512];
      yp[(size_t)l*DI] = (p + Dd*xcv)*silu_f(zv);
    }
  }
}

// deconv stride2 k3 pad1 outpad1: (B,Ci,Li)->(B,Co,2Li). W (Ci,Co,3). block per (b,o).
__global__ __launch_bounds__(256) void k_deconv2(const float* __restrict__ x, const float* __restrict__ W,
                          const float* __restrict__ bias, float* __restrict__ y,
                          int Ci, int Co, int Li, int cs, int ts){
  __shared__ float w[384];
  int b = blockIdx.x / Co, o = blockIdx.x % Co;
  for (int j = threadIdx.x; j < Ci*3; j += 256){
    int i = j/3, k = j - 3*i;
    w[j] = W[((size_t)i*Co + o)*3 + k];
  }
  __syncthreads();
  int Lo = 2*Li;
  const float* xb = x + (size_t)b*Ci*Li;
  float bo = bias[o];
  size_t obase = ((size_t)b*Co + o)*Lo;
  for (int t = threadIdx.x; t < Lo; t += 256){
    float acc = bo;
    if ((t & 1) == 0){
      int m = t >> 1;
      for (int i = 0; i < Ci; i++) acc += w[i*3+1]*xb[(size_t)i*cs + (size_t)m*ts];
    } else {
      int m0 = t >> 1, m1 = m0 + 1;
      if (m1 < Li){
        for (int i = 0; i < Ci; i++){
          const float* xr = xb + (size_t)i*cs;
          acc += w[i*3+2]*xr[(size_t)m0*ts] + w[i*3+0]*xr[(size_t)m1*ts];
        }
      } else {
        for (int i = 0; i < Ci; i++) acc += w[i*3+2]*xb[(size_t)i*cs + (size_t)m0*ts];
      }
    }
    y[obase + t] = acc;
  }
}

__global__ __launch_bounds__(256) void k_copyf(const float* __restrict__ in, float* __restrict__ out, int n){
  int i = blockIdx.x*256 + threadIdx.x;
  if (i < n) out[i] = in[i];
}

extern "C" void kernel_launch(void* const* d_in, const int* in_sizes, int n_in,
                              void* d_out, int out_size, void* d_ws, size_t ws_size,
                              hipStream_t stream) {
  const float* x      = (const float*)d_in[0];
  const float* mask   = (const float*)d_in[1];
  const float* enc_W0 = (const float*)d_in[2];
  const float* enc_b0 = (const float*)d_in[3];
  const float* enc_g0 = (const float*)d_in[4];
  const float* enc_be0= (const float*)d_in[5];
  const float* enc_W1 = (const float*)d_in[6];
  const float* enc_b1 = (const float*)d_in[7];
  const float* enc_g1 = (const float*)d_in[8];
  const float* enc_be1= (const float*)d_in[9];
  const float* enc_W2 = (const float*)d_in[10];
  const float* enc_b2 = (const float*)d_in[11];
  const float* enc_g2 = (const float*)d_in[12];
  const float* enc_be2= (const float*)d_in[13];
  const float* ln_g   = (const float*)d_in[14];
  const float* ln_b   = (const float*)d_in[15];
  const float* in_W   = (const float*)d_in[16];
  const float* conv_W = (const float*)d_in[17];
  const float* conv_b = (const float*)d_in[18];
  const float* xp_W   = (const float*)d_in[19];
  const float* dt_W   = (const float*)d_in[20];
  const float* dt_b   = (const float*)d_in[21];
  const float* A_log  = (const float*)d_in[22];
  const float* D_p    = (const float*)d_in[23];
  const float* out_W  = (const float*)d_in[24];
  const float* nf_g   = (const float*)d_in[25];
  const float* nf_b   = (const float*)d_in[26];
  const float* dec_W0 = (const float*)d_in[27];
  const float* dec_b0 = (const float*)d_in[28];
  const float* dec_g0 = (const float*)d_in[29];
  const float* dec_be0= (const float*)d_in[30];
  const float* dec_W1 = (const float*)d_in[31];
  const float* dec_b1 = (const float*)d_in[32];
  const float* dec_g1 = (const float*)d_in[33];
  const float* dec_be1= (const float*)d_in[34];
  const float* dec_W2 = (const float*)d_in[35];
  const float* dec_b2 = (const float*)d_in[36];

  float* out = (float*)d_out;

  float* ws  = (float*)d_ws;
  float* S   = ws;                  // 1,048,576  (B,L,128)
  float* U   = S   + 1048576;       // 1,048,576  (B,L,128)
  float* XZ  = U   + 1048576;       // 4,194,304  (B,L,512)
  float* XC  = XZ  + 4194304;       // 2,097,152  (B,L,256)
  float* DBL = XC  + 2097152;       //   327,680  (B,L,40)
  float* Y   = DBL + 327680;        // 2,097,152  (B,L,256)
  float* EB0 = XZ;                  // encoder/decoder scratch (<=1M each)
  float* EB1 = XZ + 1048576;
  float* H0  = Y;                   // masked input (131,072), Y dead in encoder
  float* UT  = Y;                   // transposed U for dec0, Y dead in decoder

  // ---------------- encoder ----------------
  k_maskmul<<<512, 256, 0, stream>>>(x, mask, H0, NB*2*TT);
  k_conv2<<<16*32, 256, 0, stream>>>(H0, enc_W0, enc_b0, EB0, 2, 32, 4096);
  k_gn_gelu2<<<16, 1024, 0, stream>>>(EB0, enc_g0, enc_be0, 32, 2048);
  k_conv2<<<16*64, 256, 0, stream>>>(EB0, enc_W1, enc_b1, EB1, 32, 64, 2048);
  k_gn_gelu2<<<16, 1024, 0, stream>>>(EB1, enc_g1, enc_be1, 64, 1024);
  k_conv2<<<16*128, 256, 0, stream>>>(EB1, enc_W2, enc_b2, EB0, 64, 128, 1024);
  k_gn_gelu2<<<16, 1024, 0, stream>>>(EB0, enc_g2, enc_be2, 128, 512);
  k_transpose2<<<4096, 256, 0, stream>>>(EB0, S);

  // ---------------- mamba layers ----------------
  const int rows = NB*LL; // 8192
  for (int i = 0; i < NLAYER; i++){
    k_ln2<<<2048, 256, 0, stream>>>(S, ln_g + i*DM, ln_b + i*DM, U, rows);
    k_gemm_nt<0><<<dim3(8, 128), 256, 0, stream>>>(U, in_W + (size_t)i*512*DM, XZ, rows, 512, DM, DM);
    k_cconv2<<<8192, 256, 0, stream>>>(XZ, conv_W + (size_t)i*DI*4, conv_b + (size_t)i*DI, XC);
    k_gemm_nt<0><<<dim3(1, 128), 256, 0, stream>>>(XC, xp_W + (size_t)i*40*DI, DBL, rows, 40, DI, DI);
    k_scan_blk<<<4096, 256, 0, stream>>>(XC, DBL, XZ,
                                         dt_W + (size_t)i*DI*8, dt_b + (size_t)i*DI,
                                         A_log + (size_t)i*DI*16, D_p + (size_t)i*DI, Y);
    k_gemm_nt<1><<<dim3(2, 128), 256, 0, stream>>>(Y, out_W + (size_t)i*DM*DI, S, rows, DM, DI, DI);
  }

  // ---------------- decoder ----------------
  k_ln2<<<2048, 256, 0, stream>>>(S, nf_g, nf_b, U, rows);
  k_transposeB<<<4096, 256, 0, stream>>>(U, UT);   // (b,t,c) -> (b,c,t)
  k_deconv2<<<16*64, 256, 0, stream>>>(UT, dec_W0, dec_b0, EB0, 128, 64, 512, 512, 1);
  k_gn_gelu2<<<16, 1024, 0, stream>>>(EB0, dec_g0, dec_be0, 64, 1024);
  k_deconv2<<<16*32, 256, 0, stream>>>(EB0, dec_W1, dec_b1, EB1, 64, 32, 1024, 1024, 1);
  k_gn_gelu2<<<16, 1024, 0, stream>>>(EB1, dec_g1, dec_be1, 32, 2048);
  k_deconv2<<<16*2, 256, 0, stream>>>(EB1, dec_W2, dec_b2, out, 32, 2, 2048, 2048, 1);

  // echoes (f32)
  k_copyf<<<512, 256, 0, stream>>>(x,    out + 131072, 131072);
  k_copyf<<<512, 256, 0, stream>>>(mask, out + 262144, 131072);
}

// Round 11
// 1667.455 us; speedup vs baseline: 12.8728x; 1.7527x over previous
//
#include <hip/hip_runtime.h>
#include <hip/hip_bf16.h>
#include <math.h>

#define NB 16
#define TT 4096
#define LL 512
#define DM 128
#define DI 256
#define NLAYER 6

static __device__ __forceinline__ float gelu_f(float v){
  return 0.5f*v*(1.f + erff(v*0.70710678118654752f));
}
static __device__ __forceinline__ float silu_f(float v){
  return v/(1.f + __expf(-v));
}
// container slot for (d,l) inside the dead xi half of XZ (b-row of 262144 floats):
// addr = b*262144 + d*1024 + ((l>>8)<<9) + (l&255)   (bijective into l*512+dd, dd<256)
static __device__ __forceinline__ size_t cont_off(int d, int l){
  return (size_t)d*1024 + (((size_t)(l >> 8)) << 9) + (l & 255);
}

__global__ __launch_bounds__(256) void k_maskmul(const float* __restrict__ x, const float* __restrict__ m,
                          float* __restrict__ out, int n){
  int i = blockIdx.x*256 + threadIdx.x;
  if (i < n) out[i] = x[i]*m[i];
}

// conv1d stride2 pad1 k3: (B,Ci,Li)->(B,Co,Li/2). block per (b,o). W (Co,Ci,3).
__global__ __launch_bounds__(256) void k_conv2(const float* __restrict__ x, const float* __restrict__ W,
                        const float* __restrict__ bias, float* __restrict__ y,
                        int Ci, int Co, int Li){
  __shared__ float w[192];
  int b = blockIdx.x / Co, o = blockIdx.x % Co;
  for (int j = threadIdx.x; j < Ci*3; j += 256) w[j] = W[(size_t)o*Ci*3 + j];
  __syncthreads();
  int Lo = Li >> 1;
  const float* xb = x + (size_t)b*Ci*Li;
  float bo = bias[o];
  float* yo = y + ((size_t)b*Co + o)*Lo;
  for (int t = threadIdx.x; t < Lo; t += 256){
    int tin = 2*t - 1;
    float acc = bo;
    for (int ci = 0; ci < Ci; ci++){
      const float* xr = xb + (size_t)ci*Li;
      float v0 = (tin >= 0) ? xr[tin] : 0.f;
      acc += w[ci*3+0]*v0 + w[ci*3+1]*xr[tin+1] + w[ci*3+2]*xr[tin+2];
    }
    yo[t] = acc;
  }
}

// -------- GroupNorm(1): wide 2-kernel version (n = C*Tl = 65536 per batch) --------
// partials: 8 blocks per batch, fixed slots -> deterministic
__global__ __launch_bounds__(256) void k_gn_part(const float* __restrict__ x, float* __restrict__ gp){
  int b = blockIdx.x >> 3, k8 = blockIdx.x & 7;
  const float* xb = x + (size_t)b*65536 + (size_t)k8*8192;
  float s = 0.f, s2 = 0.f;
  for (int i = threadIdx.x; i < 8192; i += 256){ float v = xb[i]; s += v; s2 += v*v; }
  #pragma unroll
  for (int o = 32; o; o >>= 1){ s += __shfl_down(s, o); s2 += __shfl_down(s2, o); }
  __shared__ float sh[8];
  int wid = threadIdx.x >> 6;
  if ((threadIdx.x & 63) == 0){ sh[wid] = s; sh[wid+4] = s2; }
  __syncthreads();
  if (threadIdx.x == 0){
    float a = sh[0]+sh[1]+sh[2]+sh[3], a2 = sh[4]+sh[5]+sh[6]+sh[7];
    gp[(b*8+k8)*2+0] = a; gp[(b*8+k8)*2+1] = a2;
  }
}
// apply: wide, reads the 8 partials (L1-hot) per element
__global__ __launch_bounds__(256) void k_gn_apply(float* __restrict__ x, const float* __restrict__ g,
                          const float* __restrict__ be, int Tl, const float* __restrict__ gp){
  int gidx = blockIdx.x*256 + threadIdx.x;      // over 16*65536
  int b = gidx >> 16, i = gidx & 65535;
  float s = 0.f, s2 = 0.f;
  #pragma unroll
  for (int k = 0; k < 8; k++){ s += gp[(b*8+k)*2]; s2 += gp[(b*8+k)*2+1]; }
  float mean = s*(1.f/65536.f);
  float inv  = rsqrtf(s2*(1.f/65536.f) - mean*mean + 1e-5f);
  int c = i / Tl;
  float* p = x + (size_t)b*65536 + i;
  float v = (*p - mean)*inv*g[c] + be[c];
  *p = gelu_f(v);
}

// (B,128,512) NCH -> (B,512,128) BLD.
__global__ __launch_bounds__(256) void k_transpose2(const float* __restrict__ in, float* __restrict__ out){
  int idx = blockIdx.x*256 + threadIdx.x;
  if (idx >= NB*DM*LL) return;
  int t = idx & 511;
  int c = (idx >> 9) & 127;
  int b = idx >> 16;
  out[(size_t)b*65536 + (size_t)t*128 + c] = in[idx];
}

// (B,512,128) BLD -> (B,128,512) NCH.
__global__ __launch_bounds__(256) void k_transposeB(const float* __restrict__ in, float* __restrict__ out){
  int idx = blockIdx.x*256 + threadIdx.x;
  if (idx >= NB*DM*LL) return;
  int m = idx & 511;
  int c = (idx >> 9) & 127;
  int b = idx >> 16;
  out[idx] = in[(size_t)b*65536 + (size_t)m*128 + c];
}

// LayerNorm last-dim(128), one wave per row.
__global__ __launch_bounds__(256) void k_ln2(const float* __restrict__ x, const float* __restrict__ g,
                      const float* __restrict__ be, float* __restrict__ out, int rows){
  int row = blockIdx.x*4 + (threadIdx.x >> 6);
  if (row >= rows) return;
  int lid = threadIdx.x & 63;
  const float* xr = x + (size_t)row*DM;
  float v0 = xr[lid], v1 = xr[lid+64];
  float s = v0 + v1;
  #pragma unroll
  for (int o = 32; o; o >>= 1) s += __shfl_xor(s, o);
  float mean = s*(1.f/128.f);
  float d0 = v0-mean, d1 = v1-mean;
  float s2 = d0*d0 + d1*d1;
  #pragma unroll
  for (int o = 32; o; o >>= 1) s2 += __shfl_xor(s2, o);
  float inv = rsqrtf(s2*(1.f/128.f) + 1e-5f);
  float* orow = out + (size_t)row*DM;
  orow[lid]    = d0*inv*g[lid]    + be[lid];
  orow[lid+64] = d1*inv*g[lid+64] + be[lid+64];
}

// C[M,N] (+)= A[M,K](row stride lda) * B[N,K]^T. 64x64 tile, BK=16, 4x4/thread.
template<int ACCUM>
__global__ __launch_bounds__(256) void k_gemm_nt(const float* __restrict__ A, const float* __restrict__ B,
                          float* __restrict__ C, int M, int N, int K, int lda){
  __shared__ float As[64][17];
  __shared__ float Bs[64][17];
  int tx = threadIdx.x & 15, ty = threadIdx.x >> 4;
  int m0 = blockIdx.y*64, n0 = blockIdx.x*64;
  int lr = threadIdx.x >> 2;
  int lc = (threadIdx.x & 3)*4;
  float acc[4][4] = {};
  for (int k0 = 0; k0 < K; k0 += 16){
    float4 av = *(const float4*)(A + (size_t)(m0+lr)*lda + k0 + lc);
    As[lr][lc+0]=av.x; As[lr][lc+1]=av.y; As[lr][lc+2]=av.z; As[lr][lc+3]=av.w;
    float4 bv = make_float4(0.f,0.f,0.f,0.f);
    if (n0+lr < N) bv = *(const float4*)(B + (size_t)(n0+lr)*K + k0 + lc);
    Bs[lr][lc+0]=bv.x; Bs[lr][lc+1]=bv.y; Bs[lr][lc+2]=bv.z; Bs[lr][lc+3]=bv.w;
    __syncthreads();
    #pragma unroll
    for (int k = 0; k < 16; k++){
      float a[4], bb[4];
      #pragma unroll
      for (int i = 0; i < 4; i++) a[i]  = As[ty*4+i][k];
      #pragma unroll
      for (int j = 0; j < 4; j++) bb[j] = Bs[tx*4+j][k];
      #pragma unroll
      for (int i = 0; i < 4; i++)
        #pragma unroll
        for (int j = 0; j < 4; j++) acc[i][j] += a[i]*bb[j];
    }
    __syncthreads();
  }
  #pragma unroll
  for (int i = 0; i < 4; i++){
    int m = m0 + ty*4 + i;
    #pragma unroll
    for (int j = 0; j < 4; j++){
      int n = n0 + tx*4 + j;
      if (n < N){
        size_t off = (size_t)m*N + n;
        C[off] = (ACCUM ? C[off] : 0.f) + acc[i][j];
      }
    }
  }
}

// depthwise causal conv k=4 over xi=XZ[...,:256], +bias, SiLU -> XC (B,L,256)
__global__ __launch_bounds__(256) void k_cconv2(const float* __restrict__ xz, const float* __restrict__ cw,
                         const float* __restrict__ cb, float* __restrict__ xc){
  int idx = blockIdx.x*256 + threadIdx.x;
  if (idx >= NB*LL*DI) return;
  int d = idx & 255;
  int l = (idx >> 8) & 511;
  int b = idx >> 17;
  const float* xi = xz + (size_t)b*262144 + d;
  float acc = cb[d];
  #pragma unroll
  for (int j = 0; j < 4; j++){
    int m = l - 3 + j;
    if (m >= 0) acc += xi[(size_t)m*512]*cw[d*4 + j];
  }
  xc[idx] = silu_f(acc);
}

// dt (softplus) into the (d,l)-container inside XZ's dead xi half.
__global__ __launch_bounds__(256) void k_dtT(const float* __restrict__ dbl, const float* __restrict__ dtW,
                      const float* __restrict__ dtb, float* __restrict__ xz){
  int idx = blockIdx.x*256 + threadIdx.x;     // (b,d,l), l fastest
  if (idx >= NB*DI*LL) return;
  int l = idx & 511;
  int d = (idx >> 9) & 255;
  int b = idx >> 17;
  const float* r = dbl + (size_t)b*20480 + l*40;
  float acc = dtb[d];
  #pragma unroll
  for (int j = 0; j < 8; j++) acc += r[j]*dtW[d*8 + j];
  float dt = (acc > 20.f) ? acc : log1pf(__expf(acc));
  xz[(size_t)b*262144 + cont_off(d, l)] = dt;
}

// XC (b,l,256) -> XCT (b,256,512) via LDS tile transpose. block=(b, dtile8, ltile16), 256 thr (32x8)
__global__ __launch_bounds__(256) void k_tr_xc(const float* __restrict__ xc, float* __restrict__ xct){
  __shared__ float t[32][33];
  int bid = blockIdx.x;
  int lt = bid & 15, dt8 = (bid >> 4) & 7, b = bid >> 7;
  int tx = threadIdx.x & 31, ty = threadIdx.x >> 5;
  int d0 = dt8*32, l0 = lt*32;
  const float* src = xc + (size_t)b*131072;
  #pragma unroll
  for (int j = 0; j < 4; j++)
    t[ty + j*8][tx] = src[(size_t)(l0 + ty + j*8)*256 + d0 + tx];
  __syncthreads();
  float* dst = xct + (size_t)b*131072;
  #pragma unroll
  for (int j = 0; j < 4; j++)
    dst[(size_t)(d0 + ty + j*8)*512 + l0 + tx] = t[tx][ty + j*8];
}

// Block-parallel scan, L-contiguous. One block per (b,d). thread=(chunk c, state s).
// reads XCT (b,d,l), dt container, dbl(bm,cm); writes yraw (p + D*xc) into container slots.
__global__ __launch_bounds__(256) void k_scanT(const float* __restrict__ xct,
                        float* __restrict__ xz, const float* __restrict__ dbl,
                        const float* __restrict__ Alog, const float* __restrict__ Dp){
  int bd = blockIdx.x;
  int b = bd >> 8, d = bd & 255;
  int tid = threadIdx.x;
  int c = tid >> 4;
  int s = tid & 15;
  float a  = -__expf(Alog[d*16 + s]);
  float Dd = Dp[d];
  const float* xp = xct + (size_t)b*131072 + (size_t)d*512;
  float* cont = xz + (size_t)b*262144;
  const float* dbp = dbl + (size_t)b*20480;

  const int l0 = c*32;
  float e[32], dbx[32];
  float A = 1.f, Bv = 0.f;
  #pragma unroll
  for (int i = 0; i < 32; i++){
    int l = l0 + i;
    float dt  = cont[cont_off(d, l)];
    float xcv = xp[l];
    float ei  = __expf(dt*a);
    float di  = dt*dbp[l*40 + 8 + s]*xcv;
    e[i] = ei; dbx[i] = di;
    A *= ei; Bv = ei*Bv + di;
  }
  __shared__ float sA[16][17], sB[16][17];
  sA[c][s] = A; sB[c][s] = Bv;
  __syncthreads();
  if (tid < 16){
    float P = 0.f;
    for (int cc = 0; cc < 16; cc++){
      float Ac = sA[cc][tid], Bc = sB[cc][tid];
      sB[cc][tid] = P;
      P = Ac*P + Bc;
    }
  }
  __syncthreads();
  float h = sB[c][s];
  #pragma unroll
  for (int i = 0; i < 32; i++){
    int l = l0 + i;
    h = e[i]*h + dbx[i];
    float p = h * dbp[l*40 + 24 + s];
    p += __shfl_xor(p, 1); p += __shfl_xor(p, 2);
    p += __shfl_xor(p, 4); p += __shfl_xor(p, 8);
    if (s == 0){
      float xcv = xp[l];
      cont[cont_off(d, l)] = p + Dd*xcv;   // overwrite dt slot (phase1 done)
    }
  }
}

// gate + transpose: Y(b,l,256) = cont(b,d,l) * silu(z(b,l,256+d))
__global__ __launch_bounds__(256) void k_gateT(const float* __restrict__ xz, float* __restrict__ y){
  __shared__ float t[32][33];
  int bid = blockIdx.x;
  int lt = bid & 15, dt8 = (bid >> 4) & 7, b = bid >> 7;
  int tx = threadIdx.x & 31, ty = threadIdx.x >> 5;
  int d0 = dt8*32, l0 = lt*32;
  const float* cont = xz + (size_t)b*262144;
  #pragma unroll
  for (int j = 0; j < 4; j++)
    t[ty + j*8][tx] = cont[cont_off(d0 + ty + j*8, l0 + tx)];
  __syncthreads();
  #pragma unroll
  for (int j = 0; j < 4; j++){
    int l = l0 + ty + j*8;
    int dd = d0 + tx;
    float zv = xz[(size_t)b*262144 + (size_t)l*512 + 256 + dd];
    y[(size_t)b*131072 + (size_t)l*256 + dd] = t[tx][ty + j*8]*silu_f(zv);
  }
}

// deconv stride2 k3 pad1 outpad1: (B,Ci,Li)->(B,Co,2Li). W (Ci,Co,3). block per (b,o).
__global__ __launch_bounds__(256) void k_deconv2(const float* __restrict__ x, const float* __restrict__ W,
                          const float* __restrict__ bias, float* __restrict__ y,
                          int Ci, int Co, int Li, int cs, int ts){
  __shared__ float w[384];
  int b = blockIdx.x / Co, o = blockIdx.x % Co;
  for (int j = threadIdx.x; j < Ci*3; j += 256){
    int i = j/3, k = j - 3*i;
    w[j] = W[((size_t)i*Co + o)*3 + k];
  }
  __syncthreads();
  int Lo = 2*Li;
  const float* xb = x + (size_t)b*Ci*Li;
  float bo = bias[o];
  size_t obase = ((size_t)b*Co + o)*Lo;
  for (int t = threadIdx.x; t < Lo; t += 256){
    float acc = bo;
    if ((t & 1) == 0){
      int m = t >> 1;
      for (int i = 0; i < Ci; i++) acc += w[i*3+1]*xb[(size_t)i*cs + (size_t)m*ts];
    } else {
      int m0 = t >> 1, m1 = m0 + 1;
      if (m1 < Li){
        for (int i = 0; i < Ci; i++){
          const float* xr = xb + (size_t)i*cs;
          acc += w[i*3+2]*xr[(size_t)m0*ts] + w[i*3+0]*xr[(size_t)m1*ts];
        }
      } else {
        for (int i = 0; i < Ci; i++) acc += w[i*3+2]*xb[(size_t)i*cs + (size_t)m0*ts];
      }
    }
    y[obase + t] = acc;
  }
}

__global__ __launch_bounds__(256) void k_copyf(const float* __restrict__ in, float* __restrict__ out, int n){
  int i = blockIdx.x*256 + threadIdx.x;
  if (i < n) out[i] = in[i];
}

extern "C" void kernel_launch(void* const* d_in, const int* in_sizes, int n_in,
                              void* d_out, int out_size, void* d_ws, size_t ws_size,
                              hipStream_t stream) {
  const float* x      = (const float*)d_in[0];
  const float* mask   = (const float*)d_in[1];
  const float* enc_W0 = (const float*)d_in[2];
  const float* enc_b0 = (const float*)d_in[3];
  const float* enc_g0 = (const float*)d_in[4];
  const float* enc_be0= (const float*)d_in[5];
  const float* enc_W1 = (const float*)d_in[6];
  const float* enc_b1 = (const float*)d_in[7];
  const float* enc_g1 = (const float*)d_in[8];
  const float* enc_be1= (const float*)d_in[9];
  const float* enc_W2 = (const float*)d_in[10];
  const float* enc_b2 = (const float*)d_in[11];
  const float* enc_g2 = (const float*)d_in[12];
  const float* enc_be2= (const float*)d_in[13];
  const float* ln_g   = (const float*)d_in[14];
  const float* ln_b   = (const float*)d_in[15];
  const float* in_W   = (const float*)d_in[16];
  const float* conv_W = (const float*)d_in[17];
  const float* conv_b = (const float*)d_in[18];
  const float* xp_W   = (const float*)d_in[19];
  const float* dt_W   = (const float*)d_in[20];
  const float* dt_b   = (const float*)d_in[21];
  const float* A_log  = (const float*)d_in[22];
  const float* D_p    = (const float*)d_in[23];
  const float* out_W  = (const float*)d_in[24];
  const float* nf_g   = (const float*)d_in[25];
  const float* nf_b   = (const float*)d_in[26];
  const float* dec_W0 = (const float*)d_in[27];
  const float* dec_b0 = (const float*)d_in[28];
  const float* dec_g0 = (const float*)d_in[29];
  const float* dec_be0= (const float*)d_in[30];
  const float* dec_W1 = (const float*)d_in[31];
  const float* dec_b1 = (const float*)d_in[32];
  const float* dec_g1 = (const float*)d_in[33];
  const float* dec_be1= (const float*)d_in[34];
  const float* dec_W2 = (const float*)d_in[35];
  const float* dec_b2 = (const float*)d_in[36];

  float* out = (float*)d_out;

  float* ws  = (float*)d_ws;
  float* S   = ws;                  // 1,048,576  (B,L,128)
  float* U   = S   + 1048576;       // 1,048,576  (B,L,128)
  float* XZ  = U   + 1048576;       // 4,194,304  (B,L,512); xi half doubles as dt/yraw container
  float* CBUF= XZ  + 4194304;       // 2,097,152  XC, then gated Y (B,L,256)
  float* XCT = CBUF+ 2097152;       // 2,097,152  (B,256,512)
  float* DBL = XCT + 2097152;       //   327,680  (B,L,40)
  float* EB0 = XZ;                  // encoder/decoder scratch (<=1M each)
  float* EB1 = XZ + 1048576;
  float* H0  = CBUF;                // masked input (131,072)
  float* UT  = CBUF;                // transposed U for dec0
  float* GNP = DBL;                 // GN partials (256 floats), DBL dead in enc/dec

  // ---------------- encoder ----------------
  k_maskmul<<<512, 256, 0, stream>>>(x, mask, H0, NB*2*TT);
  k_conv2<<<16*32, 256, 0, stream>>>(H0, enc_W0, enc_b0, EB0, 2, 32, 4096);
  k_gn_part<<<128, 256, 0, stream>>>(EB0, GNP);
  k_gn_apply<<<4096, 256, 0, stream>>>(EB0, enc_g0, enc_be0, 2048, GNP);
  k_conv2<<<16*64, 256, 0, stream>>>(EB0, enc_W1, enc_b1, EB1, 32, 64, 2048);
  k_gn_part<<<128, 256, 0, stream>>>(EB1, GNP);
  k_gn_apply<<<4096, 256, 0, stream>>>(EB1, enc_g1, enc_be1, 1024, GNP);
  k_conv2<<<16*128, 256, 0, stream>>>(EB1, enc_W2, enc_b2, EB0, 64, 128, 1024);
  k_gn_part<<<128, 256, 0, stream>>>(EB0, GNP);
  k_gn_apply<<<4096, 256, 0, stream>>>(EB0, enc_g2, enc_be2, 512, GNP);
  k_transpose2<<<4096, 256, 0, stream>>>(EB0, S);

  // ---------------- mamba layers ----------------
  const int rows = NB*LL; // 8192
  for (int i = 0; i < NLAYER; i++){
    k_ln2<<<2048, 256, 0, stream>>>(S, ln_g + i*DM, ln_b + i*DM, U, rows);
    k_gemm_nt<0><<<dim3(8, 128), 256, 0, stream>>>(U, in_W + (size_t)i*512*DM, XZ, rows, 512, DM, DM);
    k_cconv2<<<8192, 256, 0, stream>>>(XZ, conv_W + (size_t)i*DI*4, conv_b + (size_t)i*DI, CBUF);
    k_gemm_nt<0><<<dim3(1, 128), 256, 0, stream>>>(CBUF, xp_W + (size_t)i*40*DI, DBL, rows, 40, DI, DI);
    k_dtT<<<8192, 256, 0, stream>>>(DBL, dt_W + (size_t)i*DI*8, dt_b + (size_t)i*DI, XZ);
    k_tr_xc<<<2048, 256, 0, stream>>>(CBUF, XCT);
    k_scanT<<<4096, 256, 0, stream>>>(XCT, XZ, DBL,
                                      A_log + (size_t)i*DI*16, D_p + (size_t)i*DI);
    k_gateT<<<2048, 256, 0, stream>>>(XZ, CBUF);
    k_gemm_nt<1><<<dim3(2, 128), 256, 0, stream>>>(CBUF, out_W + (size_t)i*DM*DI, S, rows, DM, DI, DI);
  }

  // ---------------- decoder ----------------
  k_ln2<<<2048, 256, 0, stream>>>(S, nf_g, nf_b, U, rows);
  k_transposeB<<<4096, 256, 0, stream>>>(U, UT);   // (b,t,c) -> (b,c,t)
  k_deconv2<<<16*64, 256, 0, stream>>>(UT, dec_W0, dec_b0, EB0, 128, 64, 512, 512, 1);
  k_gn_part<<<128, 256, 0, stream>>>(EB0, GNP);
  k_gn_apply<<<4096, 256, 0, stream>>>(EB0, dec_g0, dec_be0, 1024, GNP);
  k_deconv2<<<16*32, 256, 0, stream>>>(EB0, dec_W1, dec_b1, EB1, 64, 32, 1024, 1024, 1);
  k_gn_part<<<128, 256, 0, stream>>>(EB1, GNP);
  k_gn_apply<<<4096, 256, 0, stream>>>(EB1, dec_g1, dec_be1, 2048, GNP);
  k_deconv2<<<16*2, 256, 0, stream>>>(EB1, dec_W2, dec_b2, out, 32, 2, 2048, 2048, 1);

  // echoes (f32)
  k_copyf<<<512, 256, 0, stream>>>(x,    out + 131072, 131072);
  k_copyf<<<512, 256, 0, stream>>>(mask, out + 262144, 131072);
}

// Round 12
// 1616.767 us; speedup vs baseline: 13.2763x; 1.0314x over previous
//
#include <hip/hip_runtime.h>
#include <hip/hip_bf16.h>
#include <math.h>

#define NB 16
#define TT 4096
#define LL 512
#define DM 128
#define DI 256
#define NLAYER 6

static __device__ __forceinline__ float gelu_f(float v){
  return 0.5f*v*(1.f + erff(v*0.70710678118654752f));
}
static __device__ __forceinline__ float silu_f(float v){
  return v/(1.f + __expf(-v));
}
// container slot for (d,l) inside the dead xi half of XZ (b-row of 262144 floats)
static __device__ __forceinline__ size_t cont_off(int d, int l){
  return (size_t)d*1024 + (((size_t)(l >> 8)) << 9) + (l & 255);
}

__global__ __launch_bounds__(256) void k_maskmul(const float* __restrict__ x, const float* __restrict__ m,
                          float* __restrict__ out, int n){
  int i = blockIdx.x*256 + threadIdx.x;
  if (i < n) out[i] = x[i]*m[i];
}

// conv1d stride2 pad1 k3: (B,Ci,Li)->(B,Co,Li/2). block per (b,o). W (Co,Ci,3).
__global__ __launch_bounds__(256) void k_conv2(const float* __restrict__ x, const float* __restrict__ W,
                        const float* __restrict__ bias, float* __restrict__ y,
                        int Ci, int Co, int Li){
  __shared__ float w[192];
  int b = blockIdx.x / Co, o = blockIdx.x % Co;
  for (int j = threadIdx.x; j < Ci*3; j += 256) w[j] = W[(size_t)o*Ci*3 + j];
  __syncthreads();
  int Lo = Li >> 1;
  const float* xb = x + (size_t)b*Ci*Li;
  float bo = bias[o];
  float* yo = y + ((size_t)b*Co + o)*Lo;
  for (int t = threadIdx.x; t < Lo; t += 256){
    int tin = 2*t - 1;
    float acc = bo;
    for (int ci = 0; ci < Ci; ci++){
      const float* xr = xb + (size_t)ci*Li;
      float v0 = (tin >= 0) ? xr[tin] : 0.f;
      acc += w[ci*3+0]*v0 + w[ci*3+1]*xr[tin+1] + w[ci*3+2]*xr[tin+2];
    }
    yo[t] = acc;
  }
}

// -------- GroupNorm(1): wide 2-kernel version (n = 65536 per batch) --------
__global__ __launch_bounds__(256) void k_gn_part(const float* __restrict__ x, float* __restrict__ gp){
  int b = blockIdx.x >> 3, k8 = blockIdx.x & 7;
  const float* xb = x + (size_t)b*65536 + (size_t)k8*8192;
  float s = 0.f, s2 = 0.f;
  for (int i = threadIdx.x; i < 8192; i += 256){ float v = xb[i]; s += v; s2 += v*v; }
  #pragma unroll
  for (int o = 32; o; o >>= 1){ s += __shfl_down(s, o); s2 += __shfl_down(s2, o); }
  __shared__ float sh[8];
  int wid = threadIdx.x >> 6;
  if ((threadIdx.x & 63) == 0){ sh[wid] = s; sh[wid+4] = s2; }
  __syncthreads();
  if (threadIdx.x == 0){
    float a = sh[0]+sh[1]+sh[2]+sh[3], a2 = sh[4]+sh[5]+sh[6]+sh[7];
    gp[(b*8+k8)*2+0] = a; gp[(b*8+k8)*2+1] = a2;
  }
}
__global__ __launch_bounds__(256) void k_gn_apply(float* __restrict__ x, const float* __restrict__ g,
                          const float* __restrict__ be, int Tl, const float* __restrict__ gp){
  int gidx = blockIdx.x*256 + threadIdx.x;
  int b = gidx >> 16, i = gidx & 65535;
  float s = 0.f, s2 = 0.f;
  #pragma unroll
  for (int k = 0; k < 8; k++){ s += gp[(b*8+k)*2]; s2 += gp[(b*8+k)*2+1]; }
  float mean = s*(1.f/65536.f);
  float inv  = rsqrtf(s2*(1.f/65536.f) - mean*mean + 1e-5f);
  int c = i / Tl;
  float* p = x + (size_t)b*65536 + i;
  float v = (*p - mean)*inv*g[c] + be[c];
  *p = gelu_f(v);
}

// (B,128,512) NCH -> (B,512,128) BLD.
__global__ __launch_bounds__(256) void k_transpose2(const float* __restrict__ in, float* __restrict__ out){
  int idx = blockIdx.x*256 + threadIdx.x;
  if (idx >= NB*DM*LL) return;
  int t = idx & 511;
  int c = (idx >> 9) & 127;
  int b = idx >> 16;
  out[(size_t)b*65536 + (size_t)t*128 + c] = in[idx];
}

// (B,512,128) BLD -> (B,128,512) NCH.
__global__ __launch_bounds__(256) void k_transposeB(const float* __restrict__ in, float* __restrict__ out){
  int idx = blockIdx.x*256 + threadIdx.x;
  if (idx >= NB*DM*LL) return;
  int m = idx & 511;
  int c = (idx >> 9) & 127;
  int b = idx >> 16;
  out[idx] = in[(size_t)b*65536 + (size_t)m*128 + c];
}

// LayerNorm last-dim(128), one wave per row.
__global__ __launch_bounds__(256) void k_ln2(const float* __restrict__ x, const float* __restrict__ g,
                      const float* __restrict__ be, float* __restrict__ out, int rows){
  int row = blockIdx.x*4 + (threadIdx.x >> 6);
  if (row >= rows) return;
  int lid = threadIdx.x & 63;
  const float* xr = x + (size_t)row*DM;
  float v0 = xr[lid], v1 = xr[lid+64];
  float s = v0 + v1;
  #pragma unroll
  for (int o = 32; o; o >>= 1) s += __shfl_xor(s, o);
  float mean = s*(1.f/128.f);
  float d0 = v0-mean, d1 = v1-mean;
  float s2 = d0*d0 + d1*d1;
  #pragma unroll
  for (int o = 32; o; o >>= 1) s2 += __shfl_xor(s2, o);
  float inv = rsqrtf(s2*(1.f/128.f) + 1e-5f);
  float* orow = out + (size_t)row*DM;
  orow[lid]    = d0*inv*g[lid]    + be[lid];
  orow[lid+64] = d1*inv*g[lid+64] + be[lid+64];
}

// 128x128 tile fp32 GEMM: C[M,N] = A[M,K] * B[N,K]^T. BK=16, 8x8/thread.
// Requires M%128==0, N%128==0, K%16==0. C row stride = N.
__global__ __launch_bounds__(256) void k_gemm128(const float* __restrict__ A, const float* __restrict__ B,
                          float* __restrict__ C, int N, int K, int lda){
  __shared__ float As[16][140];
  __shared__ float Bs[16][140];
  int tid = threadIdx.x;
  int tx = tid & 15, ty = tid >> 4;
  int m0 = blockIdx.y*128, n0 = blockIdx.x*128;
  int lr = tid >> 2;
  int lc = (tid & 3)*4;
  float acc[8][8] = {};
  for (int k0 = 0; k0 < K; k0 += 16){
    float4 a0 = *(const float4*)(A + (size_t)(m0+lr)*lda + k0 + lc);
    float4 a1 = *(const float4*)(A + (size_t)(m0+lr+64)*lda + k0 + lc);
    float4 b0 = *(const float4*)(B + (size_t)(n0+lr)*K + k0 + lc);
    float4 b1 = *(const float4*)(B + (size_t)(n0+lr+64)*K + k0 + lc);
    As[lc+0][lr] = a0.x; As[lc+1][lr] = a0.y; As[lc+2][lr] = a0.z; As[lc+3][lr] = a0.w;
    As[lc+0][lr+64] = a1.x; As[lc+1][lr+64] = a1.y; As[lc+2][lr+64] = a1.z; As[lc+3][lr+64] = a1.w;
    Bs[lc+0][lr] = b0.x; Bs[lc+1][lr] = b0.y; Bs[lc+2][lr] = b0.z; Bs[lc+3][lr] = b0.w;
    Bs[lc+0][lr+64] = b1.x; Bs[lc+1][lr+64] = b1.y; Bs[lc+2][lr+64] = b1.z; Bs[lc+3][lr+64] = b1.w;
    __syncthreads();
    #pragma unroll
    for (int k = 0; k < 16; k++){
      float4 av0 = *(const float4*)&As[k][ty*8];
      float4 av1 = *(const float4*)&As[k][ty*8+4];
      float4 bv0 = *(const float4*)&Bs[k][tx*8];
      float4 bv1 = *(const float4*)&Bs[k][tx*8+4];
      float a[8] = {av0.x,av0.y,av0.z,av0.w,av1.x,av1.y,av1.z,av1.w};
      float bb[8] = {bv0.x,bv0.y,bv0.z,bv0.w,bv1.x,bv1.y,bv1.z,bv1.w};
      #pragma unroll
      for (int i = 0; i < 8; i++)
        #pragma unroll
        for (int j = 0; j < 8; j++) acc[i][j] += a[i]*bb[j];
    }
    __syncthreads();
  }
  #pragma unroll
  for (int i = 0; i < 8; i++){
    int m = m0 + ty*8 + i;
    float4 c0 = make_float4(acc[i][0],acc[i][1],acc[i][2],acc[i][3]);
    float4 c1 = make_float4(acc[i][4],acc[i][5],acc[i][6],acc[i][7]);
    *(float4*)(C + (size_t)m*N + n0 + tx*8)     = c0;
    *(float4*)(C + (size_t)m*N + n0 + tx*8 + 4) = c1;
  }
}

// 64x64 tile GEMM. TRANS=1: store C^T[n*mtot+m] (for xp-proj -> DBLT).
template<int ACCUM, int TRANS>
__global__ __launch_bounds__(256) void k_gemm_nt(const float* __restrict__ A, const float* __restrict__ B,
                          float* __restrict__ C, int M, int N, int K, int lda, int mtot){
  __shared__ float As[64][17];
  __shared__ float Bs[64][17];
  int tx = threadIdx.x & 15, ty = threadIdx.x >> 4;
  int m0 = blockIdx.y*64, n0 = blockIdx.x*64;
  int lr = threadIdx.x >> 2;
  int lc = (threadIdx.x & 3)*4;
  float acc[4][4] = {};
  for (int k0 = 0; k0 < K; k0 += 16){
    float4 av = *(const float4*)(A + (size_t)(m0+lr)*lda + k0 + lc);
    As[lr][lc+0]=av.x; As[lr][lc+1]=av.y; As[lr][lc+2]=av.z; As[lr][lc+3]=av.w;
    float4 bv = make_float4(0.f,0.f,0.f,0.f);
    if (n0+lr < N) bv = *(const float4*)(B + (size_t)(n0+lr)*K + k0 + lc);
    Bs[lr][lc+0]=bv.x; Bs[lr][lc+1]=bv.y; Bs[lr][lc+2]=bv.z; Bs[lr][lc+3]=bv.w;
    __syncthreads();
    #pragma unroll
    for (int k = 0; k < 16; k++){
      float a[4], bb[4];
      #pragma unroll
      for (int i = 0; i < 4; i++) a[i]  = As[ty*4+i][k];
      #pragma unroll
      for (int j = 0; j < 4; j++) bb[j] = Bs[tx*4+j][k];
      #pragma unroll
      for (int i = 0; i < 4; i++)
        #pragma unroll
        for (int j = 0; j < 4; j++) acc[i][j] += a[i]*bb[j];
    }
    __syncthreads();
  }
  if (TRANS){
    #pragma unroll
    for (int j = 0; j < 4; j++){
      int n = n0 + tx*4 + j;
      if (n < N){
        float4 cv = make_float4(acc[0][j],acc[1][j],acc[2][j],acc[3][j]);
        *(float4*)(C + (size_t)n*mtot + m0 + ty*4) = cv;
      }
    }
  } else {
    #pragma unroll
    for (int i = 0; i < 4; i++){
      int m = m0 + ty*4 + i;
      #pragma unroll
      for (int j = 0; j < 4; j++){
        int n = n0 + tx*4 + j;
        if (n < N){
          size_t off = (size_t)m*N + n;
          C[off] = (ACCUM ? C[off] : 0.f) + acc[i][j];
        }
      }
    }
  }
}

// depthwise causal conv k=4 over xi=XZ[...,:256], +bias, SiLU -> XC (B,L,256)
__global__ __launch_bounds__(256) void k_cconv2(const float* __restrict__ xz, const float* __restrict__ cw,
                         const float* __restrict__ cb, float* __restrict__ xc){
  int idx = blockIdx.x*256 + threadIdx.x;
  if (idx >= NB*LL*DI) return;
  int d = idx & 255;
  int l = (idx >> 8) & 511;
  int b = idx >> 17;
  const float* xi = xz + (size_t)b*262144 + d;
  float acc = cb[d];
  #pragma unroll
  for (int j = 0; j < 4; j++){
    int m = l - 3 + j;
    if (m >= 0) acc += xi[(size_t)m*512]*cw[d*4 + j];
  }
  xc[idx] = silu_f(acc);
}

// dt (softplus) from DBLT (40 x 8192) into container. coalesced reads & writes.
__global__ __launch_bounds__(256) void k_dtT(const float* __restrict__ dblt, const float* __restrict__ dtW,
                      const float* __restrict__ dtb, float* __restrict__ xz){
  int idx = blockIdx.x*256 + threadIdx.x;     // (b,d,l), l fastest
  if (idx >= NB*DI*LL) return;
  int l = idx & 511;
  int d = (idx >> 9) & 255;
  int b = idx >> 17;
  int row = b*512 + l;
  float acc = dtb[d];
  #pragma unroll
  for (int j = 0; j < 8; j++) acc += dblt[(size_t)j*8192 + row]*dtW[d*8 + j];
  float dt = (acc > 20.f) ? acc : log1pf(__expf(acc));
  xz[(size_t)b*262144 + cont_off(d, l)] = dt;
}

// XC (b,l,256) -> XCT (b,256,512) via LDS tile transpose.
__global__ __launch_bounds__(256) void k_tr_xc(const float* __restrict__ xc, float* __restrict__ xct){
  __shared__ float t[32][33];
  int bid = blockIdx.x;
  int lt = bid & 15, dt8 = (bid >> 4) & 7, b = bid >> 7;
  int tx = threadIdx.x & 31, ty = threadIdx.x >> 5;
  int d0 = dt8*32, l0 = lt*32;
  const float* src = xc + (size_t)b*131072;
  #pragma unroll
  for (int j = 0; j < 4; j++)
    t[ty + j*8][tx] = src[(size_t)(l0 + ty + j*8)*256 + d0 + tx];
  __syncthreads();
  float* dst = xct + (size_t)b*131072;
  #pragma unroll
  for (int j = 0; j < 4; j++)
    dst[(size_t)(d0 + ty + j*8)*512 + l0 + tx] = t[tx][ty + j*8];
}

// Block-parallel scan, all-contiguous accesses. One block per (b,d).
__global__ __launch_bounds__(256) void k_scanT(const float* __restrict__ xct,
                        float* __restrict__ xz, const float* __restrict__ dblt,
                        const float* __restrict__ Alog, const float* __restrict__ Dp){
  int bd = blockIdx.x;
  int b = bd >> 8, d = bd & 255;
  int tid = threadIdx.x;
  int c = tid >> 4;
  int s = tid & 15;
  float a  = -__expf(Alog[d*16 + s]);
  float Dd = Dp[d];
  const float* xp = xct + (size_t)b*131072 + (size_t)d*512;
  float* cont = xz + (size_t)b*262144;
  const int l0 = c*32;
  const float* dtp = cont + cont_off(d, l0);
  const float* bmp = dblt + (size_t)(8+s)*8192  + b*512 + l0;
  const float* cmp = dblt + (size_t)(24+s)*8192 + b*512 + l0;

  float e[32], dbx[32];
  float A = 1.f, Bv = 0.f;
  #pragma unroll
  for (int q = 0; q < 8; q++){
    float4 dt4 = *(const float4*)(dtp + q*4);
    float4 xc4 = *(const float4*)(xp + l0 + q*4);
    float4 bm4 = *(const float4*)(bmp + q*4);
    float dts[4] = {dt4.x, dt4.y, dt4.z, dt4.w};
    float xcs[4] = {xc4.x, xc4.y, xc4.z, xc4.w};
    float bms[4] = {bm4.x, bm4.y, bm4.z, bm4.w};
    #pragma unroll
    for (int r = 0; r < 4; r++){
      int i = q*4 + r;
      float ei = __expf(dts[r]*a);
      float di = dts[r]*bms[r]*xcs[r];
      e[i] = ei; dbx[i] = di;
      A *= ei; Bv = ei*Bv + di;
    }
  }
  __shared__ float sA[16][17], sB[16][17];
  sA[c][s] = A; sB[c][s] = Bv;
  __syncthreads();
  if (tid < 16){
    float P = 0.f;
    for (int cc = 0; cc < 16; cc++){
      float Ac = sA[cc][tid], Bc = sB[cc][tid];
      sB[cc][tid] = P;
      P = Ac*P + Bc;
    }
  }
  __syncthreads();
  float h = sB[c][s];
  #pragma unroll
  for (int q = 0; q < 8; q++){
    float4 cm4 = *(const float4*)(cmp + q*4);
    float cms[4] = {cm4.x, cm4.y, cm4.z, cm4.w};
    #pragma unroll
    for (int r = 0; r < 4; r++){
      int i = q*4 + r;
      h = e[i]*h + dbx[i];
      float p = h*cms[r];
      p += __shfl_xor(p, 1); p += __shfl_xor(p, 2);
      p += __shfl_xor(p, 4); p += __shfl_xor(p, 8);
      if (s == 0){
        int l = l0 + i;
        cont[cont_off(d, l)] = p + Dd*xp[l];
      }
    }
  }
}

// gate + transpose: Y(b,l,256) = cont(b,d,l) * silu(z(b,l,256+d))
__global__ __launch_bounds__(256) void k_gateT(const float* __restrict__ xz, float* __restrict__ y){
  __shared__ float t[32][33];
  int bid = blockIdx.x;
  int lt = bid & 15, dt8 = (bid >> 4) & 7, b = bid >> 7;
  int tx = threadIdx.x & 31, ty = threadIdx.x >> 5;
  int d0 = dt8*32, l0 = lt*32;
  const float* cont = xz + (size_t)b*262144;
  #pragma unroll
  for (int j = 0; j < 4; j++)
    t[ty + j*8][tx] = cont[cont_off(d0 + ty + j*8, l0 + tx)];
  __syncthreads();
  #pragma unroll
  for (int j = 0; j < 4; j++){
    int l = l0 + ty + j*8;
    int dd = d0 + tx;
    float zv = xz[(size_t)b*262144 + (size_t)l*512 + 256 + dd];
    y[(size_t)b*131072 + (size_t)l*256 + dd] = t[tx][ty + j*8]*silu_f(zv);
  }
}

// deconv stride2 k3 pad1 outpad1: (B,Ci,Li)->(B,Co,2Li). W (Ci,Co,3). block per (b,o).
__global__ __launch_bounds__(256) void k_deconv2(const float* __restrict__ x, const float* __restrict__ W,
                          const float* __restrict__ bias, float* __restrict__ y,
                          int Ci, int Co, int Li, int cs, int ts){
  __shared__ float w[384];
  int b = blockIdx.x / Co, o = blockIdx.x % Co;
  for (int j = threadIdx.x; j < Ci*3; j += 256){
    int i = j/3, k = j - 3*i;
    w[j] = W[((size_t)i*Co + o)*3 + k];
  }
  __syncthreads();
  int Lo = 2*Li;
  const float* xb = x + (size_t)b*Ci*Li;
  float bo = bias[o];
  size_t obase = ((size_t)b*Co + o)*Lo;
  for (int t = threadIdx.x; t < Lo; t += 256){
    float acc = bo;
    if ((t & 1) == 0){
      int m = t >> 1;
      for (int i = 0; i < Ci; i++) acc += w[i*3+1]*xb[(size_t)i*cs + (size_t)m*ts];
    } else {
      int m0 = t >> 1, m1 = m0 + 1;
      if (m1 < Li){
        for (int i = 0; i < Ci; i++){
          const float* xr = xb + (size_t)i*cs;
          acc += w[i*3+2]*xr[(size_t)m0*ts] + w[i*3+0]*xr[(size_t)m1*ts];
        }
      } else {
        for (int i = 0; i < Ci; i++) acc += w[i*3+2]*xb[(size_t)i*cs + (size_t)m0*ts];
      }
    }
    y[obase + t] = acc;
  }
}

__global__ __launch_bounds__(256) void k_copyf(const float* __restrict__ in, float* __restrict__ out, int n){
  int i = blockIdx.x*256 + threadIdx.x;
  if (i < n) out[i] = in[i];
}

extern "C" void kernel_launch(void* const* d_in, const int* in_sizes, int n_in,
                              void* d_out, int out_size, void* d_ws, size_t ws_size,
                              hipStream_t stream) {
  const float* x      = (const float*)d_in[0];
  const float* mask   = (const float*)d_in[1];
  const float* enc_W0 = (const float*)d_in[2];
  const float* enc_b0 = (const float*)d_in[3];
  const float* enc_g0 = (const float*)d_in[4];
  const float* enc_be0= (const float*)d_in[5];
  const float* enc_W1 = (const float*)d_in[6];
  const float* enc_b1 = (const float*)d_in[7];
  const float* enc_g1 = (const float*)d_in[8];
  const float* enc_be1= (const float*)d_in[9];
  const float* enc_W2 = (const float*)d_in[10];
  const float* enc_b2 = (const float*)d_in[11];
  const float* enc_g2 = (const float*)d_in[12];
  const float* enc_be2= (const float*)d_in[13];
  const float* ln_g   = (const float*)d_in[14];
  const float* ln_b   = (const float*)d_in[15];
  const float* in_W   = (const float*)d_in[16];
  const float* conv_W = (const float*)d_in[17];
  const float* conv_b = (const float*)d_in[18];
  const float* xp_W   = (const float*)d_in[19];
  const float* dt_W   = (const float*)d_in[20];
  const float* dt_b   = (const float*)d_in[21];
  const float* A_log  = (const float*)d_in[22];
  const float* D_p    = (const float*)d_in[23];
  const float* out_W  = (const float*)d_in[24];
  const float* nf_g   = (const float*)d_in[25];
  const float* nf_b   = (const float*)d_in[26];
  const float* dec_W0 = (const float*)d_in[27];
  const float* dec_b0 = (const float*)d_in[28];
  const float* dec_g0 = (const float*)d_in[29];
  const float* dec_be0= (const float*)d_in[30];
  const float* dec_W1 = (const float*)d_in[31];
  const float* dec_b1 = (const float*)d_in[32];
  const float* dec_g1 = (const float*)d_in[33];
  const float* dec_be1= (const float*)d_in[34];
  const float* dec_W2 = (const float*)d_in[35];
  const float* dec_b2 = (const float*)d_in[36];

  float* out = (float*)d_out;

  float* ws  = (float*)d_ws;
  float* S   = ws;                  // 1,048,576  (B,L,128)
  float* U   = S   + 1048576;       // 1,048,576  (B,L,128)
  float* XZ  = U   + 1048576;       // 4,194,304  (B,L,512); xi half doubles as dt/yraw container
  float* CBUF= XZ  + 4194304;       // 2,097,152  XC, then gated Y (B,L,256)
  float* XCT = CBUF+ 2097152;       // 2,097,152  (B,256,512)
  float* DBLT= XCT + 2097152;       //   327,680  (40, 8192) transposed dbl
  float* EB0 = XZ;                  // encoder/decoder scratch (<=1M each)
  float* EB1 = XZ + 1048576;
  float* H0  = CBUF;                // masked input (131,072)
  float* UT  = CBUF;                // transposed U for dec0
  float* GNP = DBLT;                // GN partials (256 floats)

  // ---------------- encoder ----------------
  k_maskmul<<<512, 256, 0, stream>>>(x, mask, H0, NB*2*TT);
  k_conv2<<<16*32, 256, 0, stream>>>(H0, enc_W0, enc_b0, EB0, 2, 32, 4096);
  k_gn_part<<<128, 256, 0, stream>>>(EB0, GNP);
  k_gn_apply<<<4096, 256, 0, stream>>>(EB0, enc_g0, enc_be0, 2048, GNP);
  k_conv2<<<16*64, 256, 0, stream>>>(EB0, enc_W1, enc_b1, EB1, 32, 64, 2048);
  k_gn_part<<<128, 256, 0, stream>>>(EB1, GNP);
  k_gn_apply<<<4096, 256, 0, stream>>>(EB1, enc_g1, enc_be1, 1024, GNP);
  k_conv2<<<16*128, 256, 0, stream>>>(EB1, enc_W2, enc_b2, EB0, 64, 128, 1024);
  k_gn_part<<<128, 256, 0, stream>>>(EB0, GNP);
  k_gn_apply<<<4096, 256, 0, stream>>>(EB0, enc_g2, enc_be2, 512, GNP);
  k_transpose2<<<4096, 256, 0, stream>>>(EB0, S);

  // ---------------- mamba layers ----------------
  const int rows = NB*LL; // 8192
  for (int i = 0; i < NLAYER; i++){
    k_ln2<<<2048, 256, 0, stream>>>(S, ln_g + i*DM, ln_b + i*DM, U, rows);
    k_gemm128<<<dim3(4, 64), 256, 0, stream>>>(U, in_W + (size_t)i*512*DM, XZ, 512, DM, DM);
    k_cconv2<<<8192, 256, 0, stream>>>(XZ, conv_W + (size_t)i*DI*4, conv_b + (size_t)i*DI, CBUF);
    k_gemm_nt<0,1><<<dim3(1, 128), 256, 0, stream>>>(CBUF, xp_W + (size_t)i*40*DI, DBLT, rows, 40, DI, DI, rows);
    k_dtT<<<8192, 256, 0, stream>>>(DBLT, dt_W + (size_t)i*DI*8, dt_b + (size_t)i*DI, XZ);
    k_tr_xc<<<2048, 256, 0, stream>>>(CBUF, XCT);
    k_scanT<<<4096, 256, 0, stream>>>(XCT, XZ, DBLT,
                                      A_log + (size_t)i*DI*16, D_p + (size_t)i*DI);
    k_gateT<<<2048, 256, 0, stream>>>(XZ, CBUF);
    k_gemm_nt<1,0><<<dim3(2, 128), 256, 0, stream>>>(CBUF, out_W + (size_t)i*DM*DI, S, rows, DM, DI, DI, rows);
  }

  // ---------------- decoder ----------------
  k_ln2<<<2048, 256, 0, stream>>>(S, nf_g, nf_b, U, rows);
  k_transposeB<<<4096, 256, 0, stream>>>(U, UT);   // (b,t,c) -> (b,c,t)
  k_deconv2<<<16*64, 256, 0, stream>>>(UT, dec_W0, dec_b0, EB0, 128, 64, 512, 512, 1);
  k_gn_part<<<128, 256, 0, stream>>>(EB0, GNP);
  k_gn_apply<<<4096, 256, 0, stream>>>(EB0, dec_g0, dec_be0, 1024, GNP);
  k_deconv2<<<16*32, 256, 0, stream>>>(EB0, dec_W1, dec_b1, EB1, 64, 32, 1024, 1024, 1);
  k_gn_part<<<128, 256, 0, stream>>>(EB1, GNP);
  k_gn_apply<<<4096, 256, 0, stream>>>(EB1, dec_g1, dec_be1, 2048, GNP);
  k_deconv2<<<16*2, 256, 0, stream>>>(EB1, dec_W2, dec_b2, out, 32, 2, 2048, 2048, 1);

  // echoes (f32)
  k_copyf<<<512, 256, 0, stream>>>(x,    out + 131072, 131072);
  k_copyf<<<512, 256, 0, stream>>>(mask, out + 262144, 131072);
}

// Round 13
// 1520.753 us; speedup vs baseline: 14.1146x; 1.0631x over previous
//
#include <hip/hip_runtime.h>
#include <hip/hip_bf16.h>
#include <math.h>

#define NB 16
#define TT 4096
#define LL 512
#define DM 128
#define DI 256
#define NLAYER 6

static __device__ __forceinline__ float gelu_f(float v){
  return 0.5f*v*(1.f + erff(v*0.70710678118654752f));
}
static __device__ __forceinline__ float silu_f(float v){
  return v/(1.f + __expf(-v));
}
// container slot for (d,l) inside the dead xi half of XZ (b-row of 262144 floats)
static __device__ __forceinline__ size_t cont_off(int d, int l){
  return (size_t)d*1024 + (((size_t)(l >> 8)) << 9) + (l & 255);
}

__global__ __launch_bounds__(256) void k_maskmul(const float* __restrict__ x, const float* __restrict__ m,
                          float* __restrict__ out, int n){
  int i = blockIdx.x*256 + threadIdx.x;
  if (i < n) out[i] = x[i]*m[i];
}

// conv1d stride2 pad1 k3: (B,Ci,Li)->(B,Co,Li/2). block per (b,o). W (Co,Ci,3).
__global__ __launch_bounds__(256) void k_conv2(const float* __restrict__ x, const float* __restrict__ W,
                        const float* __restrict__ bias, float* __restrict__ y,
                        int Ci, int Co, int Li){
  __shared__ float w[192];
  int b = blockIdx.x / Co, o = blockIdx.x % Co;
  for (int j = threadIdx.x; j < Ci*3; j += 256) w[j] = W[(size_t)o*Ci*3 + j];
  __syncthreads();
  int Lo = Li >> 1;
  const float* xb = x + (size_t)b*Ci*Li;
  float bo = bias[o];
  float* yo = y + ((size_t)b*Co + o)*Lo;
  for (int t = threadIdx.x; t < Lo; t += 256){
    int tin = 2*t - 1;
    float acc = bo;
    for (int ci = 0; ci < Ci; ci++){
      const float* xr = xb + (size_t)ci*Li;
      float v0 = (tin >= 0) ? xr[tin] : 0.f;
      acc += w[ci*3+0]*v0 + w[ci*3+1]*xr[tin+1] + w[ci*3+2]*xr[tin+2];
    }
    yo[t] = acc;
  }
}

// -------- GroupNorm(1): wide 2-kernel version (n = 65536 per batch) --------
__global__ __launch_bounds__(256) void k_gn_part(const float* __restrict__ x, float* __restrict__ gp){
  int b = blockIdx.x >> 3, k8 = blockIdx.x & 7;
  const float* xb = x + (size_t)b*65536 + (size_t)k8*8192;
  float s = 0.f, s2 = 0.f;
  for (int i = threadIdx.x; i < 8192; i += 256){ float v = xb[i]; s += v; s2 += v*v; }
  #pragma unroll
  for (int o = 32; o; o >>= 1){ s += __shfl_down(s, o); s2 += __shfl_down(s2, o); }
  __shared__ float sh[8];
  int wid = threadIdx.x >> 6;
  if ((threadIdx.x & 63) == 0){ sh[wid] = s; sh[wid+4] = s2; }
  __syncthreads();
  if (threadIdx.x == 0){
    float a = sh[0]+sh[1]+sh[2]+sh[3], a2 = sh[4]+sh[5]+sh[6]+sh[7];
    gp[(b*8+k8)*2+0] = a; gp[(b*8+k8)*2+1] = a2;
  }
}
__global__ __launch_bounds__(256) void k_gn_apply(float* __restrict__ x, const float* __restrict__ g,
                          const float* __restrict__ be, int Tl, const float* __restrict__ gp){
  int gidx = blockIdx.x*256 + threadIdx.x;
  int b = gidx >> 16, i = gidx & 65535;
  float s = 0.f, s2 = 0.f;
  #pragma unroll
  for (int k = 0; k < 8; k++){ s += gp[(b*8+k)*2]; s2 += gp[(b*8+k)*2+1]; }
  float mean = s*(1.f/65536.f);
  float inv  = rsqrtf(s2*(1.f/65536.f) - mean*mean + 1e-5f);
  int c = i / Tl;
  float* p = x + (size_t)b*65536 + i;
  float v = (*p - mean)*inv*g[c] + be[c];
  *p = gelu_f(v);
}

// (B,128,512) NCH -> (B,512,128) BLD.
__global__ __launch_bounds__(256) void k_transpose2(const float* __restrict__ in, float* __restrict__ out){
  int idx = blockIdx.x*256 + threadIdx.x;
  if (idx >= NB*DM*LL) return;
  int t = idx & 511;
  int c = (idx >> 9) & 127;
  int b = idx >> 16;
  out[(size_t)b*65536 + (size_t)t*128 + c] = in[idx];
}

// (B,512,128) BLD -> (B,128,512) NCH.
__global__ __launch_bounds__(256) void k_transposeB(const float* __restrict__ in, float* __restrict__ out){
  int idx = blockIdx.x*256 + threadIdx.x;
  if (idx >= NB*DM*LL) return;
  int m = idx & 511;
  int c = (idx >> 9) & 127;
  int b = idx >> 16;
  out[idx] = in[(size_t)b*65536 + (size_t)m*128 + c];
}

// LayerNorm last-dim(128), one wave per row.
__global__ __launch_bounds__(256) void k_ln2(const float* __restrict__ x, const float* __restrict__ g,
                      const float* __restrict__ be, float* __restrict__ out, int rows){
  int row = blockIdx.x*4 + (threadIdx.x >> 6);
  if (row >= rows) return;
  int lid = threadIdx.x & 63;
  const float* xr = x + (size_t)row*DM;
  float v0 = xr[lid], v1 = xr[lid+64];
  float s = v0 + v1;
  #pragma unroll
  for (int o = 32; o; o >>= 1) s += __shfl_xor(s, o);
  float mean = s*(1.f/128.f);
  float d0 = v0-mean, d1 = v1-mean;
  float s2 = d0*d0 + d1*d1;
  #pragma unroll
  for (int o = 32; o; o >>= 1) s2 += __shfl_xor(s2, o);
  float inv = rsqrtf(s2*(1.f/128.f) + 1e-5f);
  float* orow = out + (size_t)row*DM;
  orow[lid]    = d0*inv*g[lid]    + be[lid];
  orow[lid+64] = d1*inv*g[lid+64] + be[lid+64];
}

// 128x128 tile fp32 GEMM: C[M,N] = A[M,K] * B[N,K]^T. BK=16, 8x8/thread.
__global__ __launch_bounds__(256) void k_gemm128(const float* __restrict__ A, const float* __restrict__ B,
                          float* __restrict__ C, int N, int K, int lda){
  __shared__ float As[16][140];
  __shared__ float Bs[16][140];
  int tid = threadIdx.x;
  int tx = tid & 15, ty = tid >> 4;
  int m0 = blockIdx.y*128, n0 = blockIdx.x*128;
  int lr = tid >> 2;
  int lc = (tid & 3)*4;
  float acc[8][8] = {};
  for (int k0 = 0; k0 < K; k0 += 16){
    float4 a0 = *(const float4*)(A + (size_t)(m0+lr)*lda + k0 + lc);
    float4 a1 = *(const float4*)(A + (size_t)(m0+lr+64)*lda + k0 + lc);
    float4 b0 = *(const float4*)(B + (size_t)(n0+lr)*K + k0 + lc);
    float4 b1 = *(const float4*)(B + (size_t)(n0+lr+64)*K + k0 + lc);
    As[lc+0][lr] = a0.x; As[lc+1][lr] = a0.y; As[lc+2][lr] = a0.z; As[lc+3][lr] = a0.w;
    As[lc+0][lr+64] = a1.x; As[lc+1][lr+64] = a1.y; As[lc+2][lr+64] = a1.z; As[lc+3][lr+64] = a1.w;
    Bs[lc+0][lr] = b0.x; Bs[lc+1][lr] = b0.y; Bs[lc+2][lr] = b0.z; Bs[lc+3][lr] = b0.w;
    Bs[lc+0][lr+64] = b1.x; Bs[lc+1][lr+64] = b1.y; Bs[lc+2][lr+64] = b1.z; Bs[lc+3][lr+64] = b1.w;
    __syncthreads();
    #pragma unroll
    for (int k = 0; k < 16; k++){
      float4 av0 = *(const float4*)&As[k][ty*8];
      float4 av1 = *(const float4*)&As[k][ty*8+4];
      float4 bv0 = *(const float4*)&Bs[k][tx*8];
      float4 bv1 = *(const float4*)&Bs[k][tx*8+4];
      float a[8] = {av0.x,av0.y,av0.z,av0.w,av1.x,av1.y,av1.z,av1.w};
      float bb[8] = {bv0.x,bv0.y,bv0.z,bv0.w,bv1.x,bv1.y,bv1.z,bv1.w};
      #pragma unroll
      for (int i = 0; i < 8; i++)
        #pragma unroll
        for (int j = 0; j < 8; j++) acc[i][j] += a[i]*bb[j];
    }
    __syncthreads();
  }
  #pragma unroll
  for (int i = 0; i < 8; i++){
    int m = m0 + ty*8 + i;
    float4 c0 = make_float4(acc[i][0],acc[i][1],acc[i][2],acc[i][3]);
    float4 c1 = make_float4(acc[i][4],acc[i][5],acc[i][6],acc[i][7]);
    *(float4*)(C + (size_t)m*N + n0 + tx*8)     = c0;
    *(float4*)(C + (size_t)m*N + n0 + tx*8 + 4) = c1;
  }
}

// 64x64 tile GEMM (non-accum, row-major C, N guarded).
__global__ __launch_bounds__(256) void k_gemm_nt(const float* __restrict__ A, const float* __restrict__ B,
                          float* __restrict__ C, int M, int N, int K, int lda){
  __shared__ float As[64][17];
  __shared__ float Bs[64][17];
  int tx = threadIdx.x & 15, ty = threadIdx.x >> 4;
  int m0 = blockIdx.y*64, n0 = blockIdx.x*64;
  int lr = threadIdx.x >> 2;
  int lc = (threadIdx.x & 3)*4;
  float acc[4][4] = {};
  for (int k0 = 0; k0 < K; k0 += 16){
    float4 av = *(const float4*)(A + (size_t)(m0+lr)*lda + k0 + lc);
    As[lr][lc+0]=av.x; As[lr][lc+1]=av.y; As[lr][lc+2]=av.z; As[lr][lc+3]=av.w;
    float4 bv = make_float4(0.f,0.f,0.f,0.f);
    if (n0+lr < N) bv = *(const float4*)(B + (size_t)(n0+lr)*K + k0 + lc);
    Bs[lr][lc+0]=bv.x; Bs[lr][lc+1]=bv.y; Bs[lr][lc+2]=bv.z; Bs[lr][lc+3]=bv.w;
    __syncthreads();
    #pragma unroll
    for (int k = 0; k < 16; k++){
      float a[4], bb[4];
      #pragma unroll
      for (int i = 0; i < 4; i++) a[i]  = As[ty*4+i][k];
      #pragma unroll
      for (int j = 0; j < 4; j++) bb[j] = Bs[tx*4+j][k];
      #pragma unroll
      for (int i = 0; i < 4; i++)
        #pragma unroll
        for (int j = 0; j < 4; j++) acc[i][j] += a[i]*bb[j];
    }
    __syncthreads();
  }
  #pragma unroll
  for (int i = 0; i < 4; i++){
    int m = m0 + ty*4 + i;
    #pragma unroll
    for (int j = 0; j < 4; j++){
      int n = n0 + tx*4 + j;
      if (n < N) C[(size_t)m*N + n] = acc[i][j];
    }
  }
}

// out-proj GEMM with fused gate: A[m,k] = cont(k, l)*silu(z[l,k]), C += A*B^T.
// M=8192, N=128, K=256. C row stride 128. grid (2,128).
__global__ __launch_bounds__(256) void k_gemm_gate(const float* __restrict__ xz, const float* __restrict__ B,
                          float* __restrict__ C){
  __shared__ float As[64][17];
  __shared__ float Bs[64][17];
  int tx = threadIdx.x & 15, ty = threadIdx.x >> 4;
  int m0 = blockIdx.y*64, n0 = blockIdx.x*64;
  int lr = threadIdx.x >> 2;
  int lc = (threadIdx.x & 3)*4;
  int m = m0 + lr;
  int b = m >> 9, l = m & 511;
  const float* xzb = xz + (size_t)b*262144;
  float acc[4][4] = {};
  for (int k0 = 0; k0 < 256; k0 += 16){
    float4 z4 = *(const float4*)(xzb + (size_t)l*512 + 256 + k0 + lc);
    float zs[4] = {z4.x, z4.y, z4.z, z4.w};
    #pragma unroll
    for (int j = 0; j < 4; j++){
      int d = k0 + lc + j;
      As[lr][lc+j] = xzb[cont_off(d, l)]*silu_f(zs[j]);
    }
    float4 bv = *(const float4*)(B + (size_t)(n0+lr)*256 + k0 + lc);
    Bs[lr][lc+0]=bv.x; Bs[lr][lc+1]=bv.y; Bs[lr][lc+2]=bv.z; Bs[lr][lc+3]=bv.w;
    __syncthreads();
    #pragma unroll
    for (int k = 0; k < 16; k++){
      float a[4], bb[4];
      #pragma unroll
      for (int i = 0; i < 4; i++) a[i]  = As[ty*4+i][k];
      #pragma unroll
      for (int j = 0; j < 4; j++) bb[j] = Bs[tx*4+j][k];
      #pragma unroll
      for (int i = 0; i < 4; i++)
        #pragma unroll
        for (int j = 0; j < 4; j++) acc[i][j] += a[i]*bb[j];
    }
    __syncthreads();
  }
  #pragma unroll
  for (int i = 0; i < 4; i++){
    int mm = m0 + ty*4 + i;
    #pragma unroll
    for (int j = 0; j < 4; j++){
      int n = n0 + tx*4 + j;
      size_t off = (size_t)mm*128 + n;
      C[off] += acc[i][j];
    }
  }
}

// depthwise causal conv k=4 + SiLU, dual-layout output: XC (b,l,d) and XCT (b,d,l).
// block = (b, dtile8, ltile16); 256 thr (32 d x 8 l).
__global__ __launch_bounds__(256) void k_cconv2T(const float* __restrict__ xz, const float* __restrict__ cw,
                          const float* __restrict__ cb, float* __restrict__ xc, float* __restrict__ xct){
  __shared__ float xin[35][33];
  __shared__ float res[32][33];
  int bid = blockIdx.x;
  int lt = bid & 15, dt8 = (bid >> 4) & 7, b = bid >> 7;
  int tx = threadIdx.x & 31, ty = threadIdx.x >> 5;
  int d0 = dt8*32, l0 = lt*32;
  const float* xzb = xz + (size_t)b*262144;
  // stage 35 rows (l0-3 .. l0+31) x 32 d
  for (int r = ty; r < 35; r += 8){
    int lg = l0 - 3 + r;
    xin[r][tx] = (lg >= 0) ? xzb[(size_t)lg*512 + d0 + tx] : 0.f;
  }
  __syncthreads();
  int d = d0 + tx;
  float4 cw4 = *(const float4*)(cw + d*4);
  float cb0 = cb[d];
  #pragma unroll
  for (int j = 0; j < 4; j++){
    int ly = ty + j*8;
    float acc = cb0
      + xin[ly+0][tx]*cw4.x + xin[ly+1][tx]*cw4.y
      + xin[ly+2][tx]*cw4.z + xin[ly+3][tx]*cw4.w;
    float v = silu_f(acc);
    xc[(size_t)b*131072 + (size_t)(l0+ly)*256 + d] = v;
    res[ly][tx] = v;
  }
  __syncthreads();
  #pragma unroll
  for (int j = 0; j < 4; j++){
    int dd = d0 + ty + j*8;
    xct[(size_t)b*131072 + (size_t)dd*512 + l0 + tx] = res[tx][ty + j*8];
  }
}

// Block-parallel scan with fused dt-softplus. One block per (b,d).
// Phase0: dt[512] -> LDS. Phase1: per-(chunk,state) local scan. Combine. Phase3: emit yraw to container.
__global__ __launch_bounds__(256) void k_scanT2(const float* __restrict__ xct,
                        float* __restrict__ xz, const float* __restrict__ dbl,
                        const float* __restrict__ dtW, const float* __restrict__ dtb,
                        const float* __restrict__ Alog, const float* __restrict__ Dp){
  int bd = blockIdx.x;
  int b = bd >> 8, d = bd & 255;
  int tid = threadIdx.x;
  int c = tid >> 4;
  int s = tid & 15;
  const float* xp = xct + (size_t)b*131072 + (size_t)d*512;
  float* cont = xz + (size_t)b*262144;
  const float* dbp = dbl + (size_t)b*20480;

  __shared__ float sdt[512];
  {
    float w[8];
    #pragma unroll
    for (int j = 0; j < 8; j++) w[j] = dtW[d*8 + j];
    float tb = dtb[d];
    #pragma unroll
    for (int t = tid; t < 512; t += 256){
      const float* r = dbp + t*40;
      float4 r0 = *(const float4*)r;
      float4 r1 = *(const float4*)(r+4);
      float raw = tb + r0.x*w[0] + r0.y*w[1] + r0.z*w[2] + r0.w*w[3]
                     + r1.x*w[4] + r1.y*w[5] + r1.z*w[6] + r1.w*w[7];
      sdt[t] = (raw > 20.f) ? raw : log1pf(__expf(raw));
    }
  }
  float a  = -__expf(Alog[d*16 + s]);
  float Dd = Dp[d];
  __syncthreads();

  const int l0 = c*32;
  float e[32], dbx[32];
  float A = 1.f, Bv = 0.f;
  #pragma unroll
  for (int i = 0; i < 32; i++){
    int l = l0 + i;
    float dt  = sdt[l];
    float xcv = xp[l];
    float bm  = dbp[l*40 + 8 + s];
    float ei  = __expf(dt*a);
    float di  = dt*bm*xcv;
    e[i] = ei; dbx[i] = di;
    A *= ei; Bv = ei*Bv + di;
  }
  __shared__ float sA[16][17], sB[16][17];
  sA[c][s] = A; sB[c][s] = Bv;
  __syncthreads();
  if (tid < 16){
    float P = 0.f;
    for (int cc = 0; cc < 16; cc++){
      float Ac = sA[cc][tid], Bc = sB[cc][tid];
      sB[cc][tid] = P;
      P = Ac*P + Bc;
    }
  }
  __syncthreads();
  float h = sB[c][s];
  #pragma unroll
  for (int i = 0; i < 32; i++){
    int l = l0 + i;
    h = e[i]*h + dbx[i];
    float p = h * dbp[l*40 + 24 + s];
    p += __shfl_xor(p, 1); p += __shfl_xor(p, 2);
    p += __shfl_xor(p, 4); p += __shfl_xor(p, 8);
    if (s == 0){
      cont[cont_off(d, l)] = p + Dd*xp[l];
    }
  }
}

// deconv stride2 k3 pad1 outpad1: (B,Ci,Li)->(B,Co,2Li). W (Ci,Co,3). block per (b,o).
__global__ __launch_bounds__(256) void k_deconv2(const float* __restrict__ x, const float* __restrict__ W,
                          const float* __restrict__ bias, float* __restrict__ y,
                          int Ci, int Co, int Li, int cs, int ts){
  __shared__ float w[384];
  int b = blockIdx.x / Co, o = blockIdx.x % Co;
  for (int j = threadIdx.x; j < Ci*3; j += 256){
    int i = j/3, k = j - 3*i;
    w[j] = W[((size_t)i*Co + o)*3 + k];
  }
  __syncthreads();
  int Lo = 2*Li;
  const float* xb = x + (size_t)b*Ci*Li;
  float bo = bias[o];
  size_t obase = ((size_t)b*Co + o)*Lo;
  for (int t = threadIdx.x; t < Lo; t += 256){
    float acc = bo;
    if ((t & 1) == 0){
      int m = t >> 1;
      for (int i = 0; i < Ci; i++) acc += w[i*3+1]*xb[(size_t)i*cs + (size_t)m*ts];
    } else {
      int m0 = t >> 1, m1 = m0 + 1;
      if (m1 < Li){
        for (int i = 0; i < Ci; i++){
          const float* xr = xb + (size_t)i*cs;
          acc += w[i*3+2]*xr[(size_t)m0*ts] + w[i*3+0]*xr[(size_t)m1*ts];
        }
      } else {
        for (int i = 0; i < Ci; i++) acc += w[i*3+2]*xb[(size_t)i*cs + (size_t)m0*ts];
      }
    }
    y[obase + t] = acc;
  }
}

__global__ __launch_bounds__(256) void k_copyf(const float* __restrict__ in, float* __restrict__ out, int n){
  int i = blockIdx.x*256 + threadIdx.x;
  if (i < n) out[i] = in[i];
}

extern "C" void kernel_launch(void* const* d_in, const int* in_sizes, int n_in,
                              void* d_out, int out_size, void* d_ws, size_t ws_size,
                              hipStream_t stream) {
  const float* x      = (const float*)d_in[0];
  const float* mask   = (const float*)d_in[1];
  const float* enc_W0 = (const float*)d_in[2];
  const float* enc_b0 = (const float*)d_in[3];
  const float* enc_g0 = (const float*)d_in[4];
  const float* enc_be0= (const float*)d_in[5];
  const float* enc_W1 = (const float*)d_in[6];
  const float* enc_b1 = (const float*)d_in[7];
  const float* enc_g1 = (const float*)d_in[8];
  const float* enc_be1= (const float*)d_in[9];
  const float* enc_W2 = (const float*)d_in[10];
  const float* enc_b2 = (const float*)d_in[11];
  const float* enc_g2 = (const float*)d_in[12];
  const float* enc_be2= (const float*)d_in[13];
  const float* ln_g   = (const float*)d_in[14];
  const float* ln_b   = (const float*)d_in[15];
  const float* in_W   = (const float*)d_in[16];
  const float* conv_W = (const float*)d_in[17];
  const float* conv_b = (const float*)d_in[18];
  const float* xp_W   = (const float*)d_in[19];
  const float* dt_W   = (const float*)d_in[20];
  const float* dt_b   = (const float*)d_in[21];
  const float* A_log  = (const float*)d_in[22];
  const float* D_p    = (const float*)d_in[23];
  const float* out_W  = (const float*)d_in[24];
  const float* nf_g   = (const float*)d_in[25];
  const float* nf_b   = (const float*)d_in[26];
  const float* dec_W0 = (const float*)d_in[27];
  const float* dec_b0 = (const float*)d_in[28];
  const float* dec_g0 = (const float*)d_in[29];
  const float* dec_be0= (const float*)d_in[30];
  const float* dec_W1 = (const float*)d_in[31];
  const float* dec_b1 = (const float*)d_in[32];
  const float* dec_g1 = (const float*)d_in[33];
  const float* dec_be1= (const float*)d_in[34];
  const float* dec_W2 = (const float*)d_in[35];
  const float* dec_b2 = (const float*)d_in[36];

  float* out = (float*)d_out;

  float* ws  = (float*)d_ws;
  float* S   = ws;                  // 1,048,576  (B,L,128)
  float* U   = S   + 1048576;       // 1,048,576  (B,L,128)
  float* XZ  = U   + 1048576;       // 4,194,304  (B,L,512); xi half doubles as yraw container
  float* XC  = XZ  + 4194304;       // 2,097,152  (B,L,256)
  float* XCT = XC  + 2097152;       // 2,097,152  (B,256,512)
  float* DBL = XCT + 2097152;       //   327,680  (B,L,40)
  float* EB0 = XZ;                  // encoder/decoder scratch (<=1M each)
  float* EB1 = XZ + 1048576;
  float* H0  = XC;                  // masked input (131,072)
  float* UT  = XC;                  // transposed U for dec0
  float* GNP = DBL;                 // GN partials (256 floats)

  // ---------------- encoder ----------------
  k_maskmul<<<512, 256, 0, stream>>>(x, mask, H0, NB*2*TT);
  k_conv2<<<16*32, 256, 0, stream>>>(H0, enc_W0, enc_b0, EB0, 2, 32, 4096);
  k_gn_part<<<128, 256, 0, stream>>>(EB0, GNP);
  k_gn_apply<<<4096, 256, 0, stream>>>(EB0, enc_g0, enc_be0, 2048, GNP);
  k_conv2<<<16*64, 256, 0, stream>>>(EB0, enc_W1, enc_b1, EB1, 32, 64, 2048);
  k_gn_part<<<128, 256, 0, stream>>>(EB1, GNP);
  k_gn_apply<<<4096, 256, 0, stream>>>(EB1, enc_g1, enc_be1, 1024, GNP);
  k_conv2<<<16*128, 256, 0, stream>>>(EB1, enc_W2, enc_b2, EB0, 64, 128, 1024);
  k_gn_part<<<128, 256, 0, stream>>>(EB0, GNP);
  k_gn_apply<<<4096, 256, 0, stream>>>(EB0, enc_g2, enc_be2, 512, GNP);
  k_transpose2<<<4096, 256, 0, stream>>>(EB0, S);

  // ---------------- mamba layers ----------------
  const int rows = NB*LL; // 8192
  for (int i = 0; i < NLAYER; i++){
    k_ln2<<<2048, 256, 0, stream>>>(S, ln_g + i*DM, ln_b + i*DM, U, rows);
    k_gemm128<<<dim3(4, 64), 256, 0, stream>>>(U, in_W + (size_t)i*512*DM, XZ, 512, DM, DM);
    k_cconv2T<<<2048, 256, 0, stream>>>(XZ, conv_W + (size_t)i*DI*4, conv_b + (size_t)i*DI, XC, XCT);
    k_gemm_nt<<<dim3(1, 128), 256, 0, stream>>>(XC, xp_W + (size_t)i*40*DI, DBL, rows, 40, DI, DI);
    k_scanT2<<<4096, 256, 0, stream>>>(XCT, XZ, DBL,
                                       dt_W + (size_t)i*DI*8, dt_b + (size_t)i*DI,
                                       A_log + (size_t)i*DI*16, D_p + (size_t)i*DI);
    k_gemm_gate<<<dim3(2, 128), 256, 0, stream>>>(XZ, out_W + (size_t)i*DM*DI, S);
  }

  // ---------------- decoder ----------------
  k_ln2<<<2048, 256, 0, stream>>>(S, nf_g, nf_b, U, rows);
  k_transposeB<<<4096, 256, 0, stream>>>(U, UT);   // (b,t,c) -> (b,c,t)
  k_deconv2<<<16*64, 256, 0, stream>>>(UT, dec_W0, dec_b0, EB0, 128, 64, 512, 512, 1);
  k_gn_part<<<128, 256, 0, stream>>>(EB0, GNP);
  k_gn_apply<<<4096, 256, 0, stream>>>(EB0, dec_g0, dec_be0, 1024, GNP);
  k_deconv2<<<16*32, 256, 0, stream>>>(EB0, dec_W1, dec_b1, EB1, 64, 32, 1024, 1024, 1);
  k_gn_part<<<128, 256, 0, stream>>>(EB1, GNP);
  k_gn_apply<<<4096, 256, 0, stream>>>(EB1, dec_g1, dec_be1, 2048, GNP);
  k_deconv2<<<16*2, 256, 0, stream>>>(EB1, dec_W2, dec_b2, out, 32, 2, 2048, 2048, 1);

  // echoes (f32)
  k_copyf<<<512, 256, 0, stream>>>(x,    out + 131072, 131072);
  k_copyf<<<512, 256, 0, stream>>>(mask, out + 262144, 131072);
}

// Round 14
// 1336.699 us; speedup vs baseline: 16.0580x; 1.1377x over previous
//
#include <hip/hip_runtime.h>
#include <hip/hip_bf16.h>
#include <math.h>

#define NB 16
#define TT 4096
#define LL 512
#define DM 128
#define DI 256
#define NLAYER 6
#define CL 32     // scan chunk length
#define NCH 16    // chunks per sequence

static __device__ __forceinline__ float gelu_f(float v){
  return 0.5f*v*(1.f + erff(v*0.70710678118654752f));
}
static __device__ __forceinline__ float silu_f(float v){
  return v/(1.f + __expf(-v));
}

__global__ __launch_bounds__(256) void k_maskmul(const float* __restrict__ x, const float* __restrict__ m,
                          float* __restrict__ out, int n){
  int i = blockIdx.x*256 + threadIdx.x;
  if (i < n) out[i] = x[i]*m[i];
}

// conv1d stride2 pad1 k3: (B,Ci,Li)->(B,Co,Li/2). block per (b,o). W (Co,Ci,3).
__global__ __launch_bounds__(256) void k_conv2(const float* __restrict__ x, const float* __restrict__ W,
                        const float* __restrict__ bias, float* __restrict__ y,
                        int Ci, int Co, int Li){
  __shared__ float w[192];
  int b = blockIdx.x / Co, o = blockIdx.x % Co;
  for (int j = threadIdx.x; j < Ci*3; j += 256) w[j] = W[(size_t)o*Ci*3 + j];
  __syncthreads();
  int Lo = Li >> 1;
  const float* xb = x + (size_t)b*Ci*Li;
  float bo = bias[o];
  float* yo = y + ((size_t)b*Co + o)*Lo;
  for (int t = threadIdx.x; t < Lo; t += 256){
    int tin = 2*t - 1;
    float acc = bo;
    for (int ci = 0; ci < Ci; ci++){
      const float* xr = xb + (size_t)ci*Li;
      float v0 = (tin >= 0) ? xr[tin] : 0.f;
      acc += w[ci*3+0]*v0 + w[ci*3+1]*xr[tin+1] + w[ci*3+2]*xr[tin+2];
    }
    yo[t] = acc;
  }
}

// -------- GroupNorm(1): wide 2-kernel version (n = 65536 per batch) --------
__global__ __launch_bounds__(256) void k_gn_part(const float* __restrict__ x, float* __restrict__ gp){
  int b = blockIdx.x >> 3, k8 = blockIdx.x & 7;
  const float* xb = x + (size_t)b*65536 + (size_t)k8*8192;
  float s = 0.f, s2 = 0.f;
  for (int i = threadIdx.x; i < 8192; i += 256){ float v = xb[i]; s += v; s2 += v*v; }
  #pragma unroll
  for (int o = 32; o; o >>= 1){ s += __shfl_down(s, o); s2 += __shfl_down(s2, o); }
  __shared__ float sh[8];
  int wid = threadIdx.x >> 6;
  if ((threadIdx.x & 63) == 0){ sh[wid] = s; sh[wid+4] = s2; }
  __syncthreads();
  if (threadIdx.x == 0){
    float a = sh[0]+sh[1]+sh[2]+sh[3], a2 = sh[4]+sh[5]+sh[6]+sh[7];
    gp[(b*8+k8)*2+0] = a; gp[(b*8+k8)*2+1] = a2;
  }
}
__global__ __launch_bounds__(256) void k_gn_apply(float* __restrict__ x, const float* __restrict__ g,
                          const float* __restrict__ be, int Tl, const float* __restrict__ gp){
  int gidx = blockIdx.x*256 + threadIdx.x;
  int b = gidx >> 16, i = gidx & 65535;
  float s = 0.f, s2 = 0.f;
  #pragma unroll
  for (int k = 0; k < 8; k++){ s += gp[(b*8+k)*2]; s2 += gp[(b*8+k)*2+1]; }
  float mean = s*(1.f/65536.f);
  float inv  = rsqrtf(s2*(1.f/65536.f) - mean*mean + 1e-5f);
  int c = i / Tl;
  float* p = x + (size_t)b*65536 + i;
  float v = (*p - mean)*inv*g[c] + be[c];
  *p = gelu_f(v);
}

// (B,128,512) NCH -> (B,512,128) BLD.
__global__ __launch_bounds__(256) void k_transpose2(const float* __restrict__ in, float* __restrict__ out){
  int idx = blockIdx.x*256 + threadIdx.x;
  if (idx >= NB*DM*LL) return;
  int t = idx & 511;
  int c = (idx >> 9) & 127;
  int b = idx >> 16;
  out[(size_t)b*65536 + (size_t)t*128 + c] = in[idx];
}

// (B,512,128) BLD -> (B,128,512) NCH.
__global__ __launch_bounds__(256) void k_transposeB(const float* __restrict__ in, float* __restrict__ out){
  int idx = blockIdx.x*256 + threadIdx.x;
  if (idx >= NB*DM*LL) return;
  int m = idx & 511;
  int c = (idx >> 9) & 127;
  int b = idx >> 16;
  out[idx] = in[(size_t)b*65536 + (size_t)m*128 + c];
}

// LayerNorm last-dim(128), one wave per row.
__global__ __launch_bounds__(256) void k_ln2(const float* __restrict__ x, const float* __restrict__ g,
                      const float* __restrict__ be, float* __restrict__ out, int rows){
  int row = blockIdx.x*4 + (threadIdx.x >> 6);
  if (row >= rows) return;
  int lid = threadIdx.x & 63;
  const float* xr = x + (size_t)row*DM;
  float v0 = xr[lid], v1 = xr[lid+64];
  float s = v0 + v1;
  #pragma unroll
  for (int o = 32; o; o >>= 1) s += __shfl_xor(s, o);
  float mean = s*(1.f/128.f);
  float d0 = v0-mean, d1 = v1-mean;
  float s2 = d0*d0 + d1*d1;
  #pragma unroll
  for (int o = 32; o; o >>= 1) s2 += __shfl_xor(s2, o);
  float inv = rsqrtf(s2*(1.f/128.f) + 1e-5f);
  float* orow = out + (size_t)row*DM;
  orow[lid]    = d0*inv*g[lid]    + be[lid];
  orow[lid+64] = d1*inv*g[lid+64] + be[lid+64];
}

// 128x128 tile fp32 GEMM: C[M,N] = A[M,K] * B[N,K]^T. BK=16, 8x8/thread.
__global__ __launch_bounds__(256) void k_gemm128(const float* __restrict__ A, const float* __restrict__ B,
                          float* __restrict__ C, int N, int K, int lda){
  __shared__ float As[16][140];
  __shared__ float Bs[16][140];
  int tid = threadIdx.x;
  int tx = tid & 15, ty = tid >> 4;
  int m0 = blockIdx.y*128, n0 = blockIdx.x*128;
  int lr = tid >> 2;
  int lc = (tid & 3)*4;
  float acc[8][8] = {};
  for (int k0 = 0; k0 < K; k0 += 16){
    float4 a0 = *(const float4*)(A + (size_t)(m0+lr)*lda + k0 + lc);
    float4 a1 = *(const float4*)(A + (size_t)(m0+lr+64)*lda + k0 + lc);
    float4 b0 = *(const float4*)(B + (size_t)(n0+lr)*K + k0 + lc);
    float4 b1 = *(const float4*)(B + (size_t)(n0+lr+64)*K + k0 + lc);
    As[lc+0][lr] = a0.x; As[lc+1][lr] = a0.y; As[lc+2][lr] = a0.z; As[lc+3][lr] = a0.w;
    As[lc+0][lr+64] = a1.x; As[lc+1][lr+64] = a1.y; As[lc+2][lr+64] = a1.z; As[lc+3][lr+64] = a1.w;
    Bs[lc+0][lr] = b0.x; Bs[lc+1][lr] = b0.y; Bs[lc+2][lr] = b0.z; Bs[lc+3][lr] = b0.w;
    Bs[lc+0][lr+64] = b1.x; Bs[lc+1][lr+64] = b1.y; Bs[lc+2][lr+64] = b1.z; Bs[lc+3][lr+64] = b1.w;
    __syncthreads();
    #pragma unroll
    for (int k = 0; k < 16; k++){
      float4 av0 = *(const float4*)&As[k][ty*8];
      float4 av1 = *(const float4*)&As[k][ty*8+4];
      float4 bv0 = *(const float4*)&Bs[k][tx*8];
      float4 bv1 = *(const float4*)&Bs[k][tx*8+4];
      float a[8] = {av0.x,av0.y,av0.z,av0.w,av1.x,av1.y,av1.z,av1.w};
      float bb[8] = {bv0.x,bv0.y,bv0.z,bv0.w,bv1.x,bv1.y,bv1.z,bv1.w};
      #pragma unroll
      for (int i = 0; i < 8; i++)
        #pragma unroll
        for (int j = 0; j < 8; j++) acc[i][j] += a[i]*bb[j];
    }
    __syncthreads();
  }
  #pragma unroll
  for (int i = 0; i < 8; i++){
    int m = m0 + ty*8 + i;
    float4 c0 = make_float4(acc[i][0],acc[i][1],acc[i][2],acc[i][3]);
    float4 c1 = make_float4(acc[i][4],acc[i][5],acc[i][6],acc[i][7]);
    *(float4*)(C + (size_t)m*N + n0 + tx*8)     = c0;
    *(float4*)(C + (size_t)m*N + n0 + tx*8 + 4) = c1;
  }
}

// 64x64 tile GEMM. ACCUM: C += / C =. Row-major C (stride N), N guarded.
template<int ACCUM>
__global__ __launch_bounds__(256) void k_gemm_nt(const float* __restrict__ A, const float* __restrict__ B,
                          float* __restrict__ C, int M, int N, int K, int lda){
  __shared__ float As[64][17];
  __shared__ float Bs[64][17];
  int tx = threadIdx.x & 15, ty = threadIdx.x >> 4;
  int m0 = blockIdx.y*64, n0 = blockIdx.x*64;
  int lr = threadIdx.x >> 2;
  int lc = (threadIdx.x & 3)*4;
  float acc[4][4] = {};
  for (int k0 = 0; k0 < K; k0 += 16){
    float4 av = *(const float4*)(A + (size_t)(m0+lr)*lda + k0 + lc);
    As[lr][lc+0]=av.x; As[lr][lc+1]=av.y; As[lr][lc+2]=av.z; As[lr][lc+3]=av.w;
    float4 bv = make_float4(0.f,0.f,0.f,0.f);
    if (n0+lr < N) bv = *(const float4*)(B + (size_t)(n0+lr)*K + k0 + lc);
    Bs[lr][lc+0]=bv.x; Bs[lr][lc+1]=bv.y; Bs[lr][lc+2]=bv.z; Bs[lr][lc+3]=bv.w;
    __syncthreads();
    #pragma unroll
    for (int k = 0; k < 16; k++){
      float a[4], bb[4];
      #pragma unroll
      for (int i = 0; i < 4; i++) a[i]  = As[ty*4+i][k];
      #pragma unroll
      for (int j = 0; j < 4; j++) bb[j] = Bs[tx*4+j][k];
      #pragma unroll
      for (int i = 0; i < 4; i++)
        #pragma unroll
        for (int j = 0; j < 4; j++) acc[i][j] += a[i]*bb[j];
    }
    __syncthreads();
  }
  #pragma unroll
  for (int i = 0; i < 4; i++){
    int m = m0 + ty*4 + i;
    #pragma unroll
    for (int j = 0; j < 4; j++){
      int n = n0 + tx*4 + j;
      if (n < N){
        size_t off = (size_t)m*N + n;
        C[off] = (ACCUM ? C[off] : 0.f) + acc[i][j];
      }
    }
  }
}

// depthwise causal conv k=4 over xi=XZ[...,:256], +bias, SiLU -> XC (B,L,256)
__global__ __launch_bounds__(256) void k_cconv2(const float* __restrict__ xz, const float* __restrict__ cw,
                         const float* __restrict__ cb, float* __restrict__ xc){
  int idx = blockIdx.x*256 + threadIdx.x;
  if (idx >= NB*LL*DI) return;
  int d = idx & 255;
  int l = (idx >> 8) & 511;
  int b = idx >> 17;
  const float* xi = xz + (size_t)b*262144 + d;
  float acc = cb[d];
  #pragma unroll
  for (int j = 0; j < 4; j++){
    int m = l - 3 + j;
    if (m >= 0) acc += xi[(size_t)m*512]*cw[d*4 + j];
  }
  xc[idx] = silu_f(acc);
}

// ---------------- chunked scan, thread = d ----------------
// k1: per-chunk diagonal summaries. block=(b,ch), 256 thr (d). GA/GB [b][ch][s][d].
__global__ __launch_bounds__(256) void k_scan_sum(const float* __restrict__ xc, const float* __restrict__ dbl,
                        const float* __restrict__ dtW, const float* __restrict__ dtb,
                        const float* __restrict__ Alog,
                        float* __restrict__ GA, float* __restrict__ GB){
  __shared__ float srow[CL*40];
  int bid = blockIdx.x;
  int b = bid >> 4, ch = bid & 15;
  int d = threadIdx.x;
  const float* dbp = dbl + (size_t)b*20480 + ch*CL*40;
  for (int j = d; j < CL*40; j += 256) srow[j] = dbp[j];
  float4 w0 = *(const float4*)(dtW + d*8);
  float4 w1 = *(const float4*)(dtW + d*8 + 4);
  float tb = dtb[d];
  float a[16];
  #pragma unroll
  for (int s = 0; s < 16; s++) a[s] = -__expf(Alog[d*16 + s]);
  const float* xcp = xc + (size_t)b*131072 + (size_t)ch*CL*256 + d;
  __syncthreads();
  float A[16], Bv[16];
  #pragma unroll
  for (int s = 0; s < 16; s++){ A[s] = 1.f; Bv[s] = 0.f; }
  #pragma unroll
  for (int i = 0; i < CL; i++){
    const float* r = srow + i*40;
    float raw = tb + r[0]*w0.x + r[1]*w0.y + r[2]*w0.z + r[3]*w0.w
                   + r[4]*w1.x + r[5]*w1.y + r[6]*w1.z + r[7]*w1.w;
    float dt = (raw > 20.f) ? raw : log1pf(__expf(raw));
    float xcv = xcp[(size_t)i*256];
    float dxc = dt*xcv;
    #pragma unroll
    for (int s = 0; s < 16; s++){
      float e = __expf(dt*a[s]);
      A[s] *= e;
      Bv[s] = e*Bv[s] + dxc*r[8+s];
    }
  }
  size_t base = (((size_t)b*NCH + ch)*16)*256 + d;
  #pragma unroll
  for (int s = 0; s < 16; s++){
    GA[base + (size_t)s*256] = A[s];
    GB[base + (size_t)s*256] = Bv[s];
  }
}

// k2: exclusive prefix over chunks. thread per (b,s,d). GB <- h0.
__global__ __launch_bounds__(256) void k_scan_pre(const float* __restrict__ GA, float* __restrict__ GB){
  int gid = blockIdx.x*256 + threadIdx.x;   // 16*16*256 = 65536
  int b = gid >> 12;
  int s = (gid >> 8) & 15;
  int d = gid & 255;
  size_t stride = (size_t)16*256;          // chunk stride
  size_t idx = (((size_t)b*NCH)*16 + s)*256 + d;
  float P = 0.f;
  #pragma unroll
  for (int ch = 0; ch < NCH; ch++){
    float Ac = GA[idx], Bc = GB[idx];
    GB[idx] = P;
    P = Ac*P + Bc;
    idx += stride;
  }
}

// k3: replay + emit gated y in-place over xc. block=(b,ch), thread=d.
__global__ __launch_bounds__(256) void k_scan_emit(float* __restrict__ xc, const float* __restrict__ dbl,
                        const float* __restrict__ xz,
                        const float* __restrict__ dtW, const float* __restrict__ dtb,
                        const float* __restrict__ Alog, const float* __restrict__ Dp,
                        const float* __restrict__ GB){
  __shared__ float srow[CL*40];
  int bid = blockIdx.x;
  int b = bid >> 4, ch = bid & 15;
  int d = threadIdx.x;
  const float* dbp = dbl + (size_t)b*20480 + ch*CL*40;
  for (int j = d; j < CL*40; j += 256) srow[j] = dbp[j];
  float4 w0 = *(const float4*)(dtW + d*8);
  float4 w1 = *(const float4*)(dtW + d*8 + 4);
  float tb = dtb[d];
  float Dd = Dp[d];
  float a[16];
  #pragma unroll
  for (int s = 0; s < 16; s++) a[s] = -__expf(Alog[d*16 + s]);
  float h[16];
  size_t base = (((size_t)b*NCH + ch)*16)*256 + d;
  #pragma unroll
  for (int s = 0; s < 16; s++) h[s] = GB[base + (size_t)s*256];
  float* xcp = xc + (size_t)b*131072 + (size_t)ch*CL*256 + d;
  const float* zp = xz + (size_t)b*262144 + (size_t)ch*CL*512 + 256 + d;
  __syncthreads();
  #pragma unroll
  for (int i = 0; i < CL; i++){
    const float* r = srow + i*40;
    float raw = tb + r[0]*w0.x + r[1]*w0.y + r[2]*w0.z + r[3]*w0.w
                   + r[4]*w1.x + r[5]*w1.y + r[6]*w1.z + r[7]*w1.w;
    float dt = (raw > 20.f) ? raw : log1pf(__expf(raw));
    float xcv = xcp[(size_t)i*256];
    float dxc = dt*xcv;
    float y = Dd*xcv;
    #pragma unroll
    for (int s = 0; s < 16; s++){
      float e = __expf(dt*a[s]);
      h[s] = e*h[s] + dxc*r[8+s];
      y += h[s]*r[24+s];
    }
    float zv = zp[(size_t)i*512];
    xcp[(size_t)i*256] = y*silu_f(zv);
  }
}

// deconv stride2 k3 pad1 outpad1: (B,Ci,Li)->(B,Co,2Li). W (Ci,Co,3). block per (b,o).
__global__ __launch_bounds__(256) void k_deconv2(const float* __restrict__ x, const float* __restrict__ W,
                          const float* __restrict__ bias, float* __restrict__ y,
                          int Ci, int Co, int Li, int cs, int ts){
  __shared__ float w[384];
  int b = blockIdx.x / Co, o = blockIdx.x % Co;
  for (int j = threadIdx.x; j < Ci*3; j += 256){
    int i = j/3, k = j - 3*i;
    w[j] = W[((size_t)i*Co + o)*3 + k];
  }
  __syncthreads();
  int Lo = 2*Li;
  const float* xb = x + (size_t)b*Ci*Li;
  float bo = bias[o];
  size_t obase = ((size_t)b*Co + o)*Lo;
  for (int t = threadIdx.x; t < Lo; t += 256){
    float acc = bo;
    if ((t & 1) == 0){
      int m = t >> 1;
      for (int i = 0; i < Ci; i++) acc += w[i*3+1]*xb[(size_t)i*cs + (size_t)m*ts];
    } else {
      int m0 = t >> 1, m1 = m0 + 1;
      if (m1 < Li){
        for (int i = 0; i < Ci; i++){
          const float* xr = xb + (size_t)i*cs;
          acc += w[i*3+2]*xr[(size_t)m0*ts] + w[i*3+0]*xr[(size_t)m1*ts];
        }
      } else {
        for (int i = 0; i < Ci; i++) acc += w[i*3+2]*xb[(size_t)i*cs + (size_t)m0*ts];
      }
    }
    y[obase + t] = acc;
  }
}

__global__ __launch_bounds__(256) void k_copyf(const float* __restrict__ in, float* __restrict__ out, int n){
  int i = blockIdx.x*256 + threadIdx.x;
  if (i < n) out[i] = in[i];
}

extern "C" void kernel_launch(void* const* d_in, const int* in_sizes, int n_in,
                              void* d_out, int out_size, void* d_ws, size_t ws_size,
                              hipStream_t stream) {
  const float* x      = (const float*)d_in[0];
  const float* mask   = (const float*)d_in[1];
  const float* enc_W0 = (const float*)d_in[2];
  const float* enc_b0 = (const float*)d_in[3];
  const float* enc_g0 = (const float*)d_in[4];
  const float* enc_be0= (const float*)d_in[5];
  const float* enc_W1 = (const float*)d_in[6];
  const float* enc_b1 = (const float*)d_in[7];
  const float* enc_g1 = (const float*)d_in[8];
  const float* enc_be1= (const float*)d_in[9];
  const float* enc_W2 = (const float*)d_in[10];
  const float* enc_b2 = (const float*)d_in[11];
  const float* enc_g2 = (const float*)d_in[12];
  const float* enc_be2= (const float*)d_in[13];
  const float* ln_g   = (const float*)d_in[14];
  const float* ln_b   = (const float*)d_in[15];
  const float* in_W   = (const float*)d_in[16];
  const float* conv_W = (const float*)d_in[17];
  const float* conv_b = (const float*)d_in[18];
  const float* xp_W   = (const float*)d_in[19];
  const float* dt_W   = (const float*)d_in[20];
  const float* dt_b   = (const float*)d_in[21];
  const float* A_log  = (const float*)d_in[22];
  const float* D_p    = (const float*)d_in[23];
  const float* out_W  = (const float*)d_in[24];
  const float* nf_g   = (const float*)d_in[25];
  const float* nf_b   = (const float*)d_in[26];
  const float* dec_W0 = (const float*)d_in[27];
  const float* dec_b0 = (const float*)d_in[28];
  const float* dec_g0 = (const float*)d_in[29];
  const float* dec_be0= (const float*)d_in[30];
  const float* dec_W1 = (const float*)d_in[31];
  const float* dec_b1 = (const float*)d_in[32];
  const float* dec_g1 = (const float*)d_in[33];
  const float* dec_be1= (const float*)d_in[34];
  const float* dec_W2 = (const float*)d_in[35];
  const float* dec_b2 = (const float*)d_in[36];

  float* out = (float*)d_out;

  float* ws  = (float*)d_ws;
  float* S   = ws;                  // 1,048,576  (B,L,128)
  float* U   = S   + 1048576;       // 1,048,576  (B,L,128)
  float* XZ  = U   + 1048576;       // 4,194,304  (B,L,512)
  float* CBUF= XZ  + 4194304;       // 2,097,152  xc -> gated y in-place (B,L,256)
  float* GA  = CBUF+ 2097152;       // 1,048,576  [b][ch][s][d]
  float* GB  = GA  + 1048576;       // 1,048,576  [b][ch][s][d] -> h0
  float* DBL = GB  + 1048576;       //   327,680  (B,L,40)
  float* EB0 = XZ;                  // encoder/decoder scratch (<=1M each)
  float* EB1 = XZ + 1048576;
  float* H0  = CBUF;                // masked input (131,072)
  float* UT  = CBUF;                // transposed U for dec0
  float* GNP = DBL;                 // GN partials (256 floats)

  // ---------------- encoder ----------------
  k_maskmul<<<512, 256, 0, stream>>>(x, mask, H0, NB*2*TT);
  k_conv2<<<16*32, 256, 0, stream>>>(H0, enc_W0, enc_b0, EB0, 2, 32, 4096);
  k_gn_part<<<128, 256, 0, stream>>>(EB0, GNP);
  k_gn_apply<<<4096, 256, 0, stream>>>(EB0, enc_g0, enc_be0, 2048, GNP);
  k_conv2<<<16*64, 256, 0, stream>>>(EB0, enc_W1, enc_b1, EB1, 32, 64, 2048);
  k_gn_part<<<128, 256, 0, stream>>>(EB1, GNP);
  k_gn_apply<<<4096, 256, 0, stream>>>(EB1, enc_g1, enc_be1, 1024, GNP);
  k_conv2<<<16*128, 256, 0, stream>>>(EB1, enc_W2, enc_b2, EB0, 64, 128, 1024);
  k_gn_part<<<128, 256, 0, stream>>>(EB0, GNP);
  k_gn_apply<<<4096, 256, 0, stream>>>(EB0, enc_g2, enc_be2, 512, GNP);
  k_transpose2<<<4096, 256, 0, stream>>>(EB0, S);

  // ---------------- mamba layers ----------------
  const int rows = NB*LL; // 8192
  for (int i = 0; i < NLAYER; i++){
    k_ln2<<<2048, 256, 0, stream>>>(S, ln_g + i*DM, ln_b + i*DM, U, rows);
    k_gemm128<<<dim3(4, 64), 256, 0, stream>>>(U, in_W + (size_t)i*512*DM, XZ, 512, DM, DM);
    k_cconv2<<<8192, 256, 0, stream>>>(XZ, conv_W + (size_t)i*DI*4, conv_b + (size_t)i*DI, CBUF);
    k_gemm_nt<0><<<dim3(1, 128), 256, 0, stream>>>(CBUF, xp_W + (size_t)i*40*DI, DBL, rows, 40, DI, DI);
    k_scan_sum<<<256, 256, 0, stream>>>(CBUF, DBL,
                                        dt_W + (size_t)i*DI*8, dt_b + (size_t)i*DI,
                                        A_log + (size_t)i*DI*16, GA, GB);
    k_scan_pre<<<256, 256, 0, stream>>>(GA, GB);
    k_scan_emit<<<256, 256, 0, stream>>>(CBUF, DBL, XZ,
                                         dt_W + (size_t)i*DI*8, dt_b + (size_t)i*DI,
                                         A_log + (size_t)i*DI*16, D_p + (size_t)i*DI, GB);
    k_gemm_nt<1><<<dim3(2, 128), 256, 0, stream>>>(CBUF, out_W + (size_t)i*DM*DI, S, rows, DM, DI, DI);
  }

  // ---------------- decoder ----------------
  k_ln2<<<2048, 256, 0, stream>>>(S, nf_g, nf_b, U, rows);
  k_transposeB<<<4096, 256, 0, stream>>>(U, UT);   // (b,t,c) -> (b,c,t)
  k_deconv2<<<16*64, 256, 0, stream>>>(UT, dec_W0, dec_b0, EB0, 128, 64, 512, 512, 1);
  k_gn_part<<<128, 256, 0, stream>>>(EB0, GNP);
  k_gn_apply<<<4096, 256, 0, stream>>>(EB0, dec_g0, dec_be0, 1024, GNP);
  k_deconv2<<<16*32, 256, 0, stream>>>(EB0, dec_W1, dec_b1, EB1, 64, 32, 1024, 1024, 1);
  k_gn_part<<<128, 256, 0, stream>>>(EB1, GNP);
  k_gn_apply<<<4096, 256, 0, stream>>>(EB1, dec_g1, dec_be1, 2048, GNP);
  k_deconv2<<<16*2, 256, 0, stream>>>(EB1, dec_W2, dec_b2, out, 32, 2, 2048, 2048, 1);

  // echoes (f32)
  k_copyf<<<512, 256, 0, stream>>>(x,    out + 131072, 131072);
  k_copyf<<<512, 256, 0, stream>>>(mask, out + 262144, 131072);
}

// Round 15
// 1205.293 us; speedup vs baseline: 17.8088x; 1.1090x over previous
//
#include <hip/hip_runtime.h>
#include <hip/hip_bf16.h>
#include <math.h>

#define NB 16
#define TT 4096
#define LL 512
#define DM 128
#define DI 256
#define NLAYER 6
#define CL 32     // scan chunk length
#define NCH 16    // chunks per sequence

static __device__ __forceinline__ float gelu_f(float v){
  return 0.5f*v*(1.f + erff(v*0.70710678118654752f));
}
static __device__ __forceinline__ float silu_f(float v){
  return v/(1.f + __expf(-v));
}

__global__ __launch_bounds__(256) void k_maskmul(const float* __restrict__ x, const float* __restrict__ m,
                          float* __restrict__ out, int n){
  int i = blockIdx.x*256 + threadIdx.x;
  if (i < n) out[i] = x[i]*m[i];
}

// conv1d stride2 pad1 k3, L-chunked: block=(b,o,chunk of S). W (Co,Ci,3).
__global__ __launch_bounds__(256) void k_conv2(const float* __restrict__ x, const float* __restrict__ W,
                        const float* __restrict__ bias, float* __restrict__ y,
                        int Ci, int Co, int Li, int S){
  __shared__ float w[192];
  int bid = blockIdx.x;
  int ch = bid % S;
  int o  = (bid / S) % Co;
  int b  = bid / (S*Co);
  for (int j = threadIdx.x; j < Ci*3; j += 256) w[j] = W[(size_t)o*Ci*3 + j];
  __syncthreads();
  int Lo = Li >> 1;
  int Lc = Lo / S;
  int t0 = ch*Lc, t1 = t0 + Lc;
  const float* xb = x + (size_t)b*Ci*Li;
  float bo = bias[o];
  float* yo = y + ((size_t)b*Co + o)*Lo;
  for (int t = t0 + threadIdx.x; t < t1; t += 256){
    int tin = 2*t - 1;
    float acc = bo;
    for (int ci = 0; ci < Ci; ci++){
      const float* xr = xb + (size_t)ci*Li;
      float v0 = (tin >= 0) ? xr[tin] : 0.f;
      acc += w[ci*3+0]*v0 + w[ci*3+1]*xr[tin+1] + w[ci*3+2]*xr[tin+2];
    }
    yo[t] = acc;
  }
}

// -------- GroupNorm(1): wide 2-kernel version (n = 65536 per batch) --------
__global__ __launch_bounds__(256) void k_gn_part(const float* __restrict__ x, float* __restrict__ gp){
  int b = blockIdx.x >> 3, k8 = blockIdx.x & 7;
  const float* xb = x + (size_t)b*65536 + (size_t)k8*8192;
  float s = 0.f, s2 = 0.f;
  for (int i = threadIdx.x; i < 8192; i += 256){ float v = xb[i]; s += v; s2 += v*v; }
  #pragma unroll
  for (int o = 32; o; o >>= 1){ s += __shfl_down(s, o); s2 += __shfl_down(s2, o); }
  __shared__ float sh[8];
  int wid = threadIdx.x >> 6;
  if ((threadIdx.x & 63) == 0){ sh[wid] = s; sh[wid+4] = s2; }
  __syncthreads();
  if (threadIdx.x == 0){
    float a = sh[0]+sh[1]+sh[2]+sh[3], a2 = sh[4]+sh[5]+sh[6]+sh[7];
    gp[(b*8+k8)*2+0] = a; gp[(b*8+k8)*2+1] = a2;
  }
}
__global__ __launch_bounds__(256) void k_gn_apply(float* __restrict__ x, const float* __restrict__ g,
                          const float* __restrict__ be, int Tl, const float* __restrict__ gp){
  int gidx = blockIdx.x*256 + threadIdx.x;
  int b = gidx >> 16, i = gidx & 65535;
  float s = 0.f, s2 = 0.f;
  #pragma unroll
  for (int k = 0; k < 8; k++){ s += gp[(b*8+k)*2]; s2 += gp[(b*8+k)*2+1]; }
  float mean = s*(1.f/65536.f);
  float inv  = rsqrtf(s2*(1.f/65536.f) - mean*mean + 1e-5f);
  int c = i / Tl;
  float* p = x + (size_t)b*65536 + i;
  float v = (*p - mean)*inv*g[c] + be[c];
  *p = gelu_f(v);
}

// (B,128,512) NCH -> (B,512,128) BLD.
__global__ __launch_bounds__(256) void k_transpose2(const float* __restrict__ in, float* __restrict__ out){
  int idx = blockIdx.x*256 + threadIdx.x;
  if (idx >= NB*DM*LL) return;
  int t = idx & 511;
  int c = (idx >> 9) & 127;
  int b = idx >> 16;
  out[(size_t)b*65536 + (size_t)t*128 + c] = in[idx];
}

// (B,512,128) BLD -> (B,128,512) NCH.
__global__ __launch_bounds__(256) void k_transposeB(const float* __restrict__ in, float* __restrict__ out){
  int idx = blockIdx.x*256 + threadIdx.x;
  if (idx >= NB*DM*LL) return;
  int m = idx & 511;
  int c = (idx >> 9) & 127;
  int b = idx >> 16;
  out[idx] = in[(size_t)b*65536 + (size_t)m*128 + c];
}

// LayerNorm last-dim(128), one wave per row.
__global__ __launch_bounds__(256) void k_ln2(const float* __restrict__ x, const float* __restrict__ g,
                      const float* __restrict__ be, float* __restrict__ out, int rows){
  int row = blockIdx.x*4 + (threadIdx.x >> 6);
  if (row >= rows) return;
  int lid = threadIdx.x & 63;
  const float* xr = x + (size_t)row*DM;
  float v0 = xr[lid], v1 = xr[lid+64];
  float s = v0 + v1;
  #pragma unroll
  for (int o = 32; o; o >>= 1) s += __shfl_xor(s, o);
  float mean = s*(1.f/128.f);
  float d0 = v0-mean, d1 = v1-mean;
  float s2 = d0*d0 + d1*d1;
  #pragma unroll
  for (int o = 32; o; o >>= 1) s2 += __shfl_xor(s2, o);
  float inv = rsqrtf(s2*(1.f/128.f) + 1e-5f);
  float* orow = out + (size_t)row*DM;
  orow[lid]    = d0*inv*g[lid]    + be[lid];
  orow[lid+64] = d1*inv*g[lid+64] + be[lid+64];
}

// 128x128 tile fp32 GEMM: C[M,N] = A[M,K] * B[N,K]^T. BK=16, 8x8/thread.
__global__ __launch_bounds__(256) void k_gemm128(const float* __restrict__ A, const float* __restrict__ B,
                          float* __restrict__ C, int N, int K, int lda){
  __shared__ float As[16][140];
  __shared__ float Bs[16][140];
  int tid = threadIdx.x;
  int tx = tid & 15, ty = tid >> 4;
  int m0 = blockIdx.y*128, n0 = blockIdx.x*128;
  int lr = tid >> 2;
  int lc = (tid & 3)*4;
  float acc[8][8] = {};
  for (int k0 = 0; k0 < K; k0 += 16){
    float4 a0 = *(const float4*)(A + (size_t)(m0+lr)*lda + k0 + lc);
    float4 a1 = *(const float4*)(A + (size_t)(m0+lr+64)*lda + k0 + lc);
    float4 b0 = *(const float4*)(B + (size_t)(n0+lr)*K + k0 + lc);
    float4 b1 = *(const float4*)(B + (size_t)(n0+lr+64)*K + k0 + lc);
    As[lc+0][lr] = a0.x; As[lc+1][lr] = a0.y; As[lc+2][lr] = a0.z; As[lc+3][lr] = a0.w;
    As[lc+0][lr+64] = a1.x; As[lc+1][lr+64] = a1.y; As[lc+2][lr+64] = a1.z; As[lc+3][lr+64] = a1.w;
    Bs[lc+0][lr] = b0.x; Bs[lc+1][lr] = b0.y; Bs[lc+2][lr] = b0.z; Bs[lc+3][lr] = b0.w;
    Bs[lc+0][lr+64] = b1.x; Bs[lc+1][lr+64] = b1.y; Bs[lc+2][lr+64] = b1.z; Bs[lc+3][lr+64] = b1.w;
    __syncthreads();
    #pragma unroll
    for (int k = 0; k < 16; k++){
      float4 av0 = *(const float4*)&As[k][ty*8];
      float4 av1 = *(const float4*)&As[k][ty*8+4];
      float4 bv0 = *(const float4*)&Bs[k][tx*8];
      float4 bv1 = *(const float4*)&Bs[k][tx*8+4];
      float a[8] = {av0.x,av0.y,av0.z,av0.w,av1.x,av1.y,av1.z,av1.w};
      float bb[8] = {bv0.x,bv0.y,bv0.z,bv0.w,bv1.x,bv1.y,bv1.z,bv1.w};
      #pragma unroll
      for (int i = 0; i < 8; i++)
        #pragma unroll
        for (int j = 0; j < 8; j++) acc[i][j] += a[i]*bb[j];
    }
    __syncthreads();
  }
  #pragma unroll
  for (int i = 0; i < 8; i++){
    int m = m0 + ty*8 + i;
    float4 c0 = make_float4(acc[i][0],acc[i][1],acc[i][2],acc[i][3]);
    float4 c1 = make_float4(acc[i][4],acc[i][5],acc[i][6],acc[i][7]);
    *(float4*)(C + (size_t)m*N + n0 + tx*8)     = c0;
    *(float4*)(C + (size_t)m*N + n0 + tx*8 + 4) = c1;
  }
}

// 64x64 tile GEMM. ACCUM: C += / C =. Row-major C (stride N), N guarded.
template<int ACCUM>
__global__ __launch_bounds__(256) void k_gemm_nt(const float* __restrict__ A, const float* __restrict__ B,
                          float* __restrict__ C, int M, int N, int K, int lda){
  __shared__ float As[64][17];
  __shared__ float Bs[64][17];
  int tx = threadIdx.x & 15, ty = threadIdx.x >> 4;
  int m0 = blockIdx.y*64, n0 = blockIdx.x*64;
  int lr = threadIdx.x >> 2;
  int lc = (threadIdx.x & 3)*4;
  float acc[4][4] = {};
  for (int k0 = 0; k0 < K; k0 += 16){
    float4 av = *(const float4*)(A + (size_t)(m0+lr)*lda + k0 + lc);
    As[lr][lc+0]=av.x; As[lr][lc+1]=av.y; As[lr][lc+2]=av.z; As[lr][lc+3]=av.w;
    float4 bv = make_float4(0.f,0.f,0.f,0.f);
    if (n0+lr < N) bv = *(const float4*)(B + (size_t)(n0+lr)*K + k0 + lc);
    Bs[lr][lc+0]=bv.x; Bs[lr][lc+1]=bv.y; Bs[lr][lc+2]=bv.z; Bs[lr][lc+3]=bv.w;
    __syncthreads();
    #pragma unroll
    for (int k = 0; k < 16; k++){
      float a[4], bb[4];
      #pragma unroll
      for (int i = 0; i < 4; i++) a[i]  = As[ty*4+i][k];
      #pragma unroll
      for (int j = 0; j < 4; j++) bb[j] = Bs[tx*4+j][k];
      #pragma unroll
      for (int i = 0; i < 4; i++)
        #pragma unroll
        for (int j = 0; j < 4; j++) acc[i][j] += a[i]*bb[j];
    }
    __syncthreads();
  }
  #pragma unroll
  for (int i = 0; i < 4; i++){
    int m = m0 + ty*4 + i;
    #pragma unroll
    for (int j = 0; j < 4; j++){
      int n = n0 + tx*4 + j;
      if (n < N){
        size_t off = (size_t)m*N + n;
        C[off] = (ACCUM ? C[off] : 0.f) + acc[i][j];
      }
    }
  }
}

// xp-proj GEMM: 32x64 tile (N=40 guarded), grid = M/32 blocks. C[M,40] = A[M,256]*B[40,256]^T
__global__ __launch_bounds__(256) void k_gemm_xp(const float* __restrict__ A, const float* __restrict__ B,
                          float* __restrict__ C){
  __shared__ float As[32][17];
  __shared__ float Bs[64][17];
  int tid = threadIdx.x;
  int m0 = blockIdx.x*32;
  int tx = tid & 15, ty = tid >> 4;
  float acc[2][4] = {};
  for (int k0 = 0; k0 < 256; k0 += 16){
    if (tid < 128){
      int r = tid >> 2, c = (tid & 3)*4;
      float4 av = *(const float4*)(A + (size_t)(m0+r)*256 + k0 + c);
      As[r][c]=av.x; As[r][c+1]=av.y; As[r][c+2]=av.z; As[r][c+3]=av.w;
    }
    {
      int r = tid >> 2, c = (tid & 3)*4;
      float4 bv = make_float4(0.f,0.f,0.f,0.f);
      if (r < 40) bv = *(const float4*)(B + (size_t)r*256 + k0 + c);
      Bs[r][c]=bv.x; Bs[r][c+1]=bv.y; Bs[r][c+2]=bv.z; Bs[r][c+3]=bv.w;
    }
    __syncthreads();
    #pragma unroll
    for (int k = 0; k < 16; k++){
      float a[2], bb[4];
      #pragma unroll
      for (int i = 0; i < 2; i++) a[i] = As[ty*2+i][k];
      #pragma unroll
      for (int j = 0; j < 4; j++) bb[j] = Bs[tx*4+j][k];
      #pragma unroll
      for (int i = 0; i < 2; i++)
        #pragma unroll
        for (int j = 0; j < 4; j++) acc[i][j] += a[i]*bb[j];
    }
    __syncthreads();
  }
  #pragma unroll
  for (int i = 0; i < 2; i++){
    int m = m0 + ty*2 + i;
    #pragma unroll
    for (int j = 0; j < 4; j++){
      int n = tx*4 + j;
      if (n < 40) C[(size_t)m*40 + n] = acc[i][j];
    }
  }
}

// depthwise causal conv k=4 over xi=XZ[...,:256], +bias, SiLU -> XC (B,L,256)
__global__ __launch_bounds__(256) void k_cconv2(const float* __restrict__ xz, const float* __restrict__ cw,
                         const float* __restrict__ cb, float* __restrict__ xc){
  int idx = blockIdx.x*256 + threadIdx.x;
  if (idx >= NB*LL*DI) return;
  int d = idx & 255;
  int l = (idx >> 8) & 511;
  int b = idx >> 17;
  const float* xi = xz + (size_t)b*262144 + d;
  float acc = cb[d];
  #pragma unroll
  for (int j = 0; j < 4; j++){
    int m = l - 3 + j;
    if (m >= 0) acc += xi[(size_t)m*512]*cw[d*4 + j];
  }
  xc[idx] = silu_f(acc);
}

// ---------------- chunked scan, thread = d ----------------
__global__ __launch_bounds__(256) void k_scan_sum(const float* __restrict__ xc, const float* __restrict__ dbl,
                        const float* __restrict__ dtW, const float* __restrict__ dtb,
                        const float* __restrict__ Alog,
                        float* __restrict__ GA, float* __restrict__ GB){
  __shared__ float srow[CL*40];
  int bid = blockIdx.x;
  int b = bid >> 4, ch = bid & 15;
  int d = threadIdx.x;
  const float* dbp = dbl + (size_t)b*20480 + ch*CL*40;
  for (int j = d; j < CL*40; j += 256) srow[j] = dbp[j];
  float4 w0 = *(const float4*)(dtW + d*8);
  float4 w1 = *(const float4*)(dtW + d*8 + 4);
  float tb = dtb[d];
  float a[16];
  #pragma unroll
  for (int s = 0; s < 16; s++) a[s] = -__expf(Alog[d*16 + s]);
  const float* xcp = xc + (size_t)b*131072 + (size_t)ch*CL*256 + d;
  __syncthreads();
  float A[16], Bv[16];
  #pragma unroll
  for (int s = 0; s < 16; s++){ A[s] = 1.f; Bv[s] = 0.f; }
  #pragma unroll
  for (int i = 0; i < CL; i++){
    const float* r = srow + i*40;
    float raw = tb + r[0]*w0.x + r[1]*w0.y + r[2]*w0.z + r[3]*w0.w
                   + r[4]*w1.x + r[5]*w1.y + r[6]*w1.z + r[7]*w1.w;
    float dt = (raw > 20.f) ? raw : log1pf(__expf(raw));
    float xcv = xcp[(size_t)i*256];
    float dxc = dt*xcv;
    #pragma unroll
    for (int s = 0; s < 16; s++){
      float e = __expf(dt*a[s]);
      A[s] *= e;
      Bv[s] = e*Bv[s] + dxc*r[8+s];
    }
  }
  size_t base = (((size_t)b*NCH + ch)*16)*256 + d;
  #pragma unroll
  for (int s = 0; s < 16; s++){
    GA[base + (size_t)s*256] = A[s];
    GB[base + (size_t)s*256] = Bv[s];
  }
}

__global__ __launch_bounds__(256) void k_scan_pre(const float* __restrict__ GA, float* __restrict__ GB){
  int gid = blockIdx.x*256 + threadIdx.x;   // 65536
  int b = gid >> 12;
  int s = (gid >> 8) & 15;
  int d = gid & 255;
  size_t stride = (size_t)16*256;
  size_t idx = (((size_t)b*NCH)*16 + s)*256 + d;
  float P = 0.f;
  #pragma unroll
  for (int ch = 0; ch < NCH; ch++){
    float Ac = GA[idx], Bc = GB[idx];
    GB[idx] = P;
    P = Ac*P + Bc;
    idx += stride;
  }
}

__global__ __launch_bounds__(256) void k_scan_emit(float* __restrict__ xc, const float* __restrict__ dbl,
                        const float* __restrict__ xz,
                        const float* __restrict__ dtW, const float* __restrict__ dtb,
                        const float* __restrict__ Alog, const float* __restrict__ Dp,
                        const float* __restrict__ GB){
  __shared__ float srow[CL*40];
  int bid = blockIdx.x;
  int b = bid >> 4, ch = bid & 15;
  int d = threadIdx.x;
  const float* dbp = dbl + (size_t)b*20480 + ch*CL*40;
  for (int j = d; j < CL*40; j += 256) srow[j] = dbp[j];
  float4 w0 = *(const float4*)(dtW + d*8);
  float4 w1 = *(const float4*)(dtW + d*8 + 4);
  float tb = dtb[d];
  float Dd = Dp[d];
  float a[16];
  #pragma unroll
  for (int s = 0; s < 16; s++) a[s] = -__expf(Alog[d*16 + s]);
  float h[16];
  size_t base = (((size_t)b*NCH + ch)*16)*256 + d;
  #pragma unroll
  for (int s = 0; s < 16; s++) h[s] = GB[base + (size_t)s*256];
  float* xcp = xc + (size_t)b*131072 + (size_t)ch*CL*256 + d;
  const float* zp = xz + (size_t)b*262144 + (size_t)ch*CL*512 + 256 + d;
  __syncthreads();
  #pragma unroll
  for (int i = 0; i < CL; i++){
    const float* r = srow + i*40;
    float raw = tb + r[0]*w0.x + r[1]*w0.y + r[2]*w0.z + r[3]*w0.w
                   + r[4]*w1.x + r[5]*w1.y + r[6]*w1.z + r[7]*w1.w;
    float dt = (raw > 20.f) ? raw : log1pf(__expf(raw));
    float xcv = xcp[(size_t)i*256];
    float dxc = dt*xcv;
    float y = Dd*xcv;
    #pragma unroll
    for (int s = 0; s < 16; s++){
      float e = __expf(dt*a[s]);
      h[s] = e*h[s] + dxc*r[8+s];
      y += h[s]*r[24+s];
    }
    float zv = zp[(size_t)i*512];
    xcp[(size_t)i*256] = y*silu_f(zv);
  }
}

// deconv stride2 k3 pad1 outpad1, L-chunked: block=(b,o,chunk of S). W (Ci,Co,3).
__global__ __launch_bounds__(256) void k_deconv2(const float* __restrict__ x, const float* __restrict__ W,
                          const float* __restrict__ bias, float* __restrict__ y,
                          int Ci, int Co, int Li, int cs, int ts, int S){
  __shared__ float w[384];
  int bid = blockIdx.x;
  int ch = bid % S;
  int o  = (bid / S) % Co;
  int b  = bid / (S*Co);
  for (int j = threadIdx.x; j < Ci*3; j += 256){
    int i = j/3, k = j - 3*i;
    w[j] = W[((size_t)i*Co + o)*3 + k];
  }
  __syncthreads();
  int Lo = 2*Li;
  int Lc = Lo / S;
  int t0 = ch*Lc, t1 = t0 + Lc;
  const float* xb = x + (size_t)b*Ci*Li;
  float bo = bias[o];
  size_t obase = ((size_t)b*Co + o)*Lo;
  for (int t = t0 + threadIdx.x; t < t1; t += 256){
    float acc = bo;
    if ((t & 1) == 0){
      int m = t >> 1;
      for (int i = 0; i < Ci; i++) acc += w[i*3+1]*xb[(size_t)i*cs + (size_t)m*ts];
    } else {
      int m0 = t >> 1, m1 = m0 + 1;
      if (m1 < Li){
        for (int i = 0; i < Ci; i++){
          const float* xr = xb + (size_t)i*cs;
          acc += w[i*3+2]*xr[(size_t)m0*ts] + w[i*3+0]*xr[(size_t)m1*ts];
        }
      } else {
        for (int i = 0; i < Ci; i++) acc += w[i*3+2]*xb[(size_t)i*cs + (size_t)m0*ts];
      }
    }
    y[obase + t] = acc;
  }
}

__global__ __launch_bounds__(256) void k_copyf(const float* __restrict__ in, float* __restrict__ out, int n){
  int i = blockIdx.x*256 + threadIdx.x;
  if (i < n) out[i] = in[i];
}

extern "C" void kernel_launch(void* const* d_in, const int* in_sizes, int n_in,
                              void* d_out, int out_size, void* d_ws, size_t ws_size,
                              hipStream_t stream) {
  const float* x      = (const float*)d_in[0];
  const float* mask   = (const float*)d_in[1];
  const float* enc_W0 = (const float*)d_in[2];
  const float* enc_b0 = (const float*)d_in[3];
  const float* enc_g0 = (const float*)d_in[4];
  const float* enc_be0= (const float*)d_in[5];
  const float* enc_W1 = (const float*)d_in[6];
  const float* enc_b1 = (const float*)d_in[7];
  const float* enc_g1 = (const float*)d_in[8];
  const float* enc_be1= (const float*)d_in[9];
  const float* enc_W2 = (const float*)d_in[10];
  const float* enc_b2 = (const float*)d_in[11];
  const float* enc_g2 = (const float*)d_in[12];
  const float* enc_be2= (const float*)d_in[13];
  const float* ln_g   = (const float*)d_in[14];
  const float* ln_b   = (const float*)d_in[15];
  const float* in_W   = (const float*)d_in[16];
  const float* conv_W = (const float*)d_in[17];
  const float* conv_b = (const float*)d_in[18];
  const float* xp_W   = (const float*)d_in[19];
  const float* dt_W   = (const float*)d_in[20];
  const float* dt_b   = (const float*)d_in[21];
  const float* A_log  = (const float*)d_in[22];
  const float* D_p    = (const float*)d_in[23];
  const float* out_W  = (const float*)d_in[24];
  const float* nf_g   = (const float*)d_in[25];
  const float* nf_b   = (const float*)d_in[26];
  const float* dec_W0 = (const float*)d_in[27];
  const float* dec_b0 = (const float*)d_in[28];
  const float* dec_g0 = (const float*)d_in[29];
  const float* dec_be0= (const float*)d_in[30];
  const float* dec_W1 = (const float*)d_in[31];
  const float* dec_b1 = (const float*)d_in[32];
  const float* dec_g1 = (const float*)d_in[33];
  const float* dec_be1= (const float*)d_in[34];
  const float* dec_W2 = (const float*)d_in[35];
  const float* dec_b2 = (const float*)d_in[36];

  float* out = (float*)d_out;

  float* ws  = (float*)d_ws;
  float* S   = ws;                  // 1,048,576  (B,L,128)
  float* U   = S   + 1048576;       // 1,048,576  (B,L,128)
  float* XZ  = U   + 1048576;       // 4,194,304  (B,L,512)
  float* CBUF= XZ  + 4194304;       // 2,097,152  xc -> gated y in-place (B,L,256)
  float* GA  = CBUF+ 2097152;       // 1,048,576  [b][ch][s][d]
  float* GB  = GA  + 1048576;       // 1,048,576  [b][ch][s][d] -> h0
  float* DBL = GB  + 1048576;       //   327,680  (B,L,40)
  float* EB0 = XZ;                  // encoder/decoder scratch (<=1M each)
  float* EB1 = XZ + 1048576;
  float* H0  = CBUF;                // masked input (131,072)
  float* UT  = CBUF;                // transposed U for dec0
  float* GNP = DBL;                 // GN partials (256 floats)

  // ---------------- encoder ----------------
  k_maskmul<<<512, 256, 0, stream>>>(x, mask, H0, NB*2*TT);
  k_conv2<<<16*32*4, 256, 0, stream>>>(H0, enc_W0, enc_b0, EB0, 2, 32, 4096, 4);
  k_gn_part<<<128, 256, 0, stream>>>(EB0, GNP);
  k_gn_apply<<<4096, 256, 0, stream>>>(EB0, enc_g0, enc_be0, 2048, GNP);
  k_conv2<<<16*64*4, 256, 0, stream>>>(EB0, enc_W1, enc_b1, EB1, 32, 64, 2048, 4);
  k_gn_part<<<128, 256, 0, stream>>>(EB1, GNP);
  k_gn_apply<<<4096, 256, 0, stream>>>(EB1, enc_g1, enc_be1, 1024, GNP);
  k_conv2<<<16*128*2, 256, 0, stream>>>(EB1, enc_W2, enc_b2, EB0, 64, 128, 1024, 2);
  k_gn_part<<<128, 256, 0, stream>>>(EB0, GNP);
  k_gn_apply<<<4096, 256, 0, stream>>>(EB0, enc_g2, enc_be2, 512, GNP);
  k_transpose2<<<4096, 256, 0, stream>>>(EB0, S);

  // ---------------- mamba layers ----------------
  const int rows = NB*LL; // 8192
  for (int i = 0; i < NLAYER; i++){
    k_ln2<<<2048, 256, 0, stream>>>(S, ln_g + i*DM, ln_b + i*DM, U, rows);
    k_gemm128<<<dim3(4, 64), 256, 0, stream>>>(U, in_W + (size_t)i*512*DM, XZ, 512, DM, DM);
    k_cconv2<<<8192, 256, 0, stream>>>(XZ, conv_W + (size_t)i*DI*4, conv_b + (size_t)i*DI, CBUF);
    k_gemm_xp<<<256, 256, 0, stream>>>(CBUF, xp_W + (size_t)i*40*DI, DBL);
    k_scan_sum<<<256, 256, 0, stream>>>(CBUF, DBL,
                                        dt_W + (size_t)i*DI*8, dt_b + (size_t)i*DI,
                                        A_log + (size_t)i*DI*16, GA, GB);
    k_scan_pre<<<256, 256, 0, stream>>>(GA, GB);
    k_scan_emit<<<256, 256, 0, stream>>>(CBUF, DBL, XZ,
                                         dt_W + (size_t)i*DI*8, dt_b + (size_t)i*DI,
                                         A_log + (size_t)i*DI*16, D_p + (size_t)i*DI, GB);
    k_gemm_nt<1><<<dim3(2, 128), 256, 0, stream>>>(CBUF, out_W + (size_t)i*DM*DI, S, rows, DM, DI, DI);
  }

  // ---------------- decoder ----------------
  k_ln2<<<2048, 256, 0, stream>>>(S, nf_g, nf_b, U, rows);
  k_transposeB<<<4096, 256, 0, stream>>>(U, UT);   // (b,t,c) -> (b,c,t)
  k_deconv2<<<16*64*4, 256, 0, stream>>>(UT, dec_W0, dec_b0, EB0, 128, 64, 512, 512, 1, 4);
  k_gn_part<<<128, 256, 0, stream>>>(EB0, GNP);
  k_gn_apply<<<4096, 256, 0, stream>>>(EB0, dec_g0, dec_be0, 1024, GNP);
  k_deconv2<<<16*32*4, 256, 0, stream>>>(EB0, dec_W1, dec_b1, EB1, 64, 32, 1024, 1024, 1, 4);
  k_gn_part<<<128, 256, 0, stream>>>(EB1, GNP);
  k_gn_apply<<<4096, 256, 0, stream>>>(EB1, dec_g1, dec_be1, 2048, GNP);
  k_deconv2<<<16*2*16, 256, 0, stream>>>(EB1, dec_W2, dec_b2, out, 32, 2, 2048, 2048, 1, 16);

  // echoes (f32)
  k_copyf<<<512, 256, 0, stream>>>(x,    out + 131072, 131072);
  k_copyf<<<512, 256, 0, stream>>>(mask, out + 262144, 131072);
}

// Round 16
// 958.279 us; speedup vs baseline: 22.3993x; 1.2578x over previous
//
#include <hip/hip_runtime.h>
#include <hip/hip_bf16.h>
#include <math.h>

#define NB 16
#define TT 4096
#define LL 512
#define DM 128
#define DI 256
#define NLAYER 6
#define CL 32
#define NCH 16

typedef __bf16 bf16x8 __attribute__((ext_vector_type(8)));
typedef float f32x4 __attribute__((ext_vector_type(4)));
typedef unsigned short ushort;

static __device__ __forceinline__ float gelu_f(float v){
  return 0.5f*v*(1.f + erff(v*0.70710678118654752f));
}
static __device__ __forceinline__ float silu_f(float v){
  return v/(1.f + __expf(-v));
}
static __device__ __forceinline__ ushort f2b(float v){
  __hip_bfloat16 h = __float2bfloat16(v);
  return *(ushort*)&h;
}

__global__ __launch_bounds__(256) void k_maskmul(const float* __restrict__ x, const float* __restrict__ m,
                          float* __restrict__ out, int n){
  int i = blockIdx.x*256 + threadIdx.x;
  if (i < n) out[i] = x[i]*m[i];
}

__global__ __launch_bounds__(256) void k_castb(const float* __restrict__ in, ushort* __restrict__ out, int n){
  int i = blockIdx.x*256 + threadIdx.x;
  if (i < n) out[i] = f2b(in[i]);
}

// conv1d stride2 pad1 k3, L-chunked: block=(b,o,chunk of S). W (Co,Ci,3).
__global__ __launch_bounds__(256) void k_conv2(const float* __restrict__ x, const float* __restrict__ W,
                        const float* __restrict__ bias, float* __restrict__ y,
                        int Ci, int Co, int Li, int S){
  __shared__ float w[192];
  int bid = blockIdx.x;
  int ch = bid % S;
  int o  = (bid / S) % Co;
  int b  = bid / (S*Co);
  for (int j = threadIdx.x; j < Ci*3; j += 256) w[j] = W[(size_t)o*Ci*3 + j];
  __syncthreads();
  int Lo = Li >> 1;
  int Lc = Lo / S;
  int t0 = ch*Lc, t1 = t0 + Lc;
  const float* xb = x + (size_t)b*Ci*Li;
  float bo = bias[o];
  float* yo = y + ((size_t)b*Co + o)*Lo;
  for (int t = t0 + threadIdx.x; t < t1; t += 256){
    int tin = 2*t - 1;
    float acc = bo;
    for (int ci = 0; ci < Ci; ci++){
      const float* xr = xb + (size_t)ci*Li;
      float v0 = (tin >= 0) ? xr[tin] : 0.f;
      acc += w[ci*3+0]*v0 + w[ci*3+1]*xr[tin+1] + w[ci*3+2]*xr[tin+2];
    }
    yo[t] = acc;
  }
}

// -------- GroupNorm(1): wide 2-kernel version --------
__global__ __launch_bounds__(256) void k_gn_part(const float* __restrict__ x, float* __restrict__ gp){
  int b = blockIdx.x >> 3, k8 = blockIdx.x & 7;
  const float* xb = x + (size_t)b*65536 + (size_t)k8*8192;
  float s = 0.f, s2 = 0.f;
  for (int i = threadIdx.x; i < 8192; i += 256){ float v = xb[i]; s += v; s2 += v*v; }
  #pragma unroll
  for (int o = 32; o; o >>= 1){ s += __shfl_down(s, o); s2 += __shfl_down(s2, o); }
  __shared__ float sh[8];
  int wid = threadIdx.x >> 6;
  if ((threadIdx.x & 63) == 0){ sh[wid] = s; sh[wid+4] = s2; }
  __syncthreads();
  if (threadIdx.x == 0){
    float a = sh[0]+sh[1]+sh[2]+sh[3], a2 = sh[4]+sh[5]+sh[6]+sh[7];
    gp[(b*8+k8)*2+0] = a; gp[(b*8+k8)*2+1] = a2;
  }
}
__global__ __launch_bounds__(256) void k_gn_apply(float* __restrict__ x, const float* __restrict__ g,
                          const float* __restrict__ be, int Tl, const float* __restrict__ gp){
  int gidx = blockIdx.x*256 + threadIdx.x;
  int b = gidx >> 16, i = gidx & 65535;
  float s = 0.f, s2 = 0.f;
  #pragma unroll
  for (int k = 0; k < 8; k++){ s += gp[(b*8+k)*2]; s2 += gp[(b*8+k)*2+1]; }
  float mean = s*(1.f/65536.f);
  float inv  = rsqrtf(s2*(1.f/65536.f) - mean*mean + 1e-5f);
  int c = i / Tl;
  float* p = x + (size_t)b*65536 + i;
  float v = (*p - mean)*inv*g[c] + be[c];
  *p = gelu_f(v);
}

// (B,128,512) NCH -> (B,512,128) BLD.
__global__ __launch_bounds__(256) void k_transpose2(const float* __restrict__ in, float* __restrict__ out){
  int idx = blockIdx.x*256 + threadIdx.x;
  if (idx >= NB*DM*LL) return;
  int t = idx & 511;
  int c = (idx >> 9) & 127;
  int b = idx >> 16;
  out[(size_t)b*65536 + (size_t)t*128 + c] = in[idx];
}

// (B,512,128) BLD -> (B,128,512) NCH.
__global__ __launch_bounds__(256) void k_transposeB(const float* __restrict__ in, float* __restrict__ out){
  int idx = blockIdx.x*256 + threadIdx.x;
  if (idx >= NB*DM*LL) return;
  int m = idx & 511;
  int c = (idx >> 9) & 127;
  int b = idx >> 16;
  out[idx] = in[(size_t)b*65536 + (size_t)m*128 + c];
}

// LayerNorm last-dim(128) -> f32 out (decoder path).
__global__ __launch_bounds__(256) void k_ln2(const float* __restrict__ x, const float* __restrict__ g,
                      const float* __restrict__ be, float* __restrict__ out, int rows){
  int row = blockIdx.x*4 + (threadIdx.x >> 6);
  if (row >= rows) return;
  int lid = threadIdx.x & 63;
  const float* xr = x + (size_t)row*DM;
  float v0 = xr[lid], v1 = xr[lid+64];
  float s = v0 + v1;
  #pragma unroll
  for (int o = 32; o; o >>= 1) s += __shfl_xor(s, o);
  float mean = s*(1.f/128.f);
  float d0 = v0-mean, d1 = v1-mean;
  float s2 = d0*d0 + d1*d1;
  #pragma unroll
  for (int o = 32; o; o >>= 1) s2 += __shfl_xor(s2, o);
  float inv = rsqrtf(s2*(1.f/128.f) + 1e-5f);
  float* orow = out + (size_t)row*DM;
  orow[lid]    = d0*inv*g[lid]    + be[lid];
  orow[lid+64] = d1*inv*g[lid+64] + be[lid+64];
}

// LayerNorm -> bf16 out (mamba in-proj A operand).
__global__ __launch_bounds__(256) void k_ln2b(const float* __restrict__ x, const float* __restrict__ g,
                      const float* __restrict__ be, ushort* __restrict__ out, int rows){
  int row = blockIdx.x*4 + (threadIdx.x >> 6);
  if (row >= rows) return;
  int lid = threadIdx.x & 63;
  const float* xr = x + (size_t)row*DM;
  float v0 = xr[lid], v1 = xr[lid+64];
  float s = v0 + v1;
  #pragma unroll
  for (int o = 32; o; o >>= 1) s += __shfl_xor(s, o);
  float mean = s*(1.f/128.f);
  float d0 = v0-mean, d1 = v1-mean;
  float s2 = d0*d0 + d1*d1;
  #pragma unroll
  for (int o = 32; o; o >>= 1) s2 += __shfl_xor(s2, o);
  float inv = rsqrtf(s2*(1.f/128.f) + 1e-5f);
  ushort* orow = out + (size_t)row*DM;
  orow[lid]    = f2b(d0*inv*g[lid]    + be[lid]);
  orow[lid+64] = f2b(d1*inv*g[lid+64] + be[lid+64]);
}

// bf16 MFMA GEMM: C[M,N] (+)= A[M,K]*B[N,K]^T. 128x128 block tile, 4 waves of 64x64.
// A,B bf16 row-major; C f32. M%128==0, N%128==0, K%32==0.
template<int ACCUM>
__global__ __launch_bounds__(256) void k_mfma_nt(const ushort* __restrict__ A, const ushort* __restrict__ B,
                          float* __restrict__ C, int N, int K){
  int tid = threadIdx.x;
  int wid = tid >> 6, l = tid & 63;
  int wm = wid >> 1, wn = wid & 1;
  int m0 = blockIdx.y*128 + wm*64;
  int n0 = blockIdx.x*128 + wn*64;
  int lr = l & 15;
  int lk = (l >> 4)*8;
  int orow = (l >> 4)*4;
  f32x4 acc[4][4];
  #pragma unroll
  for (int i = 0; i < 4; i++)
    #pragma unroll
    for (int j = 0; j < 4; j++){
      if (ACCUM){
        #pragma unroll
        for (int r = 0; r < 4; r++)
          acc[i][j][r] = C[(size_t)(m0 + i*16 + orow + r)*N + n0 + j*16 + lr];
      } else {
        acc[i][j] = (f32x4){0.f,0.f,0.f,0.f};
      }
    }
  for (int k0 = 0; k0 < K; k0 += 32){
    bf16x8 a[4], b[4];
    #pragma unroll
    for (int f = 0; f < 4; f++)
      a[f] = *(const bf16x8*)(A + (size_t)(m0 + f*16 + lr)*K + k0 + lk);
    #pragma unroll
    for (int f = 0; f < 4; f++)
      b[f] = *(const bf16x8*)(B + (size_t)(n0 + f*16 + lr)*K + k0 + lk);
    #pragma unroll
    for (int i = 0; i < 4; i++)
      #pragma unroll
      for (int j = 0; j < 4; j++)
        acc[i][j] = __builtin_amdgcn_mfma_f32_16x16x32_bf16(a[i], b[j], acc[i][j], 0, 0, 0);
  }
  #pragma unroll
  for (int i = 0; i < 4; i++)
    #pragma unroll
    for (int j = 0; j < 4; j++)
      #pragma unroll
      for (int r = 0; r < 4; r++)
        C[(size_t)(m0 + i*16 + orow + r)*N + n0 + j*16 + lr] = acc[i][j][r];
}

// xp-proj GEMM f32: 32x64 tile (N=40 guarded). C[M,40] = A[M,256]*B[40,256]^T
__global__ __launch_bounds__(256) void k_gemm_xp(const float* __restrict__ A, const float* __restrict__ B,
                          float* __restrict__ C){
  __shared__ float As[32][17];
  __shared__ float Bs[64][17];
  int tid = threadIdx.x;
  int m0 = blockIdx.x*32;
  int tx = tid & 15, ty = tid >> 4;
  float acc[2][4] = {};
  for (int k0 = 0; k0 < 256; k0 += 16){
    if (tid < 128){
      int r = tid >> 2, c = (tid & 3)*4;
      float4 av = *(const float4*)(A + (size_t)(m0+r)*256 + k0 + c);
      As[r][c]=av.x; As[r][c+1]=av.y; As[r][c+2]=av.z; As[r][c+3]=av.w;
    }
    {
      int r = tid >> 2, c = (tid & 3)*4;
      float4 bv = make_float4(0.f,0.f,0.f,0.f);
      if (r < 40) bv = *(const float4*)(B + (size_t)r*256 + k0 + c);
      Bs[r][c]=bv.x; Bs[r][c+1]=bv.y; Bs[r][c+2]=bv.z; Bs[r][c+3]=bv.w;
    }
    __syncthreads();
    #pragma unroll
    for (int k = 0; k < 16; k++){
      float a[2], bb[4];
      #pragma unroll
      for (int i = 0; i < 2; i++) a[i] = As[ty*2+i][k];
      #pragma unroll
      for (int j = 0; j < 4; j++) bb[j] = Bs[tx*4+j][k];
      #pragma unroll
      for (int i = 0; i < 2; i++)
        #pragma unroll
        for (int j = 0; j < 4; j++) acc[i][j] += a[i]*bb[j];
    }
    __syncthreads();
  }
  #pragma unroll
  for (int i = 0; i < 2; i++){
    int m = m0 + ty*2 + i;
    #pragma unroll
    for (int j = 0; j < 4; j++){
      int n = tx*4 + j;
      if (n < 40) C[(size_t)m*40 + n] = acc[i][j];
    }
  }
}

// depthwise causal conv k=4 over xi=XZ[...,:256], +bias, SiLU -> XC (B,L,256)
__global__ __launch_bounds__(256) void k_cconv2(const float* __restrict__ xz, const float* __restrict__ cw,
                         const float* __restrict__ cb, float* __restrict__ xc){
  int idx = blockIdx.x*256 + threadIdx.x;
  if (idx >= NB*LL*DI) return;
  int d = idx & 255;
  int l = (idx >> 8) & 511;
  int b = idx >> 17;
  const float* xi = xz + (size_t)b*262144 + d;
  float acc = cb[d];
  #pragma unroll
  for (int j = 0; j < 4; j++){
    int m = l - 3 + j;
    if (m >= 0) acc += xi[(size_t)m*512]*cw[d*4 + j];
  }
  xc[idx] = silu_f(acc);
}

// ---------------- chunked scan, thread = d ----------------
__global__ __launch_bounds__(256) void k_scan_sum(const float* __restrict__ xc, const float* __restrict__ dbl,
                        const float* __restrict__ dtW, const float* __restrict__ dtb,
                        const float* __restrict__ Alog,
                        float* __restrict__ GA, float* __restrict__ GB){
  __shared__ float srow[CL*40];
  int bid = blockIdx.x;
  int b = bid >> 4, ch = bid & 15;
  int d = threadIdx.x;
  const float* dbp = dbl + (size_t)b*20480 + ch*CL*40;
  for (int j = d; j < CL*40; j += 256) srow[j] = dbp[j];
  float4 w0 = *(const float4*)(dtW + d*8);
  float4 w1 = *(const float4*)(dtW + d*8 + 4);
  float tb = dtb[d];
  float a[16];
  #pragma unroll
  for (int s = 0; s < 16; s++) a[s] = -__expf(Alog[d*16 + s]);
  const float* xcp = xc + (size_t)b*131072 + (size_t)ch*CL*256 + d;
  __syncthreads();
  float A[16], Bv[16];
  #pragma unroll
  for (int s = 0; s < 16; s++){ A[s] = 1.f; Bv[s] = 0.f; }
  #pragma unroll
  for (int i = 0; i < CL; i++){
    const float* r = srow + i*40;
    float raw = tb + r[0]*w0.x + r[1]*w0.y + r[2]*w0.z + r[3]*w0.w
                   + r[4]*w1.x + r[5]*w1.y + r[6]*w1.z + r[7]*w1.w;
    float dt = (raw > 20.f) ? raw : log1pf(__expf(raw));
    float xcv = xcp[(size_t)i*256];
    float dxc = dt*xcv;
    #pragma unroll
    for (int s = 0; s < 16; s++){
      float e = __expf(dt*a[s]);
      A[s] *= e;
      Bv[s] = e*Bv[s] + dxc*r[8+s];
    }
  }
  size_t base = (((size_t)b*NCH + ch)*16)*256 + d;
  #pragma unroll
  for (int s = 0; s < 16; s++){
    GA[base + (size_t)s*256] = A[s];
    GB[base + (size_t)s*256] = Bv[s];
  }
}

__global__ __launch_bounds__(256) void k_scan_pre(const float* __restrict__ GA, float* __restrict__ GB){
  int gid = blockIdx.x*256 + threadIdx.x;
  int b = gid >> 12;
  int s = (gid >> 8) & 15;
  int d = gid & 255;
  size_t stride = (size_t)16*256;
  size_t idx = (((size_t)b*NCH)*16 + s)*256 + d;
  float P = 0.f;
  #pragma unroll
  for (int ch = 0; ch < NCH; ch++){
    float Ac = GA[idx], Bc = GB[idx];
    GB[idx] = P;
    P = Ac*P + Bc;
    idx += stride;
  }
}

// k3: replay + gate; emit bf16 Y (rows 8192 x 256) for MFMA out-proj.
__global__ __launch_bounds__(256) void k_scan_emit(const float* __restrict__ xc, const float* __restrict__ dbl,
                        const float* __restrict__ xz,
                        const float* __restrict__ dtW, const float* __restrict__ dtb,
                        const float* __restrict__ Alog, const float* __restrict__ Dp,
                        const float* __restrict__ GB, ushort* __restrict__ yb){
  __shared__ float srow[CL*40];
  int bid = blockIdx.x;
  int b = bid >> 4, ch = bid & 15;
  int d = threadIdx.x;
  const float* dbp = dbl + (size_t)b*20480 + ch*CL*40;
  for (int j = d; j < CL*40; j += 256) srow[j] = dbp[j];
  float4 w0 = *(const float4*)(dtW + d*8);
  float4 w1 = *(const float4*)(dtW + d*8 + 4);
  float tb = dtb[d];
  float Dd = Dp[d];
  float a[16];
  #pragma unroll
  for (int s = 0; s < 16; s++) a[s] = -__expf(Alog[d*16 + s]);
  float h[16];
  size_t base = (((size_t)b*NCH + ch)*16)*256 + d;
  #pragma unroll
  for (int s = 0; s < 16; s++) h[s] = GB[base + (size_t)s*256];
  const float* xcp = xc + (size_t)b*131072 + (size_t)ch*CL*256 + d;
  const float* zp = xz + (size_t)b*262144 + (size_t)ch*CL*512 + 256 + d;
  ushort* yp = yb + (size_t)b*131072 + (size_t)ch*CL*256 + d;
  __syncthreads();
  #pragma unroll
  for (int i = 0; i < CL; i++){
    const float* r = srow + i*40;
    float raw = tb + r[0]*w0.x + r[1]*w0.y + r[2]*w0.z + r[3]*w0.w
                   + r[4]*w1.x + r[5]*w1.y + r[6]*w1.z + r[7]*w1.w;
    float dt = (raw > 20.f) ? raw : log1pf(__expf(raw));
    float xcv = xcp[(size_t)i*256];
    float dxc = dt*xcv;
    float y = Dd*xcv;
    #pragma unroll
    for (int s = 0; s < 16; s++){
      float e = __expf(dt*a[s]);
      h[s] = e*h[s] + dxc*r[8+s];
      y += h[s]*r[24+s];
    }
    float zv = zp[(size_t)i*512];
    yp[(size_t)i*256] = f2b(y*silu_f(zv));
  }
}

// deconv stride2 k3 pad1 outpad1, PAIRED: thread computes (2m, 2m+1). x NCH (ts=1).
__global__ __launch_bounds__(256) void k_deconv2p(const float* __restrict__ x, const float* __restrict__ W,
                          const float* __restrict__ bias, float* __restrict__ y,
                          int Ci, int Co, int Li, int cs, int S){
  __shared__ float w[384];
  int bid = blockIdx.x;
  int ch = bid % S;
  int o  = (bid / S) % Co;
  int b  = bid / (S*Co);
  for (int j = threadIdx.x; j < Ci*3; j += 256){
    int i = j/3, k = j - 3*i;
    w[j] = W[((size_t)i*Co + o)*3 + k];
  }
  __syncthreads();
  int Lc = Li / S;           // pairs per chunk
  int m0 = ch*Lc;
  const float* xb = x + (size_t)b*Ci*Li;
  float bo = bias[o];
  float* yo = y + ((size_t)b*Co + o)*(size_t)(2*Li);
  for (int idx = threadIdx.x; idx < Lc; idx += 256){
    int m = m0 + idx;
    float even = bo, odd = bo;
    bool has1 = (m + 1 < Li);
    for (int i = 0; i < Ci; i++){
      const float* xr = xb + (size_t)i*cs;
      float xm  = xr[m];
      float xm1 = has1 ? xr[m+1] : 0.f;
      even += w[i*3+1]*xm;
      odd  += w[i*3+2]*xm + w[i*3+0]*xm1;
    }
    *(float2*)(yo + 2*m) = make_float2(even, odd);
  }
}

__global__ __launch_bounds__(256) void k_copyf(const float* __restrict__ in, float* __restrict__ out, int n){
  int i = blockIdx.x*256 + threadIdx.x;
  if (i < n) out[i] = in[i];
}

extern "C" void kernel_launch(void* const* d_in, const int* in_sizes, int n_in,
                              void* d_out, int out_size, void* d_ws, size_t ws_size,
                              hipStream_t stream) {
  const float* x      = (const float*)d_in[0];
  const float* mask   = (const float*)d_in[1];
  const float* enc_W0 = (const float*)d_in[2];
  const float* enc_b0 = (const float*)d_in[3];
  const float* enc_g0 = (const float*)d_in[4];
  const float* enc_be0= (const float*)d_in[5];
  const float* enc_W1 = (const float*)d_in[6];
  const float* enc_b1 = (const float*)d_in[7];
  const float* enc_g1 = (const float*)d_in[8];
  const float* enc_be1= (const float*)d_in[9];
  const float* enc_W2 = (const float*)d_in[10];
  const float* enc_b2 = (const float*)d_in[11];
  const float* enc_g2 = (const float*)d_in[12];
  const float* enc_be2= (const float*)d_in[13];
  const float* ln_g   = (const float*)d_in[14];
  const float* ln_b   = (const float*)d_in[15];
  const float* in_W   = (const float*)d_in[16];
  const float* conv_W = (const float*)d_in[17];
  const float* conv_b = (const float*)d_in[18];
  const float* xp_W   = (const float*)d_in[19];
  const float* dt_W   = (const float*)d_in[20];
  const float* dt_b   = (const float*)d_in[21];
  const float* A_log  = (const float*)d_in[22];
  const float* D_p    = (const float*)d_in[23];
  const float* out_W  = (const float*)d_in[24];
  const float* nf_g   = (const float*)d_in[25];
  const float* nf_b   = (const float*)d_in[26];
  const float* dec_W0 = (const float*)d_in[27];
  const float* dec_b0 = (const float*)d_in[28];
  const float* dec_g0 = (const float*)d_in[29];
  const float* dec_be0= (const float*)d_in[30];
  const float* dec_W1 = (const float*)d_in[31];
  const float* dec_b1 = (const float*)d_in[32];
  const float* dec_g1 = (const float*)d_in[33];
  const float* dec_be1= (const float*)d_in[34];
  const float* dec_W2 = (const float*)d_in[35];
  const float* dec_b2 = (const float*)d_in[36];

  float* out = (float*)d_out;

  float* ws  = (float*)d_ws;
  float* S    = ws;                  // 1,048,576  (B,L,128)
  float* U    = S    + 1048576;      // 1,048,576; bf16 U lives here (Ub)
  float* XZ   = U    + 1048576;      // 4,194,304  (B,L,512)
  float* CBUF = XZ   + 4194304;      // 2,097,152  xc f32 (B,L,256)
  float* GA   = CBUF + 2097152;      // 1,048,576  [b][ch][s][d]; Yb aliases after scan_pre
  float* GB   = GA   + 1048576;      // 1,048,576
  float* DBL  = GB   + 1048576;      //   327,680  (B,L,40)
  float* WBIN = DBL  + 327680;       //   196,608 slots: in_W bf16 (6*512*128)
  float* WBOUT= WBIN + 196608;       //    98,304 slots: out_W bf16 (6*128*256)
  float* EB0 = XZ;
  float* EB1 = XZ + 1048576;
  float* H0  = CBUF;
  float* UT  = CBUF;
  float* GNP = DBL;
  ushort* Ub    = (ushort*)U;
  ushort* Yb    = (ushort*)GA;
  ushort* WbIn  = (ushort*)WBIN;
  ushort* WbOut = (ushort*)WBOUT;

  // weight conversion (runs every call; deterministic)
  k_castb<<<1536, 256, 0, stream>>>(in_W,  WbIn,  NLAYER*512*DM);
  k_castb<<<768, 256, 0, stream>>>(out_W, WbOut, NLAYER*DM*DI);

  // ---------------- encoder ----------------
  k_maskmul<<<512, 256, 0, stream>>>(x, mask, H0, NB*2*TT);
  k_conv2<<<16*32*4, 256, 0, stream>>>(H0, enc_W0, enc_b0, EB0, 2, 32, 4096, 4);
  k_gn_part<<<128, 256, 0, stream>>>(EB0, GNP);
  k_gn_apply<<<4096, 256, 0, stream>>>(EB0, enc_g0, enc_be0, 2048, GNP);
  k_conv2<<<16*64*4, 256, 0, stream>>>(EB0, enc_W1, enc_b1, EB1, 32, 64, 2048, 4);
  k_gn_part<<<128, 256, 0, stream>>>(EB1, GNP);
  k_gn_apply<<<4096, 256, 0, stream>>>(EB1, enc_g1, enc_be1, 1024, GNP);
  k_conv2<<<16*128*2, 256, 0, stream>>>(EB1, enc_W2, enc_b2, EB0, 64, 128, 1024, 2);
  k_gn_part<<<128, 256, 0, stream>>>(EB0, GNP);
  k_gn_apply<<<4096, 256, 0, stream>>>(EB0, enc_g2, enc_be2, 512, GNP);
  k_transpose2<<<4096, 256, 0, stream>>>(EB0, S);

  // ---------------- mamba layers ----------------
  const int rows = NB*LL; // 8192
  for (int i = 0; i < NLAYER; i++){
    k_ln2b<<<2048, 256, 0, stream>>>(S, ln_g + i*DM, ln_b + i*DM, Ub, rows);
    k_mfma_nt<0><<<dim3(4, 64), 256, 0, stream>>>(Ub, WbIn + (size_t)i*512*DM, XZ, 512, DM);
    k_cconv2<<<8192, 256, 0, stream>>>(XZ, conv_W + (size_t)i*DI*4, conv_b + (size_t)i*DI, CBUF);
    k_gemm_xp<<<256, 256, 0, stream>>>(CBUF, xp_W + (size_t)i*40*DI, DBL);
    k_scan_sum<<<256, 256, 0, stream>>>(CBUF, DBL,
                                        dt_W + (size_t)i*DI*8, dt_b + (size_t)i*DI,
                                        A_log + (size_t)i*DI*16, GA, GB);
    k_scan_pre<<<256, 256, 0, stream>>>(GA, GB);
    k_scan_emit<<<256, 256, 0, stream>>>(CBUF, DBL, XZ,
                                         dt_W + (size_t)i*DI*8, dt_b + (size_t)i*DI,
                                         A_log + (size_t)i*DI*16, D_p + (size_t)i*DI, GB, Yb);
    k_mfma_nt<1><<<dim3(1, 64), 256, 0, stream>>>(Yb, WbOut + (size_t)i*DM*DI, S, DM, DI);
  }

  // ---------------- decoder ----------------
  k_ln2<<<2048, 256, 0, stream>>>(S, nf_g, nf_b, U, rows);
  k_transposeB<<<4096, 256, 0, stream>>>(U, UT);   // (b,t,c) -> (b,c,t)
  k_deconv2p<<<16*64*2, 256, 0, stream>>>(UT, dec_W0, dec_b0, EB0, 128, 64, 512, 512, 2);
  k_gn_part<<<128, 256, 0, stream>>>(EB0, GNP);
  k_gn_apply<<<4096, 256, 0, stream>>>(EB0, dec_g0, dec_be0, 1024, GNP);
  k_deconv2p<<<16*32*4, 256, 0, stream>>>(EB0, dec_W1, dec_b1, EB1, 64, 32, 1024, 1024, 4);
  k_gn_part<<<128, 256, 0, stream>>>(EB1, GNP);
  k_gn_apply<<<4096, 256, 0, stream>>>(EB1, dec_g1, dec_be1, 2048, GNP);
  k_deconv2p<<<16*2*8, 256, 0, stream>>>(EB1, dec_W2, dec_b2, out, 32, 2, 2048, 2048, 8);

  // echoes (f32)
  k_copyf<<<512, 256, 0, stream>>>(x,    out + 131072, 131072);
  k_copyf<<<512, 256, 0, stream>>>(mask, out + 262144, 131072);
}